// Round 14
// baseline (299.106 us; speedup 1.0000x reference)
//
#include <hip/hip_runtime.h>
#include <hip/hip_bf16.h>
#include <stdint.h>
#include <stddef.h>

typedef __bf16 bf16;
typedef __attribute__((ext_vector_type(8))) __bf16 bf16x8;
typedef __attribute__((ext_vector_type(4))) __bf16 bf16x4;
typedef __attribute__((ext_vector_type(4))) float f32x4;

#define DM 2048      // model dim
#define NH 16        // heads
#define HDD 128      // head dim
#define BB 2         // batch
#define TT 2048      // seq len
#define MM (BB*TT)   // 4096 rows
#define NQKV (3*DM)  // 6144

#define L2E 1.4426950408889634f
#define ATT_SCALE 0.08838834764831845f   // 1/sqrt(128), folded into Q at RoPE
#define NEG_INF (-__builtin_inff())

static_assert(sizeof(bf16x8) == 16, "bf16x8 must be 16B");

#define SB0() __builtin_amdgcn_sched_barrier(0)
#define WAITV0() { asm volatile("s_waitcnt vmcnt(0)" ::: "memory"); SB0(); }
#define WAITL0() { asm volatile("s_waitcnt lgkmcnt(0)" ::: "memory"); SB0(); }
#define BARRIER8() { SB0(); __builtin_amdgcn_s_barrier(); SB0(); }

// ---------------------------------------------------------------- helpers
static __device__ __forceinline__ void gload_lds16(const void* g, void* l) {
  __builtin_amdgcn_global_load_lds(
      (__attribute__((address_space(1))) void*)g,
      (__attribute__((address_space(3))) void*)l, 16, 0, 0);
}

// ---------------------------------------------------------------- pre-pass
__global__ __launch_bounds__(256) void rope_table_k(float* __restrict__ cT,
                                                    float* __restrict__ sT) {
  int id = blockIdx.x * 256 + threadIdx.x;          // < 2048*64
  int t = id >> 6, i = id & 63;
  float freq = powf(10000.0f, -(float)i * (1.0f / 64.0f));
  float theta = (float)t * freq;
  float s, c;
  __sincosf(theta, &s, &c);
  cT[id] = c;
  sT[id] = s;
}

__global__ __launch_bounds__(256) void convert_x_k(const float* __restrict__ x,
                                                   bf16* __restrict__ xb) {
  size_t id = (size_t)blockIdx.x * 256 + threadIdx.x;
  size_t o = id * 8;
  float4 a = *(const float4*)(x + o);
  float4 b = *(const float4*)(x + o + 4);
  bf16x8 r;
  r[0] = (bf16)a.x; r[1] = (bf16)a.y; r[2] = (bf16)a.z; r[3] = (bf16)a.w;
  r[4] = (bf16)b.x; r[5] = (bf16)b.y; r[6] = (bf16)b.z; r[7] = (bf16)b.w;
  *(bf16x8*)(xb + o) = r;
}

// W (K x N) f32 -> Wt (N x K) bf16, 64x64 tiles
__global__ __launch_bounds__(256) void transpose_w_k(const float* __restrict__ W,
                                                     bf16* __restrict__ Wt,
                                                     int K, int N) {
  __shared__ float tile[64][65];
  int n0 = blockIdx.x * 64, k0 = blockIdx.y * 64;
  int t = threadIdx.x;
#pragma unroll
  for (int i = 0; i < 16; ++i) {
    int idx = t + i * 256;
    int r = idx >> 6, c = idx & 63;
    tile[r][c] = W[(size_t)(k0 + r) * N + n0 + c];
  }
  __syncthreads();
#pragma unroll
  for (int i = 0; i < 16; ++i) {
    int idx = t + i * 256;
    int r = idx >> 6, c = idx & 63;
    Wt[(size_t)(n0 + r) * K + k0 + c] = (bf16)tile[c][r];
  }
}

// in-place RoPE on (b,h,t,hd) bf16 buffer; SC folds ATT_SCALE (for Q)
template <bool SC>
__global__ __launch_bounds__(256) void rope_apply_k(bf16* __restrict__ buf,
                                                    const float* __restrict__ cT,
                                                    const float* __restrict__ sT) {
  int id = blockIdx.x * 256 + threadIdx.x;   // < 32*2048*16
  int i4 = id & 15;
  int t = (id >> 4) & 2047;
  int bh = id >> 15;
  int idx0 = i4 * 4;
  size_t base = ((size_t)bh * TT + t) * HDD;
  bf16x4 x1 = *(const bf16x4*)(buf + base + idx0);
  bf16x4 x2 = *(const bf16x4*)(buf + base + 64 + idx0);
  float4 ct = *(const float4*)(cT + t * 64 + idx0);
  float4 st = *(const float4*)(sT + t * 64 + idx0);
  bf16x4 o1, o2;
  float c0, s0, a, b2;
  const float scl = SC ? ATT_SCALE : 1.0f;
#pragma unroll
  for (int j = 0; j < 4; ++j) {
    c0 = (j == 0) ? ct.x : (j == 1) ? ct.y : (j == 2) ? ct.z : ct.w;
    s0 = (j == 0) ? st.x : (j == 1) ? st.y : (j == 2) ? st.z : st.w;
    a = (float)x1[j];
    b2 = (float)x2[j];
    o1[j] = (bf16)((a * c0 - b2 * s0) * scl);
    o2[j] = (bf16)((a * s0 + b2 * c0) * scl);
  }
  *(bf16x4*)(buf + base + idx0) = o1;
  *(bf16x4*)(buf + base + 64 + idx0) = o2;
}

// ---------------------------------------------------------------- GEMM (QKV, 4-phase 256x192)
#define MFMA_Q(MF0, NF0, NCNT)                                             \
  do {                                                                     \
    __builtin_amdgcn_s_setprio(1);                                         \
    _Pragma("unroll") for (int mf = 0; mf < 4; ++mf)                       \
    _Pragma("unroll") for (int nf = 0; nf < (NCNT); ++nf)                  \
    _Pragma("unroll") for (int kk = 0; kk < 2; ++kk)                       \
      acc[(MF0) + mf][(NF0) + nf] = __builtin_amdgcn_mfma_f32_16x16x32_bf16( \
          af[(MF0) + mf][kk], bfr[(NF0) + nf][kk], acc[(MF0) + mf][(NF0) + nf], 0, 0, 0); \
    __builtin_amdgcn_s_setprio(0);                                         \
  } while (0)

__global__ __launch_bounds__(512, 2) void gemm8_qkv_k(
    const bf16* __restrict__ A, const bf16* __restrict__ Bt,
    const float* __restrict__ bias,
    bf16* __restrict__ q_out, bf16* __restrict__ k_out, bf16* __restrict__ v_out,
    int M, int N, int K) {
  __shared__ __align__(16) char Lsm[2][57344];   // [buf][A:32KB | B:24KB]
  const int tid = threadIdx.x;
  const int wid = tid >> 6, l = tid & 63;
  const int lane16 = l & 15, lgrp = l >> 4;
  const int wm = wid >> 2, wn = wid & 3;

  int flat = blockIdx.y * gridDim.x + blockIdx.x;
  {
    const int cpx = (gridDim.x * gridDim.y) >> 3;
    flat = (flat & 7) * cpx + (flat >> 3);
  }
  const int bm = flat % gridDim.x;       // 0..15  (M/256)
  const int bn = flat / gridDim.x;       // 0..31  (N/192)
  const int NT = K >> 6;

  const int schunk = (l & 7) ^ ((l >> 3) & 7);
  const bf16* gA = A + (size_t)(bm * 256 + wid * 8 + (l >> 3)) * K + schunk * 8;
  const bf16* gB = Bt + (size_t)(bn * 192 + wid * 8 + (l >> 3)) * K + schunk * 8;

  auto stage_unit = [&](int mat, int t, int u, int buf) {
    const bf16* g = (mat ? gB : gA) + (size_t)(u * 64) * K + t * 64;
    gload_lds16(g, &Lsm[buf][(mat ? 32768 : 0) + u * 8192 + wid * 1024]);
  };

  f32x4 acc[8][3] = {};

#pragma unroll
  for (int u = 0; u < 4; ++u) stage_unit(0, 0, u, 0);
#pragma unroll
  for (int u = 0; u < 3; ++u) stage_unit(1, 0, u, 0);

  for (int t = 0; t < NT; ++t) {
    const int cur = t & 1;
    const char* As = &Lsm[cur][0];
    const char* Bs = &Lsm[cur][32768];
    bf16x8 af[8][2], bfr[3][2];

    WAITV0();
    BARRIER8();

    // ---- phase 0
#pragma unroll
    for (int mf = 0; mf < 4; ++mf)
#pragma unroll
      for (int kk = 0; kk < 2; ++kk) {
        int row = wm * 128 + mf * 16 + lane16;
        int ch = (kk * 4 + lgrp) ^ (lane16 & 7);
        af[mf][kk] = *(const bf16x8*)(As + row * 128 + ch * 16);
      }
#pragma unroll
    for (int nf = 0; nf < 2; ++nf)
#pragma unroll
      for (int kk = 0; kk < 2; ++kk) {
        int row = wn * 48 + nf * 16 + lane16;
        int ch = (kk * 4 + lgrp) ^ (lane16 & 7);
        bfr[nf][kk] = *(const bf16x8*)(Bs + row * 128 + ch * 16);
      }
    if (t + 1 < NT) {
#pragma unroll
      for (int u = 0; u < 4; ++u) stage_unit(0, t + 1, u, cur ^ 1);
    }
    WAITL0();
    MFMA_Q(0, 0, 2);
    BARRIER8();

    // ---- phase 1
#pragma unroll
    for (int mf = 4; mf < 8; ++mf)
#pragma unroll
      for (int kk = 0; kk < 2; ++kk) {
        int row = wm * 128 + mf * 16 + lane16;
        int ch = (kk * 4 + lgrp) ^ (lane16 & 7);
        af[mf][kk] = *(const bf16x8*)(As + row * 128 + ch * 16);
      }
#pragma unroll
    for (int kk = 0; kk < 2; ++kk) {
      int row = wn * 48 + 32 + lane16;
      int ch = (kk * 4 + lgrp) ^ (lane16 & 7);
      bfr[2][kk] = *(const bf16x8*)(Bs + row * 128 + ch * 16);
    }
    if (t + 1 < NT) {
#pragma unroll
      for (int u = 0; u < 3; ++u) stage_unit(1, t + 1, u, cur ^ 1);
    }
    WAITL0();
    MFMA_Q(0, 2, 1);
    BARRIER8();

    // ---- phase 2
    MFMA_Q(4, 0, 2);
    BARRIER8();

    // ---- phase 3
    MFMA_Q(4, 2, 1);
  }

  // ---- epilogue
#pragma unroll
  for (int nf = 0; nf < 3; ++nf) {
    int colg = bn * 192 + wn * 48 + nf * 16 + lane16;
    int which = colg >> 11;
    bf16* outb = (which == 0) ? q_out : (which == 1 ? k_out : v_out);
    int head = (colg >> 7) & 15, hd = colg & 127;
    float bv = bias[colg];
#pragma unroll
    for (int mf = 0; mf < 8; ++mf)
#pragma unroll
      for (int r = 0; r < 4; ++r) {
        int row = bm * 256 + wm * 128 + mf * 16 + lgrp * 4 + r;
        int bb = row >> 11, tt2 = row & 2047;
        outb[((size_t)(bb * NH + head) * TT + tt2) * HDD + hd] =
            (bf16)(acc[mf][nf][r] + bv);
      }
  }
}

// ---------------------------------------------------------------- GEMM (proj, 4-phase 256x128)
__global__ __launch_bounds__(512, 2) void gemm4_proj_k(
    const bf16* __restrict__ A, const bf16* __restrict__ Bt,
    const float* __restrict__ bias, float* __restrict__ c_out,
    int M, int N, int K) {
  __shared__ __align__(16) char Lsm[2][49152];   // [buf][A:32KB | B:16KB]
  const int tid = threadIdx.x;
  const int wid = tid >> 6, l = tid & 63;
  const int lane16 = l & 15, lgrp = l >> 4;
  const int wm = wid >> 2, wn = wid & 3;

  int flat = blockIdx.y * gridDim.x + blockIdx.x;
  {
    const int cpx = (gridDim.x * gridDim.y) >> 3;
    flat = (flat & 7) * cpx + (flat >> 3);
  }
  const int bm = flat % gridDim.x;       // 0..15 (M/256)
  const int bn = flat / gridDim.x;       // 0..15 (N/128)
  const int NT = K >> 6;

  const int schunk = (l & 7) ^ ((l >> 3) & 7);
  const bf16* gA = A + (size_t)(bm * 256 + wid * 8 + (l >> 3)) * K + schunk * 8;
  const bf16* gB = Bt + (size_t)(bn * 128 + wid * 8 + (l >> 3)) * K + schunk * 8;

  auto stage_unit = [&](int mat, int t, int u, int buf) {
    const bf16* g = (mat ? gB : gA) + (size_t)(u * 64) * K + t * 64;
    gload_lds16(g, &Lsm[buf][(mat ? 32768 : 0) + u * 8192 + wid * 1024]);
  };

  f32x4 acc[8][2] = {};

#pragma unroll
  for (int u = 0; u < 4; ++u) stage_unit(0, 0, u, 0);
#pragma unroll
  for (int u = 0; u < 2; ++u) stage_unit(1, 0, u, 0);

  for (int t = 0; t < NT; ++t) {
    const int cur = t & 1;
    const char* As = &Lsm[cur][0];
    const char* Bs = &Lsm[cur][32768];
    bf16x8 af[8][2], bfr[2][2];

    WAITV0();
    BARRIER8();

    // ---- phase 0
#pragma unroll
    for (int mf = 0; mf < 4; ++mf)
#pragma unroll
      for (int kk = 0; kk < 2; ++kk) {
        int row = wm * 128 + mf * 16 + lane16;
        int ch = (kk * 4 + lgrp) ^ (lane16 & 7);
        af[mf][kk] = *(const bf16x8*)(As + row * 128 + ch * 16);
      }
#pragma unroll
    for (int nf = 0; nf < 2; ++nf)
#pragma unroll
      for (int kk = 0; kk < 2; ++kk) {
        int row = wn * 32 + nf * 16 + lane16;
        int ch = (kk * 4 + lgrp) ^ (lane16 & 7);
        bfr[nf][kk] = *(const bf16x8*)(Bs + row * 128 + ch * 16);
      }
    if (t + 1 < NT) {
#pragma unroll
      for (int u = 0; u < 4; ++u) stage_unit(0, t + 1, u, cur ^ 1);
    }
    WAITL0();
    MFMA_Q(0, 0, 1);
    BARRIER8();

    // ---- phase 1
#pragma unroll
    for (int mf = 4; mf < 8; ++mf)
#pragma unroll
      for (int kk = 0; kk < 2; ++kk) {
        int row = wm * 128 + mf * 16 + lane16;
        int ch = (kk * 4 + lgrp) ^ (lane16 & 7);
        af[mf][kk] = *(const bf16x8*)(As + row * 128 + ch * 16);
      }
    if (t + 1 < NT) {
#pragma unroll
      for (int u = 0; u < 2; ++u) stage_unit(1, t + 1, u, cur ^ 1);
    }
    WAITL0();
    MFMA_Q(0, 1, 1);
    BARRIER8();

    // ---- phase 2
    MFMA_Q(4, 0, 1);
    BARRIER8();

    // ---- phase 3
    MFMA_Q(4, 1, 1);
  }

  // ---- epilogue: bias + f32 row-major store
#pragma unroll
  for (int nf = 0; nf < 2; ++nf) {
    int colg = bn * 128 + wn * 32 + nf * 16 + lane16;
    float bv = bias[colg];
#pragma unroll
    for (int mf = 0; mf < 8; ++mf)
#pragma unroll
      for (int r = 0; r < 4; ++r) {
        int row = bm * 256 + wm * 128 + mf * 16 + lgrp * 4 + r;
        c_out[(size_t)row * N + colg] = acc[mf][nf][r] + bv;
      }
  }
}

// ---------------------------------------------------------------- attention
// R13 structure with R14 change: K+V REG-STAGED (T14, R2-correctness
// precedent). Per tile: write_K+write_V (pure ds_writes from regs) ->
// __syncthreads -> issue load_K/load_V(kt+1) (plain per-lane global loads,
// land during compute, drained free by end barrier) -> compute ->
// __syncthreads. No gload_lds in attn (retired R8/R10); 2 barriers/tile.
__global__ __launch_bounds__(512, 2) void attn_k(
    const bf16* __restrict__ Q, const bf16* __restrict__ Kt,
    const bf16* __restrict__ V, bf16* __restrict__ Y) {
  __shared__ __align__(16) bf16 Ksm[128 * 128];   // [key][hd], chunk^=g4(key), 32KB
  __shared__ __align__(16) bf16 Vsm[128 * 128];   // [hd][key], chunk^=g4(hd), 32KB
  __shared__ __align__(16) bf16 Psm[8][16 * 128]; // per-wave P, chunk^=g4(row), 32KB
  const int tid = threadIdx.x, w = tid >> 6, l = tid & 63;
  const int lane16 = l & 15, lgrp = l >> 4;
  const int bh = blockIdx.y;
  const int b = bh >> 4, h = bh & 15;
  const size_t base = (size_t)bh * TT * HDD;

  uint4 kreg[4], vreg[4];
  const int vg = tid >> 4, vh8 = tid & 15;

  auto load_K = [&](int k0) {
#pragma unroll
    for (int i = 0; i < 4; ++i) {
      int key = w * 16 + i * 4 + (l >> 4);
      int c = (l & 15) ^ ((key ^ (key >> 3)) & 15);
      kreg[i] = *(const uint4*)(Kt + base + (size_t)(k0 + key) * HDD + c * 8);
    }
  };
  auto write_K = [&]() {
#pragma unroll
    for (int i = 0; i < 4; ++i) {
      int key = w * 16 + i * 4 + (l >> 4);
      *(uint4*)((char*)Ksm + key * 256 + (l & 15) * 16) = kreg[i];
    }
  };
  auto load_V = [&](int k0) {
#pragma unroll
    for (int kq = 0; kq < 4; ++kq)
      vreg[kq] = *(const uint4*)(V + base + (size_t)(k0 + vg * 4 + kq) * HDD + vh8 * 8);
  };
  auto write_V = [&]() {
    const unsigned* dw = (const unsigned*)vreg;
    int hd0 = vh8 * 8;
#pragma unroll
    for (int j = 0; j < 8; ++j) {
      int ww = j >> 1;
      unsigned sel = (j & 1) ? 0x07060302u : 0x05040100u;
      uint2 val;
      val.x = __builtin_amdgcn_perm(dw[4 + ww], dw[0 + ww], sel);
      val.y = __builtin_amdgcn_perm(dw[12 + ww], dw[8 + ww], sel);
      int hd = hd0 + j;
      int ch = (vg >> 1) ^ ((hd ^ (hd >> 3)) & 15);
      *(uint2*)((char*)Vsm + hd * 256 + (ch << 4) + ((vg & 1) << 3)) = val;
    }
  };

  for (int pass = 0; pass < 2; ++pass) {
    const int qt = (pass == 0) ? (int)blockIdx.x : 15 - (int)blockIdx.x;
    const int q0 = qt * 128;
    const int nt = qt + 1;

    // prologue: tile-0 loads issued first (oldest in queue, max overlap)
    load_K(0);
    load_V(0);

    bf16x8 qa[4];
    {
      int row = q0 + w * 16 + lane16;
#pragma unroll
      for (int kk = 0; kk < 4; ++kk)
        qa[kk] = *(const bf16x8*)(Q + base + (size_t)row * HDD + kk * 32 + lgrp * 8);
    }

    f32x4 o[8] = {};
    float m_r[4], l_r[4];
#pragma unroll
    for (int r = 0; r < 4; ++r) { m_r[r] = NEG_INF; l_r[r] = 0.f; }

    for (int kt = 0; kt < nt; ++kt) {
      const int k0 = kt * 128;
      write_K();            // WAR-safe: prev end-barrier covered all Ksm reads
      write_V();            // regs staged during prev compute (or prologue)
      __syncthreads();      // K & V visible to all waves
      if (kt + 1 < nt) {    // prefetch next tile into regs; lands during
        load_K(k0 + 128);   // compute, drained free by end-of-compute barrier
        load_V(k0 + 128);
      }

      // ---- S = Q K^T  (logits pre-scaled via Q)
      f32x4 s[8] = {};
#pragma unroll
      for (int kk = 0; kk < 4; ++kk) {
#pragma unroll
        for (int nf = 0; nf < 8; ++nf) {
          int key = nf * 16 + lane16;
          int ch = (kk * 4 + lgrp) ^ ((key ^ (key >> 3)) & 15);
          bf16x8 kf = *(const bf16x8*)((char*)Ksm + key * 256 + (ch << 4));
          s[nf] = __builtin_amdgcn_mfma_f32_16x16x32_bf16(
              qa[kk], kf, s[nf], 0, 0, 0);
        }
      }

      // ---- causal mask (diagonal tile only; wave-uniform branch)
      if (k0 + 127 > q0 + w * 16) {
        const int rowbase = q0 + w * 16 + lgrp * 4;
#pragma unroll
        for (int nf = 0; nf < 8; ++nf) {
          int col = k0 + nf * 16 + lane16;
#pragma unroll
          for (int r = 0; r < 4; ++r)
            if (col > rowbase + r) s[nf][r] = -3.0e38f;
        }
      }

      // ---- online softmax (unconditional rescale — straight-line)
#pragma unroll
      for (int r = 0; r < 4; ++r) {
        float tm = fmaxf(fmaxf(fmaxf(s[0][r], s[1][r]), fmaxf(s[2][r], s[3][r])),
                         fmaxf(fmaxf(s[4][r], s[5][r]), fmaxf(s[6][r], s[7][r])));
        tm = fmaxf(tm, __shfl_xor(tm, 1));
        tm = fmaxf(tm, __shfl_xor(tm, 2));
        tm = fmaxf(tm, __shfl_xor(tm, 4));
        tm = fmaxf(tm, __shfl_xor(tm, 8));
        float mo = m_r[r];
        float mn = fmaxf(mo, tm);
        float alpha = exp2f((mo - mn) * L2E);
        m_r[r] = mn;
        float rs = 0.f;
#pragma unroll
        for (int nf = 0; nf < 8; ++nf) {
          float p = exp2f((s[nf][r] - mn) * L2E);
          s[nf][r] = p;
          rs += p;
        }
        rs += __shfl_xor(rs, 1);
        rs += __shfl_xor(rs, 2);
        rs += __shfl_xor(rs, 4);
        rs += __shfl_xor(rs, 8);
        l_r[r] = l_r[r] * alpha + rs;
#pragma unroll
        for (int nf = 0; nf < 8; ++nf) o[nf][r] *= alpha;
      }

      // ---- P -> LDS (per-wave region, same-wave readback; no barrier)
#pragma unroll
      for (int nf = 0; nf < 8; ++nf)
#pragma unroll
        for (int r = 0; r < 4; ++r) {
          int rl = lgrp * 4 + r;
          int ch = (2 * nf + (lane16 >> 3)) ^ ((rl ^ (rl >> 3)) & 15);
          int byte = rl * 256 + (ch << 4) + ((lane16 & 7) << 1);
          *(bf16*)((char*)&Psm[w][0] + byte) = (bf16)s[nf][r];
        }
      bf16x8 pa[4];
#pragma unroll
      for (int kk = 0; kk < 4; ++kk) {
        int ch = (kk * 4 + lgrp) ^ ((lane16 ^ (lane16 >> 3)) & 15);
        pa[kk] = *(const bf16x8*)((char*)&Psm[w][0] + lane16 * 256 + (ch << 4));
      }

      // ---- O += P V
#pragma unroll
      for (int nf = 0; nf < 8; ++nf) {
#pragma unroll
        for (int kk = 0; kk < 4; ++kk) {
          int hd = nf * 16 + lane16;
          int ch = (kk * 4 + lgrp) ^ ((hd ^ (hd >> 3)) & 15);
          bf16x8 vf = *(const bf16x8*)((char*)Vsm + hd * 256 + (ch << 4));
          o[nf] = __builtin_amdgcn_mfma_f32_16x16x32_bf16(
              pa[kk], vf, o[nf], 0, 0, 0);
        }
      }

      __syncthreads();      // all reads of Ksm/Vsm done; prefetch loads landed
    }

    // ---- finalize: O / l -> Y (b,t,D) bf16
#pragma unroll
    for (int r = 0; r < 4; ++r) {
      float inv = 1.0f / l_r[r];
      int row = q0 + w * 16 + lgrp * 4 + r;
#pragma unroll
      for (int nf = 0; nf < 8; ++nf) {
        int hd = nf * 16 + lane16;
        Y[(size_t)(b * TT + row) * DM + h * HDD + hd] = (bf16)(o[nf][r] * inv);
      }
    }
  }
}

// ---------------------------------------------------------------- launch
extern "C" void kernel_launch(void* const* d_in, const int* in_sizes, int n_in,
                              void* d_out, int out_size, void* d_ws, size_t ws_size,
                              hipStream_t stream) {
  const float* x = (const float*)d_in[0];
  const float* Wqkv = (const float*)d_in[2];
  const float* bqkv = (const float*)d_in[3];
  const float* Wproj = (const float*)d_in[4];
  const float* bproj = (const float*)d_in[5];
  float* out = (float*)d_out;

  char* ws = (char*)d_ws;
  bf16* xb = (bf16*)ws;                 ws += (size_t)MM * DM * 2;
  bf16* Wqkvt = (bf16*)ws;              ws += (size_t)NQKV * DM * 2;
  bf16* Wprojt = (bf16*)ws;             ws += (size_t)DM * DM * 2;
  bf16* kb = (bf16*)ws;                 ws += (size_t)MM * DM * 2;
  bf16* vb = (bf16*)ws;                 ws += (size_t)MM * DM * 2;
  float* cosT = (float*)ws;             ws += (size_t)TT * 64 * 4;
  float* sinT = (float*)ws;             ws += (size_t)TT * 64 * 4;
  bf16* qb = (bf16*)d_out;              // q lives in d_out (overwritten by proj)
  bf16* yb = xb;                        // xb dead after QKV GEMM

  rope_table_k<<<dim3(512), dim3(256), 0, stream>>>(cosT, sinT);
  convert_x_k<<<dim3(4096), dim3(256), 0, stream>>>(x, xb);
  transpose_w_k<<<dim3(96, 32), dim3(256), 0, stream>>>(Wqkv, Wqkvt, DM, NQKV);
  transpose_w_k<<<dim3(32, 32), dim3(256), 0, stream>>>(Wproj, Wprojt, DM, DM);

  gemm8_qkv_k<<<dim3(16, 32), dim3(512), 0, stream>>>(
      xb, Wqkvt, bqkv, qb, kb, vb, MM, NQKV, DM);

  rope_apply_k<true><<<dim3(4096), dim3(256), 0, stream>>>(qb, cosT, sinT);
  rope_apply_k<false><<<dim3(4096), dim3(256), 0, stream>>>(kb, cosT, sinT);

  attn_k<<<dim3(8, 32), dim3(512), 0, stream>>>(qb, kb, vb, yb);

  gemm4_proj_k<<<dim3(16, 16), dim3(512), 0, stream>>>(
      yb, Wprojt, bproj, out, MM, DM, DM);
}

// Round 15
// 285.452 us; speedup vs baseline: 1.0478x; 1.0478x over previous
//
#include <hip/hip_runtime.h>
#include <hip/hip_bf16.h>
#include <stdint.h>
#include <stddef.h>

typedef __bf16 bf16;
typedef __attribute__((ext_vector_type(8))) __bf16 bf16x8;
typedef __attribute__((ext_vector_type(4))) __bf16 bf16x4;
typedef __attribute__((ext_vector_type(4))) float f32x4;

#define DM 2048      // model dim
#define NH 16        // heads
#define HDD 128      // head dim
#define BB 2         // batch
#define TT 2048      // seq len
#define MM (BB*TT)   // 4096 rows
#define NQKV (3*DM)  // 6144

#define L2E 1.4426950408889634f
#define ATT_SCALE 0.08838834764831845f   // 1/sqrt(128), folded into Q at RoPE
#define NEG_INF (-__builtin_inff())

static_assert(sizeof(bf16x8) == 16, "bf16x8 must be 16B");

#define SB0() __builtin_amdgcn_sched_barrier(0)
#define WAITV0() { asm volatile("s_waitcnt vmcnt(0)" ::: "memory"); SB0(); }
#define WAITL0() { asm volatile("s_waitcnt lgkmcnt(0)" ::: "memory"); SB0(); }
#define BARRIER8() { SB0(); __builtin_amdgcn_s_barrier(); SB0(); }

// ---------------------------------------------------------------- helpers
static __device__ __forceinline__ void gload_lds16(const void* g, void* l) {
  __builtin_amdgcn_global_load_lds(
      (__attribute__((address_space(1))) void*)g,
      (__attribute__((address_space(3))) void*)l, 16, 0, 0);
}

// ---------------------------------------------------------------- pre-pass
__global__ __launch_bounds__(256) void rope_table_k(float* __restrict__ cT,
                                                    float* __restrict__ sT) {
  int id = blockIdx.x * 256 + threadIdx.x;          // < 2048*64
  int t = id >> 6, i = id & 63;
  float freq = powf(10000.0f, -(float)i * (1.0f / 64.0f));
  float theta = (float)t * freq;
  float s, c;
  __sincosf(theta, &s, &c);
  cT[id] = c;
  sT[id] = s;
}

__global__ __launch_bounds__(256) void convert_x_k(const float* __restrict__ x,
                                                   bf16* __restrict__ xb) {
  size_t id = (size_t)blockIdx.x * 256 + threadIdx.x;
  size_t o = id * 8;
  float4 a = *(const float4*)(x + o);
  float4 b = *(const float4*)(x + o + 4);
  bf16x8 r;
  r[0] = (bf16)a.x; r[1] = (bf16)a.y; r[2] = (bf16)a.z; r[3] = (bf16)a.w;
  r[4] = (bf16)b.x; r[5] = (bf16)b.y; r[6] = (bf16)b.z; r[7] = (bf16)b.w;
  *(bf16x8*)(xb + o) = r;
}

// W (K x N) f32 -> Wt (N x K) bf16, 64x64 tiles
__global__ __launch_bounds__(256) void transpose_w_k(const float* __restrict__ W,
                                                     bf16* __restrict__ Wt,
                                                     int K, int N) {
  __shared__ float tile[64][65];
  int n0 = blockIdx.x * 64, k0 = blockIdx.y * 64;
  int t = threadIdx.x;
#pragma unroll
  for (int i = 0; i < 16; ++i) {
    int idx = t + i * 256;
    int r = idx >> 6, c = idx & 63;
    tile[r][c] = W[(size_t)(k0 + r) * N + n0 + c];
  }
  __syncthreads();
#pragma unroll
  for (int i = 0; i < 16; ++i) {
    int idx = t + i * 256;
    int r = idx >> 6, c = idx & 63;
    Wt[(size_t)(n0 + r) * K + k0 + c] = (bf16)tile[c][r];
  }
}

// in-place RoPE on (b,h,t,hd) bf16 buffer; SC folds ATT_SCALE (for Q)
template <bool SC>
__global__ __launch_bounds__(256) void rope_apply_k(bf16* __restrict__ buf,
                                                    const float* __restrict__ cT,
                                                    const float* __restrict__ sT) {
  int id = blockIdx.x * 256 + threadIdx.x;   // < 32*2048*16
  int i4 = id & 15;
  int t = (id >> 4) & 2047;
  int bh = id >> 15;
  int idx0 = i4 * 4;
  size_t base = ((size_t)bh * TT + t) * HDD;
  bf16x4 x1 = *(const bf16x4*)(buf + base + idx0);
  bf16x4 x2 = *(const bf16x4*)(buf + base + 64 + idx0);
  float4 ct = *(const float4*)(cT + t * 64 + idx0);
  float4 st = *(const float4*)(sT + t * 64 + idx0);
  bf16x4 o1, o2;
  float c0, s0, a, b2;
  const float scl = SC ? ATT_SCALE : 1.0f;
#pragma unroll
  for (int j = 0; j < 4; ++j) {
    c0 = (j == 0) ? ct.x : (j == 1) ? ct.y : (j == 2) ? ct.z : ct.w;
    s0 = (j == 0) ? st.x : (j == 1) ? st.y : (j == 2) ? st.z : st.w;
    a = (float)x1[j];
    b2 = (float)x2[j];
    o1[j] = (bf16)((a * c0 - b2 * s0) * scl);
    o2[j] = (bf16)((a * s0 + b2 * c0) * scl);
  }
  *(bf16x4*)(buf + base + idx0) = o1;
  *(bf16x4*)(buf + base + 64 + idx0) = o2;
}

// ---------------------------------------------------------------- GEMM (QKV, 2-barrier 256x192)
// 512 thr = 8 waves (2M x 4N); per-wave output 128x48; BK=64; 112KB LDS dbuf.
// R15: phase barriers removed — hazard analysis shows only 2 are needed:
// loop-top WAITV0+BAR (cross-wave gload_lds visibility) and post-read BAR
// (all waves' buf[cur] reads done before t+1 issues t+2 stages into it).
// Stages of t+1 (into buf^1) fly across the MFMA block, drained at next top.
#define MFMA_Q(MF0, NF0, NCNT)                                             \
  do {                                                                     \
    __builtin_amdgcn_s_setprio(1);                                         \
    _Pragma("unroll") for (int mf = 0; mf < 4; ++mf)                       \
    _Pragma("unroll") for (int nf = 0; nf < (NCNT); ++nf)                  \
    _Pragma("unroll") for (int kk = 0; kk < 2; ++kk)                       \
      acc[(MF0) + mf][(NF0) + nf] = __builtin_amdgcn_mfma_f32_16x16x32_bf16( \
          af[(MF0) + mf][kk], bfr[(NF0) + nf][kk], acc[(MF0) + mf][(NF0) + nf], 0, 0, 0); \
    __builtin_amdgcn_s_setprio(0);                                         \
  } while (0)

__global__ __launch_bounds__(512, 2) void gemm8_qkv_k(
    const bf16* __restrict__ A, const bf16* __restrict__ Bt,
    const float* __restrict__ bias,
    bf16* __restrict__ q_out, bf16* __restrict__ k_out, bf16* __restrict__ v_out,
    int M, int N, int K) {
  __shared__ __align__(16) char Lsm[2][57344];   // [buf][A:32KB | B:24KB]
  const int tid = threadIdx.x;
  const int wid = tid >> 6, l = tid & 63;
  const int lane16 = l & 15, lgrp = l >> 4;
  const int wm = wid >> 2, wn = wid & 3;

  int flat = blockIdx.y * gridDim.x + blockIdx.x;
  {
    const int cpx = (gridDim.x * gridDim.y) >> 3;
    flat = (flat & 7) * cpx + (flat >> 3);
  }
  const int bm = flat % gridDim.x;       // 0..15  (M/256)
  const int bn = flat / gridDim.x;       // 0..31  (N/192)
  const int NT = K >> 6;

  const int schunk = (l & 7) ^ ((l >> 3) & 7);
  const bf16* gA = A + (size_t)(bm * 256 + wid * 8 + (l >> 3)) * K + schunk * 8;
  const bf16* gB = Bt + (size_t)(bn * 192 + wid * 8 + (l >> 3)) * K + schunk * 8;

  auto stage_unit = [&](int mat, int t, int u, int buf) {
    const bf16* g = (mat ? gB : gA) + (size_t)(u * 64) * K + t * 64;
    gload_lds16(g, &Lsm[buf][(mat ? 32768 : 0) + u * 8192 + wid * 1024]);
  };

  f32x4 acc[8][3] = {};

#pragma unroll
  for (int u = 0; u < 4; ++u) stage_unit(0, 0, u, 0);
#pragma unroll
  for (int u = 0; u < 3; ++u) stage_unit(1, 0, u, 0);

  for (int t = 0; t < NT; ++t) {
    const int cur = t & 1;
    const char* As = &Lsm[cur][0];
    const char* Bs = &Lsm[cur][32768];
    bf16x8 af[8][2], bfr[3][2];

    WAITV0();                 // this tile's 7 stage loads landed (my wave's)
    BARRIER8();               // visible to all waves

    // ---- read all frags (ds_read) + stage t+1 (gload_lds -> buf^1)
#pragma unroll
    for (int mf = 0; mf < 8; ++mf)
#pragma unroll
      for (int kk = 0; kk < 2; ++kk) {
        int row = wm * 128 + mf * 16 + lane16;
        int ch = (kk * 4 + lgrp) ^ (lane16 & 7);
        af[mf][kk] = *(const bf16x8*)(As + row * 128 + ch * 16);
      }
#pragma unroll
    for (int nf = 0; nf < 3; ++nf)
#pragma unroll
      for (int kk = 0; kk < 2; ++kk) {
        int row = wn * 48 + nf * 16 + lane16;
        int ch = (kk * 4 + lgrp) ^ (lane16 & 7);
        bfr[nf][kk] = *(const bf16x8*)(Bs + row * 128 + ch * 16);
      }
    if (t + 1 < NT) {
#pragma unroll
      for (int u = 0; u < 4; ++u) stage_unit(0, t + 1, u, cur ^ 1);
#pragma unroll
      for (int u = 0; u < 3; ++u) stage_unit(1, t + 1, u, cur ^ 1);
    }
    WAITL0();                 // my reads of buf[cur] complete
    BARRIER8();               // all waves' reads complete -> t+2 may overwrite

    // ---- all 48 MFMA (stages of t+1 in flight underneath)
    MFMA_Q(0, 0, 3);
    MFMA_Q(4, 0, 3);
  }

  // ---- epilogue
#pragma unroll
  for (int nf = 0; nf < 3; ++nf) {
    int colg = bn * 192 + wn * 48 + nf * 16 + lane16;
    int which = colg >> 11;
    bf16* outb = (which == 0) ? q_out : (which == 1 ? k_out : v_out);
    int head = (colg >> 7) & 15, hd = colg & 127;
    float bv = bias[colg];
#pragma unroll
    for (int mf = 0; mf < 8; ++mf)
#pragma unroll
      for (int r = 0; r < 4; ++r) {
        int row = bm * 256 + wm * 128 + mf * 16 + lgrp * 4 + r;
        int bb = row >> 11, tt2 = row & 2047;
        outb[((size_t)(bb * NH + head) * TT + tt2) * HDD + hd] =
            (bf16)(acc[mf][nf][r] + bv);
      }
  }
}

// ---------------------------------------------------------------- GEMM (proj, 2-barrier 256x128)
__global__ __launch_bounds__(512, 2) void gemm4_proj_k(
    const bf16* __restrict__ A, const bf16* __restrict__ Bt,
    const float* __restrict__ bias, float* __restrict__ c_out,
    int M, int N, int K) {
  __shared__ __align__(16) char Lsm[2][49152];   // [buf][A:32KB | B:16KB]
  const int tid = threadIdx.x;
  const int wid = tid >> 6, l = tid & 63;
  const int lane16 = l & 15, lgrp = l >> 4;
  const int wm = wid >> 2, wn = wid & 3;

  int flat = blockIdx.y * gridDim.x + blockIdx.x;
  {
    const int cpx = (gridDim.x * gridDim.y) >> 3;
    flat = (flat & 7) * cpx + (flat >> 3);
  }
  const int bm = flat % gridDim.x;       // 0..15 (M/256)
  const int bn = flat / gridDim.x;       // 0..15 (N/128)
  const int NT = K >> 6;

  const int schunk = (l & 7) ^ ((l >> 3) & 7);
  const bf16* gA = A + (size_t)(bm * 256 + wid * 8 + (l >> 3)) * K + schunk * 8;
  const bf16* gB = Bt + (size_t)(bn * 128 + wid * 8 + (l >> 3)) * K + schunk * 8;

  auto stage_unit = [&](int mat, int t, int u, int buf) {
    const bf16* g = (mat ? gB : gA) + (size_t)(u * 64) * K + t * 64;
    gload_lds16(g, &Lsm[buf][(mat ? 32768 : 0) + u * 8192 + wid * 1024]);
  };

  f32x4 acc[8][2] = {};

#pragma unroll
  for (int u = 0; u < 4; ++u) stage_unit(0, 0, u, 0);
#pragma unroll
  for (int u = 0; u < 2; ++u) stage_unit(1, 0, u, 0);

  for (int t = 0; t < NT; ++t) {
    const int cur = t & 1;
    const char* As = &Lsm[cur][0];
    const char* Bs = &Lsm[cur][32768];
    bf16x8 af[8][2], bfr[2][2];

    WAITV0();
    BARRIER8();

    // ---- read all frags + stage t+1
#pragma unroll
    for (int mf = 0; mf < 8; ++mf)
#pragma unroll
      for (int kk = 0; kk < 2; ++kk) {
        int row = wm * 128 + mf * 16 + lane16;
        int ch = (kk * 4 + lgrp) ^ (lane16 & 7);
        af[mf][kk] = *(const bf16x8*)(As + row * 128 + ch * 16);
      }
#pragma unroll
    for (int nf = 0; nf < 2; ++nf)
#pragma unroll
      for (int kk = 0; kk < 2; ++kk) {
        int row = wn * 32 + nf * 16 + lane16;
        int ch = (kk * 4 + lgrp) ^ (lane16 & 7);
        bfr[nf][kk] = *(const bf16x8*)(Bs + row * 128 + ch * 16);
      }
    if (t + 1 < NT) {
#pragma unroll
      for (int u = 0; u < 4; ++u) stage_unit(0, t + 1, u, cur ^ 1);
#pragma unroll
      for (int u = 0; u < 2; ++u) stage_unit(1, t + 1, u, cur ^ 1);
    }
    WAITL0();
    BARRIER8();

    // ---- all 32 MFMA
    MFMA_Q(0, 0, 2);
    MFMA_Q(4, 0, 2);
  }

  // ---- epilogue: bias + f32 row-major store
#pragma unroll
  for (int nf = 0; nf < 2; ++nf) {
    int colg = bn * 128 + wn * 32 + nf * 16 + lane16;
    float bv = bias[colg];
#pragma unroll
    for (int mf = 0; mf < 8; ++mf)
#pragma unroll
      for (int r = 0; r < 4; ++r) {
        int row = bm * 256 + wm * 128 + mf * 16 + lgrp * 4 + r;
        c_out[(size_t)row * N + colg] = acc[mf][nf][r] + bv;
      }
  }
}

// ---------------------------------------------------------------- attention
// R13-proven version (115.4us, best): grid (8, B*H), 8 waves; q-tiles
// {bx, 15-bx}, 17 K-tiles/block, 1 block/CU. 4-bit swizzle on K/V/P.
// K via gload_lds (single buffer), V reg-staged+perm-transposed,
// __syncthreads-fenced. Q pre-scaled; unconditional softmax rescale.
// Retired: cross-tile gload prefetch (R8/R10), reg-staged K (R14 conflicts),
// defer-max (R12 spills).
__global__ __launch_bounds__(512, 2) void attn_k(
    const bf16* __restrict__ Q, const bf16* __restrict__ Kt,
    const bf16* __restrict__ V, bf16* __restrict__ Y) {
  __shared__ __align__(16) bf16 Ksm[128 * 128];   // [key][hd], chunk^=g4(key), 32KB
  __shared__ __align__(16) bf16 Vsm[128 * 128];   // [hd][key], chunk^=g4(hd), 32KB
  __shared__ __align__(16) bf16 Psm[8][16 * 128]; // per-wave P, chunk^=g4(row), 32KB
  const int tid = threadIdx.x, w = tid >> 6, l = tid & 63;
  const int lane16 = l & 15, lgrp = l >> 4;
  const int bh = blockIdx.y;
  const int b = bh >> 4, h = bh & 15;
  const size_t base = (size_t)bh * TT * HDD;

  uint4 vreg[4];
  const int vg = tid >> 4, vh8 = tid & 15;

  auto load_V = [&](int k0) {
#pragma unroll
    for (int kq = 0; kq < 4; ++kq)
      vreg[kq] = *(const uint4*)(V + base + (size_t)(k0 + vg * 4 + kq) * HDD + vh8 * 8);
  };
  auto issue_K = [&](int k0) {
#pragma unroll
    for (int i = 0; i < 4; ++i) {
      int key = w * 16 + i * 4 + (l >> 4);
      int c = (l & 15) ^ ((key ^ (key >> 3)) & 15);
      gload_lds16(Kt + base + (size_t)(k0 + key) * HDD + c * 8,
                  &Ksm[(w * 16 + i * 4) * 128 + (l & 15) * 8]);
    }
  };
  auto write_V = [&]() {
    const unsigned* dw = (const unsigned*)vreg;
    int hd0 = vh8 * 8;
#pragma unroll
    for (int j = 0; j < 8; ++j) {
      int ww = j >> 1;
      unsigned sel = (j & 1) ? 0x07060302u : 0x05040100u;
      uint2 val;
      val.x = __builtin_amdgcn_perm(dw[4 + ww], dw[0 + ww], sel);
      val.y = __builtin_amdgcn_perm(dw[12 + ww], dw[8 + ww], sel);
      int hd = hd0 + j;
      int ch = (vg >> 1) ^ ((hd ^ (hd >> 3)) & 15);
      *(uint2*)((char*)Vsm + hd * 256 + (ch << 4) + ((vg & 1) << 3)) = val;
    }
  };

  for (int pass = 0; pass < 2; ++pass) {
    const int qt = (pass == 0) ? (int)blockIdx.x : 15 - (int)blockIdx.x;
    const int q0 = qt * 128;
    const int nt = qt + 1;

    bf16x8 qa[4];
    {
      int row = q0 + w * 16 + lane16;
#pragma unroll
      for (int kk = 0; kk < 4; ++kk)
        qa[kk] = *(const bf16x8*)(Q + base + (size_t)row * HDD + kk * 32 + lgrp * 8);
    }

    f32x4 o[8] = {};
    float m_r[4], l_r[4];
#pragma unroll
    for (int r = 0; r < 4; ++r) { m_r[r] = NEG_INF; l_r[r] = 0.f; }

    for (int kt = 0; kt < nt; ++kt) {
      const int k0 = kt * 128;
      load_V(k0);           // V loads first (oldest in vmcnt queue)
      issue_K(k0);          // K direct-to-LDS, in flight during V repack
      write_V();            // waits only the 4 V loads; WAR safe (prev barrier)
      __syncthreads();      // drains vmcnt+lgkmcnt: K & V staged for all waves

      // ---- S = Q K^T  (logits pre-scaled via Q)
      f32x4 s[8] = {};
#pragma unroll
      for (int kk = 0; kk < 4; ++kk) {
#pragma unroll
        for (int nf = 0; nf < 8; ++nf) {
          int key = nf * 16 + lane16;
          int ch = (kk * 4 + lgrp) ^ ((key ^ (key >> 3)) & 15);
          bf16x8 kf = *(const bf16x8*)((char*)Ksm + key * 256 + (ch << 4));
          s[nf] = __builtin_amdgcn_mfma_f32_16x16x32_bf16(
              qa[kk], kf, s[nf], 0, 0, 0);
        }
      }

      // ---- causal mask (diagonal tile only; wave-uniform branch)
      if (k0 + 127 > q0 + w * 16) {
        const int rowbase = q0 + w * 16 + lgrp * 4;
#pragma unroll
        for (int nf = 0; nf < 8; ++nf) {
          int col = k0 + nf * 16 + lane16;
#pragma unroll
          for (int r = 0; r < 4; ++r)
            if (col > rowbase + r) s[nf][r] = -3.0e38f;
        }
      }

      // ---- online softmax (unconditional rescale — straight-line)
#pragma unroll
      for (int r = 0; r < 4; ++r) {
        float tm = fmaxf(fmaxf(fmaxf(s[0][r], s[1][r]), fmaxf(s[2][r], s[3][r])),
                         fmaxf(fmaxf(s[4][r], s[5][r]), fmaxf(s[6][r], s[7][r])));
        tm = fmaxf(tm, __shfl_xor(tm, 1));
        tm = fmaxf(tm, __shfl_xor(tm, 2));
        tm = fmaxf(tm, __shfl_xor(tm, 4));
        tm = fmaxf(tm, __shfl_xor(tm, 8));
        float mo = m_r[r];
        float mn = fmaxf(mo, tm);
        float alpha = exp2f((mo - mn) * L2E);
        m_r[r] = mn;
        float rs = 0.f;
#pragma unroll
        for (int nf = 0; nf < 8; ++nf) {
          float p = exp2f((s[nf][r] - mn) * L2E);
          s[nf][r] = p;
          rs += p;
        }
        rs += __shfl_xor(rs, 1);
        rs += __shfl_xor(rs, 2);
        rs += __shfl_xor(rs, 4);
        rs += __shfl_xor(rs, 8);
        l_r[r] = l_r[r] * alpha + rs;
#pragma unroll
        for (int nf = 0; nf < 8; ++nf) o[nf][r] *= alpha;
      }

      // ---- P -> LDS (per-wave region, same-wave readback; no barrier)
#pragma unroll
      for (int nf = 0; nf < 8; ++nf)
#pragma unroll
        for (int r = 0; r < 4; ++r) {
          int rl = lgrp * 4 + r;
          int ch = (2 * nf + (lane16 >> 3)) ^ ((rl ^ (rl >> 3)) & 15);
          int byte = rl * 256 + (ch << 4) + ((lane16 & 7) << 1);
          *(bf16*)((char*)&Psm[w][0] + byte) = (bf16)s[nf][r];
        }
      bf16x8 pa[4];
#pragma unroll
      for (int kk = 0; kk < 4; ++kk) {
        int ch = (kk * 4 + lgrp) ^ ((lane16 ^ (lane16 >> 3)) & 15);
        pa[kk] = *(const bf16x8*)((char*)&Psm[w][0] + lane16 * 256 + (ch << 4));
      }

      // ---- O += P V
#pragma unroll
      for (int nf = 0; nf < 8; ++nf) {
#pragma unroll
        for (int kk = 0; kk < 4; ++kk) {
          int hd = nf * 16 + lane16;
          int ch = (kk * 4 + lgrp) ^ ((hd ^ (hd >> 3)) & 15);
          bf16x8 vf = *(const bf16x8*)((char*)Vsm + hd * 256 + (ch << 4));
          o[nf] = __builtin_amdgcn_mfma_f32_16x16x32_bf16(
              pa[kk], vf, o[nf], 0, 0, 0);
        }
      }

      __syncthreads();      // all waves done reading Ksm/Vsm before next stage
    }

    // ---- finalize: O / l -> Y (b,t,D) bf16
#pragma unroll
    for (int r = 0; r < 4; ++r) {
      float inv = 1.0f / l_r[r];
      int row = q0 + w * 16 + lgrp * 4 + r;
#pragma unroll
      for (int nf = 0; nf < 8; ++nf) {
        int hd = nf * 16 + lane16;
        Y[(size_t)(b * TT + row) * DM + h * HDD + hd] = (bf16)(o[nf][r] * inv);
      }
    }
  }
}

// ---------------------------------------------------------------- launch
extern "C" void kernel_launch(void* const* d_in, const int* in_sizes, int n_in,
                              void* d_out, int out_size, void* d_ws, size_t ws_size,
                              hipStream_t stream) {
  const float* x = (const float*)d_in[0];
  const float* Wqkv = (const float*)d_in[2];
  const float* bqkv = (const float*)d_in[3];
  const float* Wproj = (const float*)d_in[4];
  const float* bproj = (const float*)d_in[5];
  float* out = (float*)d_out;

  char* ws = (char*)d_ws;
  bf16* xb = (bf16*)ws;                 ws += (size_t)MM * DM * 2;
  bf16* Wqkvt = (bf16*)ws;              ws += (size_t)NQKV * DM * 2;
  bf16* Wprojt = (bf16*)ws;             ws += (size_t)DM * DM * 2;
  bf16* kb = (bf16*)ws;                 ws += (size_t)MM * DM * 2;
  bf16* vb = (bf16*)ws;                 ws += (size_t)MM * DM * 2;
  float* cosT = (float*)ws;             ws += (size_t)TT * 64 * 4;
  float* sinT = (float*)ws;             ws += (size_t)TT * 64 * 4;
  bf16* qb = (bf16*)d_out;              // q lives in d_out (overwritten by proj)
  bf16* yb = xb;                        // xb dead after QKV GEMM

  rope_table_k<<<dim3(512), dim3(256), 0, stream>>>(cosT, sinT);
  convert_x_k<<<dim3(4096), dim3(256), 0, stream>>>(x, xb);
  transpose_w_k<<<dim3(96, 32), dim3(256), 0, stream>>>(Wqkv, Wqkvt, DM, NQKV);
  transpose_w_k<<<dim3(32, 32), dim3(256), 0, stream>>>(Wproj, Wprojt, DM, DM);

  gemm8_qkv_k<<<dim3(16, 32), dim3(512), 0, stream>>>(
      xb, Wqkvt, bqkv, qb, kb, vb, MM, NQKV, DM);

  rope_apply_k<true><<<dim3(4096), dim3(256), 0, stream>>>(qb, cosT, sinT);
  rope_apply_k<false><<<dim3(4096), dim3(256), 0, stream>>>(kb, cosT, sinT);

  attn_k<<<dim3(8, 32), dim3(512), 0, stream>>>(qb, kb, vb, yb);

  gemm4_proj_k<<<dim3(16, 16), dim3(512), 0, stream>>>(
      yb, Wprojt, bproj, out, MM, DM, DM);
}

// Round 16
// 278.048 us; speedup vs baseline: 1.0757x; 1.0266x over previous
//
#include <hip/hip_runtime.h>
#include <hip/hip_bf16.h>
#include <stdint.h>
#include <stddef.h>

typedef __bf16 bf16;
typedef __attribute__((ext_vector_type(8))) __bf16 bf16x8;
typedef __attribute__((ext_vector_type(4))) __bf16 bf16x4;
typedef __attribute__((ext_vector_type(4))) float f32x4;

#define DM 2048      // model dim
#define NH 16        // heads
#define HDD 128      // head dim
#define BB 2         // batch
#define TT 2048      // seq len
#define MM (BB*TT)   // 4096 rows
#define NQKV (3*DM)  // 6144

#define L2E 1.4426950408889634f
#define ATT_SCALE 0.08838834764831845f   // 1/sqrt(128), folded into Q at RoPE
#define NEG_INF (-__builtin_inff())

static_assert(sizeof(bf16x8) == 16, "bf16x8 must be 16B");

#define SB0() __builtin_amdgcn_sched_barrier(0)
#define WAITV0() { asm volatile("s_waitcnt vmcnt(0)" ::: "memory"); SB0(); }
#define WAITL0() { asm volatile("s_waitcnt lgkmcnt(0)" ::: "memory"); SB0(); }
#define BARRIER8() { SB0(); __builtin_amdgcn_s_barrier(); SB0(); }

// ---------------------------------------------------------------- helpers
static __device__ __forceinline__ void gload_lds16(const void* g, void* l) {
  __builtin_amdgcn_global_load_lds(
      (__attribute__((address_space(1))) void*)g,
      (__attribute__((address_space(3))) void*)l, 16, 0, 0);
}

// ---------------------------------------------------------------- pre-pass
__global__ __launch_bounds__(256) void rope_table_k(float* __restrict__ cT,
                                                    float* __restrict__ sT) {
  int id = blockIdx.x * 256 + threadIdx.x;          // < 2048*64
  int t = id >> 6, i = id & 63;
  float freq = powf(10000.0f, -(float)i * (1.0f / 64.0f));
  float theta = (float)t * freq;
  float s, c;
  __sincosf(theta, &s, &c);
  cT[id] = c;
  sT[id] = s;
}

__global__ __launch_bounds__(256) void convert_x_k(const float* __restrict__ x,
                                                   bf16* __restrict__ xb) {
  size_t id = (size_t)blockIdx.x * 256 + threadIdx.x;
  size_t o = id * 8;
  float4 a = *(const float4*)(x + o);
  float4 b = *(const float4*)(x + o + 4);
  bf16x8 r;
  r[0] = (bf16)a.x; r[1] = (bf16)a.y; r[2] = (bf16)a.z; r[3] = (bf16)a.w;
  r[4] = (bf16)b.x; r[5] = (bf16)b.y; r[6] = (bf16)b.z; r[7] = (bf16)b.w;
  *(bf16x8*)(xb + o) = r;
}

// W (K x N) f32 -> Wt (N x K) bf16, 64x64 tiles
__global__ __launch_bounds__(256) void transpose_w_k(const float* __restrict__ W,
                                                     bf16* __restrict__ Wt,
                                                     int K, int N) {
  __shared__ float tile[64][65];
  int n0 = blockIdx.x * 64, k0 = blockIdx.y * 64;
  int t = threadIdx.x;
#pragma unroll
  for (int i = 0; i < 16; ++i) {
    int idx = t + i * 256;
    int r = idx >> 6, c = idx & 63;
    tile[r][c] = W[(size_t)(k0 + r) * N + n0 + c];
  }
  __syncthreads();
#pragma unroll
  for (int i = 0; i < 16; ++i) {
    int idx = t + i * 256;
    int r = idx >> 6, c = idx & 63;
    Wt[(size_t)(n0 + r) * K + k0 + c] = (bf16)tile[c][r];
  }
}

// in-place RoPE on (b,h,t,hd) bf16 buffer; SC folds ATT_SCALE (for Q)
template <bool SC>
__global__ __launch_bounds__(256) void rope_apply_k(bf16* __restrict__ buf,
                                                    const float* __restrict__ cT,
                                                    const float* __restrict__ sT) {
  int id = blockIdx.x * 256 + threadIdx.x;   // < 32*2048*16
  int i4 = id & 15;
  int t = (id >> 4) & 2047;
  int bh = id >> 15;
  int idx0 = i4 * 4;
  size_t base = ((size_t)bh * TT + t) * HDD;
  bf16x4 x1 = *(const bf16x4*)(buf + base + idx0);
  bf16x4 x2 = *(const bf16x4*)(buf + base + 64 + idx0);
  float4 ct = *(const float4*)(cT + t * 64 + idx0);
  float4 st = *(const float4*)(sT + t * 64 + idx0);
  bf16x4 o1, o2;
  float c0, s0, a, b2;
  const float scl = SC ? ATT_SCALE : 1.0f;
#pragma unroll
  for (int j = 0; j < 4; ++j) {
    c0 = (j == 0) ? ct.x : (j == 1) ? ct.y : (j == 2) ? ct.z : ct.w;
    s0 = (j == 0) ? st.x : (j == 1) ? st.y : (j == 2) ? st.z : st.w;
    a = (float)x1[j];
    b2 = (float)x2[j];
    o1[j] = (bf16)((a * c0 - b2 * s0) * scl);
    o2[j] = (bf16)((a * s0 + b2 * c0) * scl);
  }
  *(bf16x4*)(buf + base + idx0) = o1;
  *(bf16x4*)(buf + base + 64 + idx0) = o2;
}

// ---------------------------------------------------------------- GEMM (QKV, 1-barrier 256x192)
// 512 thr = 8 waves (2M x 4N); per-wave output 128x48; BK=64; 112KB LDS dbuf.
// R16: mid-tile WAITL0+BAR removed (redundant — arrival at next top BAR
// already implies all waves completed this tile's reads). One barrier/tile;
// ds_reads and MFMAs interleave via compiler lgkmcnt; stages of t+1 fly
// under the MFMA block and are drained at t+1's top WAITV0 (zero barriers
// crossed in flight).
#define MFMA_Q(MF0, NF0, NCNT)                                             \
  do {                                                                     \
    __builtin_amdgcn_s_setprio(1);                                         \
    _Pragma("unroll") for (int mf = 0; mf < 4; ++mf)                       \
    _Pragma("unroll") for (int nf = 0; nf < (NCNT); ++nf)                  \
    _Pragma("unroll") for (int kk = 0; kk < 2; ++kk)                       \
      acc[(MF0) + mf][(NF0) + nf] = __builtin_amdgcn_mfma_f32_16x16x32_bf16( \
          af[(MF0) + mf][kk], bfr[(NF0) + nf][kk], acc[(MF0) + mf][(NF0) + nf], 0, 0, 0); \
    __builtin_amdgcn_s_setprio(0);                                         \
  } while (0)

__global__ __launch_bounds__(512, 2) void gemm8_qkv_k(
    const bf16* __restrict__ A, const bf16* __restrict__ Bt,
    const float* __restrict__ bias,
    bf16* __restrict__ q_out, bf16* __restrict__ k_out, bf16* __restrict__ v_out,
    int M, int N, int K) {
  __shared__ __align__(16) char Lsm[2][57344];   // [buf][A:32KB | B:24KB]
  const int tid = threadIdx.x;
  const int wid = tid >> 6, l = tid & 63;
  const int lane16 = l & 15, lgrp = l >> 4;
  const int wm = wid >> 2, wn = wid & 3;

  int flat = blockIdx.y * gridDim.x + blockIdx.x;
  {
    const int cpx = (gridDim.x * gridDim.y) >> 3;
    flat = (flat & 7) * cpx + (flat >> 3);
  }
  const int bm = flat % gridDim.x;       // 0..15  (M/256)
  const int bn = flat / gridDim.x;       // 0..31  (N/192)
  const int NT = K >> 6;

  const int schunk = (l & 7) ^ ((l >> 3) & 7);
  const bf16* gA = A + (size_t)(bm * 256 + wid * 8 + (l >> 3)) * K + schunk * 8;
  const bf16* gB = Bt + (size_t)(bn * 192 + wid * 8 + (l >> 3)) * K + schunk * 8;

  auto stage_unit = [&](int mat, int t, int u, int buf) {
    const bf16* g = (mat ? gB : gA) + (size_t)(u * 64) * K + t * 64;
    gload_lds16(g, &Lsm[buf][(mat ? 32768 : 0) + u * 8192 + wid * 1024]);
  };

  f32x4 acc[8][3] = {};

#pragma unroll
  for (int u = 0; u < 4; ++u) stage_unit(0, 0, u, 0);
#pragma unroll
  for (int u = 0; u < 3; ++u) stage_unit(1, 0, u, 0);

  for (int t = 0; t < NT; ++t) {
    const int cur = t & 1;
    const char* As = &Lsm[cur][0];
    const char* Bs = &Lsm[cur][32768];
    bf16x8 af[8][2], bfr[3][2];

    WAITV0();                 // this tile's 7 stage loads landed (my wave's)
    BARRIER8();               // visible to all waves; prev tile fully done

    // ---- read all frags (ds_read) + stage t+1 (gload_lds -> buf^1)
#pragma unroll
    for (int mf = 0; mf < 8; ++mf)
#pragma unroll
      for (int kk = 0; kk < 2; ++kk) {
        int row = wm * 128 + mf * 16 + lane16;
        int ch = (kk * 4 + lgrp) ^ (lane16 & 7);
        af[mf][kk] = *(const bf16x8*)(As + row * 128 + ch * 16);
      }
#pragma unroll
    for (int nf = 0; nf < 3; ++nf)
#pragma unroll
      for (int kk = 0; kk < 2; ++kk) {
        int row = wn * 48 + nf * 16 + lane16;
        int ch = (kk * 4 + lgrp) ^ (lane16 & 7);
        bfr[nf][kk] = *(const bf16x8*)(Bs + row * 128 + ch * 16);
      }
    if (t + 1 < NT) {
#pragma unroll
      for (int u = 0; u < 4; ++u) stage_unit(0, t + 1, u, cur ^ 1);
#pragma unroll
      for (int u = 0; u < 3; ++u) stage_unit(1, t + 1, u, cur ^ 1);
    }

    // ---- all 48 MFMA; compiler interleaves with the ds_reads above
    MFMA_Q(0, 0, 3);
    MFMA_Q(4, 0, 3);
  }

  // ---- epilogue
#pragma unroll
  for (int nf = 0; nf < 3; ++nf) {
    int colg = bn * 192 + wn * 48 + nf * 16 + lane16;
    int which = colg >> 11;
    bf16* outb = (which == 0) ? q_out : (which == 1 ? k_out : v_out);
    int head = (colg >> 7) & 15, hd = colg & 127;
    float bv = bias[colg];
#pragma unroll
    for (int mf = 0; mf < 8; ++mf)
#pragma unroll
      for (int r = 0; r < 4; ++r) {
        int row = bm * 256 + wm * 128 + mf * 16 + lgrp * 4 + r;
        int bb = row >> 11, tt2 = row & 2047;
        outb[((size_t)(bb * NH + head) * TT + tt2) * HDD + hd] =
            (bf16)(acc[mf][nf][r] + bv);
      }
  }
}

// ---------------------------------------------------------------- GEMM (proj, 1-barrier 256x128)
__global__ __launch_bounds__(512, 2) void gemm4_proj_k(
    const bf16* __restrict__ A, const bf16* __restrict__ Bt,
    const float* __restrict__ bias, float* __restrict__ c_out,
    int M, int N, int K) {
  __shared__ __align__(16) char Lsm[2][49152];   // [buf][A:32KB | B:16KB]
  const int tid = threadIdx.x;
  const int wid = tid >> 6, l = tid & 63;
  const int lane16 = l & 15, lgrp = l >> 4;
  const int wm = wid >> 2, wn = wid & 3;

  int flat = blockIdx.y * gridDim.x + blockIdx.x;
  {
    const int cpx = (gridDim.x * gridDim.y) >> 3;
    flat = (flat & 7) * cpx + (flat >> 3);
  }
  const int bm = flat % gridDim.x;       // 0..15 (M/256)
  const int bn = flat / gridDim.x;       // 0..15 (N/128)
  const int NT = K >> 6;

  const int schunk = (l & 7) ^ ((l >> 3) & 7);
  const bf16* gA = A + (size_t)(bm * 256 + wid * 8 + (l >> 3)) * K + schunk * 8;
  const bf16* gB = Bt + (size_t)(bn * 128 + wid * 8 + (l >> 3)) * K + schunk * 8;

  auto stage_unit = [&](int mat, int t, int u, int buf) {
    const bf16* g = (mat ? gB : gA) + (size_t)(u * 64) * K + t * 64;
    gload_lds16(g, &Lsm[buf][(mat ? 32768 : 0) + u * 8192 + wid * 1024]);
  };

  f32x4 acc[8][2] = {};

#pragma unroll
  for (int u = 0; u < 4; ++u) stage_unit(0, 0, u, 0);
#pragma unroll
  for (int u = 0; u < 2; ++u) stage_unit(1, 0, u, 0);

  for (int t = 0; t < NT; ++t) {
    const int cur = t & 1;
    const char* As = &Lsm[cur][0];
    const char* Bs = &Lsm[cur][32768];
    bf16x8 af[8][2], bfr[2][2];

    WAITV0();
    BARRIER8();

    // ---- read all frags + stage t+1
#pragma unroll
    for (int mf = 0; mf < 8; ++mf)
#pragma unroll
      for (int kk = 0; kk < 2; ++kk) {
        int row = wm * 128 + mf * 16 + lane16;
        int ch = (kk * 4 + lgrp) ^ (lane16 & 7);
        af[mf][kk] = *(const bf16x8*)(As + row * 128 + ch * 16);
      }
#pragma unroll
    for (int nf = 0; nf < 2; ++nf)
#pragma unroll
      for (int kk = 0; kk < 2; ++kk) {
        int row = wn * 32 + nf * 16 + lane16;
        int ch = (kk * 4 + lgrp) ^ (lane16 & 7);
        bfr[nf][kk] = *(const bf16x8*)(Bs + row * 128 + ch * 16);
      }
    if (t + 1 < NT) {
#pragma unroll
      for (int u = 0; u < 4; ++u) stage_unit(0, t + 1, u, cur ^ 1);
#pragma unroll
      for (int u = 0; u < 2; ++u) stage_unit(1, t + 1, u, cur ^ 1);
    }

    // ---- all 32 MFMA
    MFMA_Q(0, 0, 2);
    MFMA_Q(4, 0, 2);
  }

  // ---- epilogue: bias + f32 row-major store
#pragma unroll
  for (int nf = 0; nf < 2; ++nf) {
    int colg = bn * 128 + wn * 32 + nf * 16 + lane16;
    float bv = bias[colg];
#pragma unroll
    for (int mf = 0; mf < 8; ++mf)
#pragma unroll
      for (int r = 0; r < 4; ++r) {
        int row = bm * 256 + wm * 128 + mf * 16 + lgrp * 4 + r;
        c_out[(size_t)row * N + colg] = acc[mf][nf][r] + bv;
      }
  }
}

// ---------------------------------------------------------------- attention
// R13-proven version (115.4us, best): grid (8, B*H), 8 waves; q-tiles
// {bx, 15-bx}, 17 K-tiles/block, 1 block/CU. 4-bit swizzle on K/V/P.
// K via gload_lds (single buffer), V reg-staged+perm-transposed,
// __syncthreads-fenced. Q pre-scaled; unconditional softmax rescale.
// Retired: cross-tile gload prefetch (R8/R10), reg-staged K (R14 conflicts),
// defer-max (R12 spills).
__global__ __launch_bounds__(512, 2) void attn_k(
    const bf16* __restrict__ Q, const bf16* __restrict__ Kt,
    const bf16* __restrict__ V, bf16* __restrict__ Y) {
  __shared__ __align__(16) bf16 Ksm[128 * 128];   // [key][hd], chunk^=g4(key), 32KB
  __shared__ __align__(16) bf16 Vsm[128 * 128];   // [hd][key], chunk^=g4(hd), 32KB
  __shared__ __align__(16) bf16 Psm[8][16 * 128]; // per-wave P, chunk^=g4(row), 32KB
  const int tid = threadIdx.x, w = tid >> 6, l = tid & 63;
  const int lane16 = l & 15, lgrp = l >> 4;
  const int bh = blockIdx.y;
  const int b = bh >> 4, h = bh & 15;
  const size_t base = (size_t)bh * TT * HDD;

  uint4 vreg[4];
  const int vg = tid >> 4, vh8 = tid & 15;

  auto load_V = [&](int k0) {
#pragma unroll
    for (int kq = 0; kq < 4; ++kq)
      vreg[kq] = *(const uint4*)(V + base + (size_t)(k0 + vg * 4 + kq) * HDD + vh8 * 8);
  };
  auto issue_K = [&](int k0) {
#pragma unroll
    for (int i = 0; i < 4; ++i) {
      int key = w * 16 + i * 4 + (l >> 4);
      int c = (l & 15) ^ ((key ^ (key >> 3)) & 15);
      gload_lds16(Kt + base + (size_t)(k0 + key) * HDD + c * 8,
                  &Ksm[(w * 16 + i * 4) * 128 + (l & 15) * 8]);
    }
  };
  auto write_V = [&]() {
    const unsigned* dw = (const unsigned*)vreg;
    int hd0 = vh8 * 8;
#pragma unroll
    for (int j = 0; j < 8; ++j) {
      int ww = j >> 1;
      unsigned sel = (j & 1) ? 0x07060302u : 0x05040100u;
      uint2 val;
      val.x = __builtin_amdgcn_perm(dw[4 + ww], dw[0 + ww], sel);
      val.y = __builtin_amdgcn_perm(dw[12 + ww], dw[8 + ww], sel);
      int hd = hd0 + j;
      int ch = (vg >> 1) ^ ((hd ^ (hd >> 3)) & 15);
      *(uint2*)((char*)Vsm + hd * 256 + (ch << 4) + ((vg & 1) << 3)) = val;
    }
  };

  for (int pass = 0; pass < 2; ++pass) {
    const int qt = (pass == 0) ? (int)blockIdx.x : 15 - (int)blockIdx.x;
    const int q0 = qt * 128;
    const int nt = qt + 1;

    bf16x8 qa[4];
    {
      int row = q0 + w * 16 + lane16;
#pragma unroll
      for (int kk = 0; kk < 4; ++kk)
        qa[kk] = *(const bf16x8*)(Q + base + (size_t)row * HDD + kk * 32 + lgrp * 8);
    }

    f32x4 o[8] = {};
    float m_r[4], l_r[4];
#pragma unroll
    for (int r = 0; r < 4; ++r) { m_r[r] = NEG_INF; l_r[r] = 0.f; }

    for (int kt = 0; kt < nt; ++kt) {
      const int k0 = kt * 128;
      load_V(k0);           // V loads first (oldest in vmcnt queue)
      issue_K(k0);          // K direct-to-LDS, in flight during V repack
      write_V();            // waits only the 4 V loads; WAR safe (prev barrier)
      __syncthreads();      // drains vmcnt+lgkmcnt: K & V staged for all waves

      // ---- S = Q K^T  (logits pre-scaled via Q)
      f32x4 s[8] = {};
#pragma unroll
      for (int kk = 0; kk < 4; ++kk) {
#pragma unroll
        for (int nf = 0; nf < 8; ++nf) {
          int key = nf * 16 + lane16;
          int ch = (kk * 4 + lgrp) ^ ((key ^ (key >> 3)) & 15);
          bf16x8 kf = *(const bf16x8*)((char*)Ksm + key * 256 + (ch << 4));
          s[nf] = __builtin_amdgcn_mfma_f32_16x16x32_bf16(
              qa[kk], kf, s[nf], 0, 0, 0);
        }
      }

      // ---- causal mask (diagonal tile only; wave-uniform branch)
      if (k0 + 127 > q0 + w * 16) {
        const int rowbase = q0 + w * 16 + lgrp * 4;
#pragma unroll
        for (int nf = 0; nf < 8; ++nf) {
          int col = k0 + nf * 16 + lane16;
#pragma unroll
          for (int r = 0; r < 4; ++r)
            if (col > rowbase + r) s[nf][r] = -3.0e38f;
        }
      }

      // ---- online softmax (unconditional rescale — straight-line)
#pragma unroll
      for (int r = 0; r < 4; ++r) {
        float tm = fmaxf(fmaxf(fmaxf(s[0][r], s[1][r]), fmaxf(s[2][r], s[3][r])),
                         fmaxf(fmaxf(s[4][r], s[5][r]), fmaxf(s[6][r], s[7][r])));
        tm = fmaxf(tm, __shfl_xor(tm, 1));
        tm = fmaxf(tm, __shfl_xor(tm, 2));
        tm = fmaxf(tm, __shfl_xor(tm, 4));
        tm = fmaxf(tm, __shfl_xor(tm, 8));
        float mo = m_r[r];
        float mn = fmaxf(mo, tm);
        float alpha = exp2f((mo - mn) * L2E);
        m_r[r] = mn;
        float rs = 0.f;
#pragma unroll
        for (int nf = 0; nf < 8; ++nf) {
          float p = exp2f((s[nf][r] - mn) * L2E);
          s[nf][r] = p;
          rs += p;
        }
        rs += __shfl_xor(rs, 1);
        rs += __shfl_xor(rs, 2);
        rs += __shfl_xor(rs, 4);
        rs += __shfl_xor(rs, 8);
        l_r[r] = l_r[r] * alpha + rs;
#pragma unroll
        for (int nf = 0; nf < 8; ++nf) o[nf][r] *= alpha;
      }

      // ---- P -> LDS (per-wave region, same-wave readback; no barrier)
#pragma unroll
      for (int nf = 0; nf < 8; ++nf)
#pragma unroll
        for (int r = 0; r < 4; ++r) {
          int rl = lgrp * 4 + r;
          int ch = (2 * nf + (lane16 >> 3)) ^ ((rl ^ (rl >> 3)) & 15);
          int byte = rl * 256 + (ch << 4) + ((lane16 & 7) << 1);
          *(bf16*)((char*)&Psm[w][0] + byte) = (bf16)s[nf][r];
        }
      bf16x8 pa[4];
#pragma unroll
      for (int kk = 0; kk < 4; ++kk) {
        int ch = (kk * 4 + lgrp) ^ ((lane16 ^ (lane16 >> 3)) & 15);
        pa[kk] = *(const bf16x8*)((char*)&Psm[w][0] + lane16 * 256 + (ch << 4));
      }

      // ---- O += P V
#pragma unroll
      for (int nf = 0; nf < 8; ++nf) {
#pragma unroll
        for (int kk = 0; kk < 4; ++kk) {
          int hd = nf * 16 + lane16;
          int ch = (kk * 4 + lgrp) ^ ((hd ^ (hd >> 3)) & 15);
          bf16x8 vf = *(const bf16x8*)((char*)Vsm + hd * 256 + (ch << 4));
          o[nf] = __builtin_amdgcn_mfma_f32_16x16x32_bf16(
              pa[kk], vf, o[nf], 0, 0, 0);
        }
      }

      __syncthreads();      // all waves done reading Ksm/Vsm before next stage
    }

    // ---- finalize: O / l -> Y (b,t,D) bf16
#pragma unroll
    for (int r = 0; r < 4; ++r) {
      float inv = 1.0f / l_r[r];
      int row = q0 + w * 16 + lgrp * 4 + r;
#pragma unroll
      for (int nf = 0; nf < 8; ++nf) {
        int hd = nf * 16 + lane16;
        Y[(size_t)(b * TT + row) * DM + h * HDD + hd] = (bf16)(o[nf][r] * inv);
      }
    }
  }
}

// ---------------------------------------------------------------- launch
extern "C" void kernel_launch(void* const* d_in, const int* in_sizes, int n_in,
                              void* d_out, int out_size, void* d_ws, size_t ws_size,
                              hipStream_t stream) {
  const float* x = (const float*)d_in[0];
  const float* Wqkv = (const float*)d_in[2];
  const float* bqkv = (const float*)d_in[3];
  const float* Wproj = (const float*)d_in[4];
  const float* bproj = (const float*)d_in[5];
  float* out = (float*)d_out;

  char* ws = (char*)d_ws;
  bf16* xb = (bf16*)ws;                 ws += (size_t)MM * DM * 2;
  bf16* Wqkvt = (bf16*)ws;              ws += (size_t)NQKV * DM * 2;
  bf16* Wprojt = (bf16*)ws;             ws += (size_t)DM * DM * 2;
  bf16* kb = (bf16*)ws;                 ws += (size_t)MM * DM * 2;
  bf16* vb = (bf16*)ws;                 ws += (size_t)MM * DM * 2;
  float* cosT = (float*)ws;             ws += (size_t)TT * 64 * 4;
  float* sinT = (float*)ws;             ws += (size_t)TT * 64 * 4;
  bf16* qb = (bf16*)d_out;              // q lives in d_out (overwritten by proj)
  bf16* yb = xb;                        // xb dead after QKV GEMM

  rope_table_k<<<dim3(512), dim3(256), 0, stream>>>(cosT, sinT);
  convert_x_k<<<dim3(4096), dim3(256), 0, stream>>>(x, xb);
  transpose_w_k<<<dim3(96, 32), dim3(256), 0, stream>>>(Wqkv, Wqkvt, DM, NQKV);
  transpose_w_k<<<dim3(32, 32), dim3(256), 0, stream>>>(Wproj, Wprojt, DM, DM);

  gemm8_qkv_k<<<dim3(16, 32), dim3(512), 0, stream>>>(
      xb, Wqkvt, bqkv, qb, kb, vb, MM, NQKV, DM);

  rope_apply_k<true><<<dim3(4096), dim3(256), 0, stream>>>(qb, cosT, sinT);
  rope_apply_k<false><<<dim3(4096), dim3(256), 0, stream>>>(kb, cosT, sinT);

  attn_k<<<dim3(8, 32), dim3(512), 0, stream>>>(qb, kb, vb, yb);

  gemm4_proj_k<<<dim3(16, 16), dim3(512), 0, stream>>>(
      yb, Wprojt, bproj, out, MM, DM, DM);
}

// Round 17
// 273.197 us; speedup vs baseline: 1.0948x; 1.0178x over previous
//
#include <hip/hip_runtime.h>
#include <hip/hip_bf16.h>
#include <stdint.h>
#include <stddef.h>

typedef __bf16 bf16;
typedef __attribute__((ext_vector_type(8))) __bf16 bf16x8;
typedef __attribute__((ext_vector_type(4))) __bf16 bf16x4;
typedef __attribute__((ext_vector_type(4))) float f32x4;

#define DM 2048      // model dim
#define NH 16        // heads
#define HDD 128      // head dim
#define BB 2         // batch
#define TT 2048      // seq len
#define MM (BB*TT)   // 4096 rows
#define NQKV (3*DM)  // 6144

#define L2E 1.4426950408889634f
#define ATT_SCALE 0.08838834764831845f       // 1/sqrt(128)
#define QSCALE (ATT_SCALE * L2E)             // folded into Q at RoPE: logits in log2 domain
#define NEG_INF (-__builtin_inff())

static_assert(sizeof(bf16x8) == 16, "bf16x8 must be 16B");

#define SB0() __builtin_amdgcn_sched_barrier(0)
#define WAITV0() { asm volatile("s_waitcnt vmcnt(0)" ::: "memory"); SB0(); }
#define BARRIER8() { SB0(); __builtin_amdgcn_s_barrier(); SB0(); }

// ---------------------------------------------------------------- helpers
static __device__ __forceinline__ void gload_lds16(const void* g, void* l) {
  __builtin_amdgcn_global_load_lds(
      (__attribute__((address_space(1))) void*)g,
      (__attribute__((address_space(3))) void*)l, 16, 0, 0);
}

// ---------------------------------------------------------------- pre-pass
__global__ __launch_bounds__(256) void rope_table_k(float* __restrict__ cT,
                                                    float* __restrict__ sT) {
  int id = blockIdx.x * 256 + threadIdx.x;          // < 2048*64
  int t = id >> 6, i = id & 63;
  float freq = powf(10000.0f, -(float)i * (1.0f / 64.0f));
  float theta = (float)t * freq;
  float s, c;
  __sincosf(theta, &s, &c);
  cT[id] = c;
  sT[id] = s;
}

__global__ __launch_bounds__(256) void convert_x_k(const float* __restrict__ x,
                                                   bf16* __restrict__ xb) {
  size_t id = (size_t)blockIdx.x * 256 + threadIdx.x;
  size_t o = id * 8;
  float4 a = *(const float4*)(x + o);
  float4 b = *(const float4*)(x + o + 4);
  bf16x8 r;
  r[0] = (bf16)a.x; r[1] = (bf16)a.y; r[2] = (bf16)a.z; r[3] = (bf16)a.w;
  r[4] = (bf16)b.x; r[5] = (bf16)b.y; r[6] = (bf16)b.z; r[7] = (bf16)b.w;
  *(bf16x8*)(xb + o) = r;
}

// W (K x N) f32 -> Wt (N x K) bf16, 64x64 tiles
__global__ __launch_bounds__(256) void transpose_w_k(const float* __restrict__ W,
                                                     bf16* __restrict__ Wt,
                                                     int K, int N) {
  __shared__ float tile[64][65];
  int n0 = blockIdx.x * 64, k0 = blockIdx.y * 64;
  int t = threadIdx.x;
#pragma unroll
  for (int i = 0; i < 16; ++i) {
    int idx = t + i * 256;
    int r = idx >> 6, c = idx & 63;
    tile[r][c] = W[(size_t)(k0 + r) * N + n0 + c];
  }
  __syncthreads();
#pragma unroll
  for (int i = 0; i < 16; ++i) {
    int idx = t + i * 256;
    int r = idx >> 6, c = idx & 63;
    Wt[(size_t)(n0 + r) * K + k0 + c] = (bf16)tile[c][r];
  }
}

// in-place RoPE on (b,h,t,hd) bf16 buffer; SC folds QSCALE (for Q)
template <bool SC>
__global__ __launch_bounds__(256) void rope_apply_k(bf16* __restrict__ buf,
                                                    const float* __restrict__ cT,
                                                    const float* __restrict__ sT) {
  int id = blockIdx.x * 256 + threadIdx.x;   // < 32*2048*16
  int i4 = id & 15;
  int t = (id >> 4) & 2047;
  int bh = id >> 15;
  int idx0 = i4 * 4;
  size_t base = ((size_t)bh * TT + t) * HDD;
  bf16x4 x1 = *(const bf16x4*)(buf + base + idx0);
  bf16x4 x2 = *(const bf16x4*)(buf + base + 64 + idx0);
  float4 ct = *(const float4*)(cT + t * 64 + idx0);
  float4 st = *(const float4*)(sT + t * 64 + idx0);
  bf16x4 o1, o2;
  float c0, s0, a, b2;
  const float scl = SC ? (float)QSCALE : 1.0f;
#pragma unroll
  for (int j = 0; j < 4; ++j) {
    c0 = (j == 0) ? ct.x : (j == 1) ? ct.y : (j == 2) ? ct.z : ct.w;
    s0 = (j == 0) ? st.x : (j == 1) ? st.y : (j == 2) ? st.z : st.w;
    a = (float)x1[j];
    b2 = (float)x2[j];
    o1[j] = (bf16)((a * c0 - b2 * s0) * scl);
    o2[j] = (bf16)((a * s0 + b2 * c0) * scl);
  }
  *(bf16x4*)(buf + base + idx0) = o1;
  *(bf16x4*)(buf + base + 64 + idx0) = o2;
}

// ---------------------------------------------------------------- GEMM (QKV, 1-barrier 256x192)
// R16-proven: one barrier/tile; ds_reads+MFMAs interleave via compiler lgkmcnt;
// stages of t+1 fly under the MFMA block, drained at t+1's top WAITV0.
#define MFMA_Q(MF0, NF0, NCNT)                                             \
  do {                                                                     \
    __builtin_amdgcn_s_setprio(1);                                         \
    _Pragma("unroll") for (int mf = 0; mf < 4; ++mf)                       \
    _Pragma("unroll") for (int nf = 0; nf < (NCNT); ++nf)                  \
    _Pragma("unroll") for (int kk = 0; kk < 2; ++kk)                       \
      acc[(MF0) + mf][(NF0) + nf] = __builtin_amdgcn_mfma_f32_16x16x32_bf16( \
          af[(MF0) + mf][kk], bfr[(NF0) + nf][kk], acc[(MF0) + mf][(NF0) + nf], 0, 0, 0); \
    __builtin_amdgcn_s_setprio(0);                                         \
  } while (0)

__global__ __launch_bounds__(512, 2) void gemm8_qkv_k(
    const bf16* __restrict__ A, const bf16* __restrict__ Bt,
    const float* __restrict__ bias,
    bf16* __restrict__ q_out, bf16* __restrict__ k_out, bf16* __restrict__ v_out,
    int M, int N, int K) {
  __shared__ __align__(16) char Lsm[2][57344];   // [buf][A:32KB | B:24KB]
  const int tid = threadIdx.x;
  const int wid = tid >> 6, l = tid & 63;
  const int lane16 = l & 15, lgrp = l >> 4;
  const int wm = wid >> 2, wn = wid & 3;

  int flat = blockIdx.y * gridDim.x + blockIdx.x;
  {
    const int cpx = (gridDim.x * gridDim.y) >> 3;
    flat = (flat & 7) * cpx + (flat >> 3);
  }
  const int bm = flat % gridDim.x;       // 0..15  (M/256)
  const int bn = flat / gridDim.x;       // 0..31  (N/192)
  const int NT = K >> 6;

  const int schunk = (l & 7) ^ ((l >> 3) & 7);
  const bf16* gA = A + (size_t)(bm * 256 + wid * 8 + (l >> 3)) * K + schunk * 8;
  const bf16* gB = Bt + (size_t)(bn * 192 + wid * 8 + (l >> 3)) * K + schunk * 8;

  auto stage_unit = [&](int mat, int t, int u, int buf) {
    const bf16* g = (mat ? gB : gA) + (size_t)(u * 64) * K + t * 64;
    gload_lds16(g, &Lsm[buf][(mat ? 32768 : 0) + u * 8192 + wid * 1024]);
  };

  f32x4 acc[8][3] = {};

#pragma unroll
  for (int u = 0; u < 4; ++u) stage_unit(0, 0, u, 0);
#pragma unroll
  for (int u = 0; u < 3; ++u) stage_unit(1, 0, u, 0);

  for (int t = 0; t < NT; ++t) {
    const int cur = t & 1;
    const char* As = &Lsm[cur][0];
    const char* Bs = &Lsm[cur][32768];
    bf16x8 af[8][2], bfr[3][2];

    WAITV0();                 // this tile's 7 stage loads landed (my wave's)
    BARRIER8();               // visible to all waves; prev tile fully done

    // ---- read all frags (ds_read) + stage t+1 (gload_lds -> buf^1)
#pragma unroll
    for (int mf = 0; mf < 8; ++mf)
#pragma unroll
      for (int kk = 0; kk < 2; ++kk) {
        int row = wm * 128 + mf * 16 + lane16;
        int ch = (kk * 4 + lgrp) ^ (lane16 & 7);
        af[mf][kk] = *(const bf16x8*)(As + row * 128 + ch * 16);
      }
#pragma unroll
    for (int nf = 0; nf < 3; ++nf)
#pragma unroll
      for (int kk = 0; kk < 2; ++kk) {
        int row = wn * 48 + nf * 16 + lane16;
        int ch = (kk * 4 + lgrp) ^ (lane16 & 7);
        bfr[nf][kk] = *(const bf16x8*)(Bs + row * 128 + ch * 16);
      }
    if (t + 1 < NT) {
#pragma unroll
      for (int u = 0; u < 4; ++u) stage_unit(0, t + 1, u, cur ^ 1);
#pragma unroll
      for (int u = 0; u < 3; ++u) stage_unit(1, t + 1, u, cur ^ 1);
    }

    // ---- all 48 MFMA; compiler interleaves with the ds_reads above
    MFMA_Q(0, 0, 3);
    MFMA_Q(4, 0, 3);
  }

  // ---- epilogue
#pragma unroll
  for (int nf = 0; nf < 3; ++nf) {
    int colg = bn * 192 + wn * 48 + nf * 16 + lane16;
    int which = colg >> 11;
    bf16* outb = (which == 0) ? q_out : (which == 1 ? k_out : v_out);
    int head = (colg >> 7) & 15, hd = colg & 127;
    float bv = bias[colg];
#pragma unroll
    for (int mf = 0; mf < 8; ++mf)
#pragma unroll
      for (int r = 0; r < 4; ++r) {
        int row = bm * 256 + wm * 128 + mf * 16 + lgrp * 4 + r;
        int bb = row >> 11, tt2 = row & 2047;
        outb[((size_t)(bb * NH + head) * TT + tt2) * HDD + hd] =
            (bf16)(acc[mf][nf][r] + bv);
      }
  }
}

// ---------------------------------------------------------------- GEMM (proj, 1-barrier 256x128)
__global__ __launch_bounds__(512, 2) void gemm4_proj_k(
    const bf16* __restrict__ A, const bf16* __restrict__ Bt,
    const float* __restrict__ bias, float* __restrict__ c_out,
    int M, int N, int K) {
  __shared__ __align__(16) char Lsm[2][49152];   // [buf][A:32KB | B:16KB]
  const int tid = threadIdx.x;
  const int wid = tid >> 6, l = tid & 63;
  const int lane16 = l & 15, lgrp = l >> 4;
  const int wm = wid >> 2, wn = wid & 3;

  int flat = blockIdx.y * gridDim.x + blockIdx.x;
  {
    const int cpx = (gridDim.x * gridDim.y) >> 3;
    flat = (flat & 7) * cpx + (flat >> 3);
  }
  const int bm = flat % gridDim.x;       // 0..15 (M/256)
  const int bn = flat / gridDim.x;       // 0..15 (N/128)
  const int NT = K >> 6;

  const int schunk = (l & 7) ^ ((l >> 3) & 7);
  const bf16* gA = A + (size_t)(bm * 256 + wid * 8 + (l >> 3)) * K + schunk * 8;
  const bf16* gB = Bt + (size_t)(bn * 128 + wid * 8 + (l >> 3)) * K + schunk * 8;

  auto stage_unit = [&](int mat, int t, int u, int buf) {
    const bf16* g = (mat ? gB : gA) + (size_t)(u * 64) * K + t * 64;
    gload_lds16(g, &Lsm[buf][(mat ? 32768 : 0) + u * 8192 + wid * 1024]);
  };

  f32x4 acc[8][2] = {};

#pragma unroll
  for (int u = 0; u < 4; ++u) stage_unit(0, 0, u, 0);
#pragma unroll
  for (int u = 0; u < 2; ++u) stage_unit(1, 0, u, 0);

  for (int t = 0; t < NT; ++t) {
    const int cur = t & 1;
    const char* As = &Lsm[cur][0];
    const char* Bs = &Lsm[cur][32768];
    bf16x8 af[8][2], bfr[2][2];

    WAITV0();
    BARRIER8();

    // ---- read all frags + stage t+1
#pragma unroll
    for (int mf = 0; mf < 8; ++mf)
#pragma unroll
      for (int kk = 0; kk < 2; ++kk) {
        int row = wm * 128 + mf * 16 + lane16;
        int ch = (kk * 4 + lgrp) ^ (lane16 & 7);
        af[mf][kk] = *(const bf16x8*)(As + row * 128 + ch * 16);
      }
#pragma unroll
    for (int nf = 0; nf < 2; ++nf)
#pragma unroll
      for (int kk = 0; kk < 2; ++kk) {
        int row = wn * 32 + nf * 16 + lane16;
        int ch = (kk * 4 + lgrp) ^ (lane16 & 7);
        bfr[nf][kk] = *(const bf16x8*)(Bs + row * 128 + ch * 16);
      }
    if (t + 1 < NT) {
#pragma unroll
      for (int u = 0; u < 4; ++u) stage_unit(0, t + 1, u, cur ^ 1);
#pragma unroll
      for (int u = 0; u < 2; ++u) stage_unit(1, t + 1, u, cur ^ 1);
    }

    // ---- all 32 MFMA
    MFMA_Q(0, 0, 2);
    MFMA_Q(4, 0, 2);
  }

  // ---- epilogue: bias + f32 row-major store
#pragma unroll
  for (int nf = 0; nf < 2; ++nf) {
    int colg = bn * 128 + wn * 32 + nf * 16 + lane16;
    float bv = bias[colg];
#pragma unroll
    for (int mf = 0; mf < 8; ++mf)
#pragma unroll
      for (int r = 0; r < 4; ++r) {
        int row = bm * 256 + wm * 128 + mf * 16 + lgrp * 4 + r;
        c_out[(size_t)row * N + colg] = acc[mf][nf][r] + bv;
      }
  }
}

// ---------------------------------------------------------------- attention
// R13 structure + R17 edits: (1) V prefetched into the compute phase —
// load_V(kt+1) issued right after the staging barrier, lands under ~10k cyc
// of compute, so next tile's write_V starts with zero wait (registers-only
// change, same barrier pattern). (2) log2-domain softmax: Q carries
// ATT_SCALE*L2E, exp2 applied directly (no *L2E muls).
// Retired: cross-tile gload prefetch (R8/R10), reg-staged K (R14), defer-max (R12).
__global__ __launch_bounds__(512, 2) void attn_k(
    const bf16* __restrict__ Q, const bf16* __restrict__ Kt,
    const bf16* __restrict__ V, bf16* __restrict__ Y) {
  __shared__ __align__(16) bf16 Ksm[128 * 128];   // [key][hd], chunk^=g4(key), 32KB
  __shared__ __align__(16) bf16 Vsm[128 * 128];   // [hd][key], chunk^=g4(hd), 32KB
  __shared__ __align__(16) bf16 Psm[8][16 * 128]; // per-wave P, chunk^=g4(row), 32KB
  const int tid = threadIdx.x, w = tid >> 6, l = tid & 63;
  const int lane16 = l & 15, lgrp = l >> 4;
  const int bh = blockIdx.y;
  const int b = bh >> 4, h = bh & 15;
  const size_t base = (size_t)bh * TT * HDD;

  uint4 vreg[4];
  const int vg = tid >> 4, vh8 = tid & 15;

  auto load_V = [&](int k0) {
#pragma unroll
    for (int kq = 0; kq < 4; ++kq)
      vreg[kq] = *(const uint4*)(V + base + (size_t)(k0 + vg * 4 + kq) * HDD + vh8 * 8);
  };
  auto issue_K = [&](int k0) {
#pragma unroll
    for (int i = 0; i < 4; ++i) {
      int key = w * 16 + i * 4 + (l >> 4);
      int c = (l & 15) ^ ((key ^ (key >> 3)) & 15);
      gload_lds16(Kt + base + (size_t)(k0 + key) * HDD + c * 8,
                  &Ksm[(w * 16 + i * 4) * 128 + (l & 15) * 8]);
    }
  };
  auto write_V = [&]() {
    const unsigned* dw = (const unsigned*)vreg;
    int hd0 = vh8 * 8;
#pragma unroll
    for (int j = 0; j < 8; ++j) {
      int ww = j >> 1;
      unsigned sel = (j & 1) ? 0x07060302u : 0x05040100u;
      uint2 val;
      val.x = __builtin_amdgcn_perm(dw[4 + ww], dw[0 + ww], sel);
      val.y = __builtin_amdgcn_perm(dw[12 + ww], dw[8 + ww], sel);
      int hd = hd0 + j;
      int ch = (vg >> 1) ^ ((hd ^ (hd >> 3)) & 15);
      *(uint2*)((char*)Vsm + hd * 256 + (ch << 4) + ((vg & 1) << 3)) = val;
    }
  };

  for (int pass = 0; pass < 2; ++pass) {
    const int qt = (pass == 0) ? (int)blockIdx.x : 15 - (int)blockIdx.x;
    const int q0 = qt * 128;
    const int nt = qt + 1;

    load_V(0);              // prologue V prefetch (overlaps Q-frag loads)

    bf16x8 qa[4];
    {
      int row = q0 + w * 16 + lane16;
#pragma unroll
      for (int kk = 0; kk < 4; ++kk)
        qa[kk] = *(const bf16x8*)(Q + base + (size_t)row * HDD + kk * 32 + lgrp * 8);
    }

    f32x4 o[8] = {};
    float m_r[4], l_r[4];
#pragma unroll
    for (int r = 0; r < 4; ++r) { m_r[r] = NEG_INF; l_r[r] = 0.f; }

    for (int kt = 0; kt < nt; ++kt) {
      const int k0 = kt * 128;
      issue_K(k0);          // K direct-to-LDS (linear dest, single buffer)
      write_V();            // vreg prefetched last tile -> zero wait
      __syncthreads();      // drains K gloads + V ds_writes: staged for all
      if (kt + 1 < nt) load_V(k0 + 128);   // lands under compute

      // ---- S = Q K^T  (logits already in log2 domain via QSCALE)
      f32x4 s[8] = {};
#pragma unroll
      for (int kk = 0; kk < 4; ++kk) {
#pragma unroll
        for (int nf = 0; nf < 8; ++nf) {
          int key = nf * 16 + lane16;
          int ch = (kk * 4 + lgrp) ^ ((key ^ (key >> 3)) & 15);
          bf16x8 kf = *(const bf16x8*)((char*)Ksm + key * 256 + (ch << 4));
          s[nf] = __builtin_amdgcn_mfma_f32_16x16x32_bf16(
              qa[kk], kf, s[nf], 0, 0, 0);
        }
      }

      // ---- causal mask (diagonal tile only; wave-uniform branch)
      if (k0 + 127 > q0 + w * 16) {
        const int rowbase = q0 + w * 16 + lgrp * 4;
#pragma unroll
        for (int nf = 0; nf < 8; ++nf) {
          int col = k0 + nf * 16 + lane16;
#pragma unroll
          for (int r = 0; r < 4; ++r)
            if (col > rowbase + r) s[nf][r] = -3.0e38f;
        }
      }

      // ---- online softmax (log2 domain, unconditional rescale)
#pragma unroll
      for (int r = 0; r < 4; ++r) {
        float tm = fmaxf(fmaxf(fmaxf(s[0][r], s[1][r]), fmaxf(s[2][r], s[3][r])),
                         fmaxf(fmaxf(s[4][r], s[5][r]), fmaxf(s[6][r], s[7][r])));
        tm = fmaxf(tm, __shfl_xor(tm, 1));
        tm = fmaxf(tm, __shfl_xor(tm, 2));
        tm = fmaxf(tm, __shfl_xor(tm, 4));
        tm = fmaxf(tm, __shfl_xor(tm, 8));
        float mo = m_r[r];
        float mn = fmaxf(mo, tm);
        float alpha = exp2f(mo - mn);
        m_r[r] = mn;
        float rs = 0.f;
#pragma unroll
        for (int nf = 0; nf < 8; ++nf) {
          float p = exp2f(s[nf][r] - mn);
          s[nf][r] = p;
          rs += p;
        }
        rs += __shfl_xor(rs, 1);
        rs += __shfl_xor(rs, 2);
        rs += __shfl_xor(rs, 4);
        rs += __shfl_xor(rs, 8);
        l_r[r] = l_r[r] * alpha + rs;
#pragma unroll
        for (int nf = 0; nf < 8; ++nf) o[nf][r] *= alpha;
      }

      // ---- P -> LDS (per-wave region, same-wave readback; no barrier)
#pragma unroll
      for (int nf = 0; nf < 8; ++nf)
#pragma unroll
        for (int r = 0; r < 4; ++r) {
          int rl = lgrp * 4 + r;
          int ch = (2 * nf + (lane16 >> 3)) ^ ((rl ^ (rl >> 3)) & 15);
          int byte = rl * 256 + (ch << 4) + ((lane16 & 7) << 1);
          *(bf16*)((char*)&Psm[w][0] + byte) = (bf16)s[nf][r];
        }
      bf16x8 pa[4];
#pragma unroll
      for (int kk = 0; kk < 4; ++kk) {
        int ch = (kk * 4 + lgrp) ^ ((lane16 ^ (lane16 >> 3)) & 15);
        pa[kk] = *(const bf16x8*)((char*)&Psm[w][0] + lane16 * 256 + (ch << 4));
      }

      // ---- O += P V
#pragma unroll
      for (int nf = 0; nf < 8; ++nf) {
#pragma unroll
        for (int kk = 0; kk < 4; ++kk) {
          int hd = nf * 16 + lane16;
          int ch = (kk * 4 + lgrp) ^ ((hd ^ (hd >> 3)) & 15);
          bf16x8 vf = *(const bf16x8*)((char*)Vsm + hd * 256 + (ch << 4));
          o[nf] = __builtin_amdgcn_mfma_f32_16x16x32_bf16(
              pa[kk], vf, o[nf], 0, 0, 0);
        }
      }

      __syncthreads();      // all reads of Ksm/Vsm done; V prefetch landed
    }

    // ---- finalize: O / l -> Y (b,t,D) bf16
#pragma unroll
    for (int r = 0; r < 4; ++r) {
      float inv = 1.0f / l_r[r];
      int row = q0 + w * 16 + lgrp * 4 + r;
#pragma unroll
      for (int nf = 0; nf < 8; ++nf) {
        int hd = nf * 16 + lane16;
        Y[(size_t)(b * TT + row) * DM + h * HDD + hd] = (bf16)(o[nf][r] * inv);
      }
    }
  }
}

// ---------------------------------------------------------------- launch
extern "C" void kernel_launch(void* const* d_in, const int* in_sizes, int n_in,
                              void* d_out, int out_size, void* d_ws, size_t ws_size,
                              hipStream_t stream) {
  const float* x = (const float*)d_in[0];
  const float* Wqkv = (const float*)d_in[2];
  const float* bqkv = (const float*)d_in[3];
  const float* Wproj = (const float*)d_in[4];
  const float* bproj = (const float*)d_in[5];
  float* out = (float*)d_out;

  char* ws = (char*)d_ws;
  bf16* xb = (bf16*)ws;                 ws += (size_t)MM * DM * 2;
  bf16* Wqkvt = (bf16*)ws;              ws += (size_t)NQKV * DM * 2;
  bf16* Wprojt = (bf16*)ws;             ws += (size_t)DM * DM * 2;
  bf16* kb = (bf16*)ws;                 ws += (size_t)MM * DM * 2;
  bf16* vb = (bf16*)ws;                 ws += (size_t)MM * DM * 2;
  float* cosT = (float*)ws;             ws += (size_t)TT * 64 * 4;
  float* sinT = (float*)ws;             ws += (size_t)TT * 64 * 4;
  bf16* qb = (bf16*)d_out;              // q lives in d_out (overwritten by proj)
  bf16* yb = xb;                        // xb dead after QKV GEMM

  rope_table_k<<<dim3(512), dim3(256), 0, stream>>>(cosT, sinT);
  convert_x_k<<<dim3(4096), dim3(256), 0, stream>>>(x, xb);
  transpose_w_k<<<dim3(96, 32), dim3(256), 0, stream>>>(Wqkv, Wqkvt, DM, NQKV);
  transpose_w_k<<<dim3(32, 32), dim3(256), 0, stream>>>(Wproj, Wprojt, DM, DM);

  gemm8_qkv_k<<<dim3(16, 32), dim3(512), 0, stream>>>(
      xb, Wqkvt, bqkv, qb, kb, vb, MM, NQKV, DM);

  rope_apply_k<true><<<dim3(4096), dim3(256), 0, stream>>>(qb, cosT, sinT);
  rope_apply_k<false><<<dim3(4096), dim3(256), 0, stream>>>(kb, cosT, sinT);

  attn_k<<<dim3(8, 32), dim3(512), 0, stream>>>(qb, kb, vb, yb);

  gemm4_proj_k<<<dim3(16, 16), dim3(512), 0, stream>>>(
      yb, Wprojt, bproj, out, MM, DM, DM);
}

// Round 18
// 263.389 us; speedup vs baseline: 1.1356x; 1.0372x over previous
//
#include <hip/hip_runtime.h>
#include <hip/hip_bf16.h>
#include <stdint.h>
#include <stddef.h>

typedef __bf16 bf16;
typedef __attribute__((ext_vector_type(8))) __bf16 bf16x8;
typedef __attribute__((ext_vector_type(4))) __bf16 bf16x4;
typedef __attribute__((ext_vector_type(4))) float f32x4;

#define DM 2048      // model dim
#define NH 16        // heads
#define HDD 128      // head dim
#define BB 2         // batch
#define TT 2048      // seq len
#define MM (BB*TT)   // 4096 rows
#define NQKV (3*DM)  // 6144

#define L2E 1.4426950408889634f
#define ATT_SCALE 0.08838834764831845f       // 1/sqrt(128)
#define QSCALE (ATT_SCALE * L2E)             // folded into Q: logits in log2 domain
#define NEG_INF (-__builtin_inff())

static_assert(sizeof(bf16x8) == 16, "bf16x8 must be 16B");

#define SB0() __builtin_amdgcn_sched_barrier(0)
#define WAITV0() { asm volatile("s_waitcnt vmcnt(0)" ::: "memory"); SB0(); }
#define BARRIER8() { SB0(); __builtin_amdgcn_s_barrier(); SB0(); }

// ---------------------------------------------------------------- helpers
static __device__ __forceinline__ void gload_lds16(const void* g, void* l) {
  __builtin_amdgcn_global_load_lds(
      (__attribute__((address_space(1))) void*)g,
      (__attribute__((address_space(3))) void*)l, 16, 0, 0);
}

// ---------------------------------------------------------------- pre-pass
__global__ __launch_bounds__(256) void rope_table_k(float* __restrict__ cT,
                                                    float* __restrict__ sT) {
  int id = blockIdx.x * 256 + threadIdx.x;          // < 2048*64
  int t = id >> 6, i = id & 63;
  float freq = powf(10000.0f, -(float)i * (1.0f / 64.0f));
  float theta = (float)t * freq;
  float s, c;
  __sincosf(theta, &s, &c);
  cT[id] = c;
  sT[id] = s;
}

__global__ __launch_bounds__(256) void convert_x_k(const float* __restrict__ x,
                                                   bf16* __restrict__ xb) {
  size_t id = (size_t)blockIdx.x * 256 + threadIdx.x;
  size_t o = id * 8;
  float4 a = *(const float4*)(x + o);
  float4 b = *(const float4*)(x + o + 4);
  bf16x8 r;
  r[0] = (bf16)a.x; r[1] = (bf16)a.y; r[2] = (bf16)a.z; r[3] = (bf16)a.w;
  r[4] = (bf16)b.x; r[5] = (bf16)b.y; r[6] = (bf16)b.z; r[7] = (bf16)b.w;
  *(bf16x8*)(xb + o) = r;
}

// W (K x N) f32 -> Wt (N x K) bf16, 64x64 tiles
__global__ __launch_bounds__(256) void transpose_w_k(const float* __restrict__ W,
                                                     bf16* __restrict__ Wt,
                                                     int K, int N) {
  __shared__ float tile[64][65];
  int n0 = blockIdx.x * 64, k0 = blockIdx.y * 64;
  int t = threadIdx.x;
#pragma unroll
  for (int i = 0; i < 16; ++i) {
    int idx = t + i * 256;
    int r = idx >> 6, c = idx & 63;
    tile[r][c] = W[(size_t)(k0 + r) * N + n0 + c];
  }
  __syncthreads();
#pragma unroll
  for (int i = 0; i < 16; ++i) {
    int idx = t + i * 256;
    int r = idx >> 6, c = idx & 63;
    Wt[(size_t)(n0 + r) * K + k0 + c] = (bf16)tile[c][r];
  }
}

// in-place RoPE on BOTH q and k in one launch (block-uniform buffer select);
// q gets QSCALE folded (log2-domain logits).
__global__ __launch_bounds__(256) void rope_apply_k(bf16* __restrict__ qbuf,
                                                    bf16* __restrict__ kbuf,
                                                    const float* __restrict__ cT,
                                                    const float* __restrict__ sT) {
  int id = blockIdx.x * 256 + threadIdx.x;   // < 64*2048*16
  int i4 = id & 15;
  int t = (id >> 4) & 2047;
  int bh64 = id >> 15;                       // 0..63; <32 -> q, >=32 -> k
  const bool isq = bh64 < 32;
  bf16* buf = isq ? qbuf : kbuf;
  const float scl = isq ? (float)QSCALE : 1.0f;
  int bh = isq ? bh64 : (bh64 - 32);
  int idx0 = i4 * 4;
  size_t base = ((size_t)bh * TT + t) * HDD;
  bf16x4 x1 = *(const bf16x4*)(buf + base + idx0);
  bf16x4 x2 = *(const bf16x4*)(buf + base + 64 + idx0);
  float4 ct = *(const float4*)(cT + t * 64 + idx0);
  float4 st = *(const float4*)(sT + t * 64 + idx0);
  bf16x4 o1, o2;
  float c0, s0, a, b2;
#pragma unroll
  for (int j = 0; j < 4; ++j) {
    c0 = (j == 0) ? ct.x : (j == 1) ? ct.y : (j == 2) ? ct.z : ct.w;
    s0 = (j == 0) ? st.x : (j == 1) ? st.y : (j == 2) ? st.z : st.w;
    a = (float)x1[j];
    b2 = (float)x2[j];
    o1[j] = (bf16)((a * c0 - b2 * s0) * scl);
    o2[j] = (bf16)((a * s0 + b2 * c0) * scl);
  }
  *(bf16x4*)(buf + base + idx0) = o1;
  *(bf16x4*)(buf + base + 64 + idx0) = o2;
}

// ---------------------------------------------------------------- GEMM (QKV, 1-barrier 256x192)
#define MFMA_Q(MF0, NF0, NCNT)                                             \
  do {                                                                     \
    __builtin_amdgcn_s_setprio(1);                                         \
    _Pragma("unroll") for (int mf = 0; mf < 4; ++mf)                       \
    _Pragma("unroll") for (int nf = 0; nf < (NCNT); ++nf)                  \
    _Pragma("unroll") for (int kk = 0; kk < 2; ++kk)                       \
      acc[(MF0) + mf][(NF0) + nf] = __builtin_amdgcn_mfma_f32_16x16x32_bf16( \
          af[(MF0) + mf][kk], bfr[(NF0) + nf][kk], acc[(MF0) + mf][(NF0) + nf], 0, 0, 0); \
    __builtin_amdgcn_s_setprio(0);                                         \
  } while (0)

__global__ __launch_bounds__(512, 2) void gemm8_qkv_k(
    const bf16* __restrict__ A, const bf16* __restrict__ Bt,
    const float* __restrict__ bias,
    bf16* __restrict__ q_out, bf16* __restrict__ k_out, bf16* __restrict__ v_out,
    int M, int N, int K) {
  __shared__ __align__(16) char Lsm[2][57344];   // [buf][A:32KB | B:24KB]
  const int tid = threadIdx.x;
  const int wid = tid >> 6, l = tid & 63;
  const int lane16 = l & 15, lgrp = l >> 4;
  const int wm = wid >> 2, wn = wid & 3;

  int flat = blockIdx.y * gridDim.x + blockIdx.x;
  {
    const int cpx = (gridDim.x * gridDim.y) >> 3;
    flat = (flat & 7) * cpx + (flat >> 3);
  }
  const int bm = flat % gridDim.x;       // 0..15  (M/256)
  const int bn = flat / gridDim.x;       // 0..31  (N/192)
  const int NT = K >> 6;

  const int schunk = (l & 7) ^ ((l >> 3) & 7);
  const bf16* gA = A + (size_t)(bm * 256 + wid * 8 + (l >> 3)) * K + schunk * 8;
  const bf16* gB = Bt + (size_t)(bn * 192 + wid * 8 + (l >> 3)) * K + schunk * 8;

  auto stage_unit = [&](int mat, int t, int u, int buf) {
    const bf16* g = (mat ? gB : gA) + (size_t)(u * 64) * K + t * 64;
    gload_lds16(g, &Lsm[buf][(mat ? 32768 : 0) + u * 8192 + wid * 1024]);
  };

  f32x4 acc[8][3] = {};

#pragma unroll
  for (int u = 0; u < 4; ++u) stage_unit(0, 0, u, 0);
#pragma unroll
  for (int u = 0; u < 3; ++u) stage_unit(1, 0, u, 0);

  for (int t = 0; t < NT; ++t) {
    const int cur = t & 1;
    const char* As = &Lsm[cur][0];
    const char* Bs = &Lsm[cur][32768];
    bf16x8 af[8][2], bfr[3][2];

    WAITV0();                 // this tile's 7 stage loads landed (my wave's)
    BARRIER8();               // visible to all waves; prev tile fully done

    // ---- read all frags (ds_read) + stage t+1 (gload_lds -> buf^1)
#pragma unroll
    for (int mf = 0; mf < 8; ++mf)
#pragma unroll
      for (int kk = 0; kk < 2; ++kk) {
        int row = wm * 128 + mf * 16 + lane16;
        int ch = (kk * 4 + lgrp) ^ (lane16 & 7);
        af[mf][kk] = *(const bf16x8*)(As + row * 128 + ch * 16);
      }
#pragma unroll
    for (int nf = 0; nf < 3; ++nf)
#pragma unroll
      for (int kk = 0; kk < 2; ++kk) {
        int row = wn * 48 + nf * 16 + lane16;
        int ch = (kk * 4 + lgrp) ^ (lane16 & 7);
        bfr[nf][kk] = *(const bf16x8*)(Bs + row * 128 + ch * 16);
      }
    if (t + 1 < NT) {
#pragma unroll
      for (int u = 0; u < 4; ++u) stage_unit(0, t + 1, u, cur ^ 1);
#pragma unroll
      for (int u = 0; u < 3; ++u) stage_unit(1, t + 1, u, cur ^ 1);
    }

    // ---- all 48 MFMA; compiler interleaves with the ds_reads above
    MFMA_Q(0, 0, 3);
    MFMA_Q(4, 0, 3);
  }

  // ---- epilogue
#pragma unroll
  for (int nf = 0; nf < 3; ++nf) {
    int colg = bn * 192 + wn * 48 + nf * 16 + lane16;
    int which = colg >> 11;
    bf16* outb = (which == 0) ? q_out : (which == 1 ? k_out : v_out);
    int head = (colg >> 7) & 15, hd = colg & 127;
    float bv = bias[colg];
#pragma unroll
    for (int mf = 0; mf < 8; ++mf)
#pragma unroll
      for (int r = 0; r < 4; ++r) {
        int row = bm * 256 + wm * 128 + mf * 16 + lgrp * 4 + r;
        int bb = row >> 11, tt2 = row & 2047;
        outb[((size_t)(bb * NH + head) * TT + tt2) * HDD + hd] =
            (bf16)(acc[mf][nf][r] + bv);
      }
  }
}

// ---------------------------------------------------------------- GEMM (proj, 1-barrier 256x128)
__global__ __launch_bounds__(512, 2) void gemm4_proj_k(
    const bf16* __restrict__ A, const bf16* __restrict__ Bt,
    const float* __restrict__ bias, float* __restrict__ c_out,
    int M, int N, int K) {
  __shared__ __align__(16) char Lsm[2][49152];   // [buf][A:32KB | B:16KB]
  const int tid = threadIdx.x;
  const int wid = tid >> 6, l = tid & 63;
  const int lane16 = l & 15, lgrp = l >> 4;
  const int wm = wid >> 2, wn = wid & 3;

  int flat = blockIdx.y * gridDim.x + blockIdx.x;
  {
    const int cpx = (gridDim.x * gridDim.y) >> 3;
    flat = (flat & 7) * cpx + (flat >> 3);
  }
  const int bm = flat % gridDim.x;       // 0..15 (M/256)
  const int bn = flat / gridDim.x;       // 0..15 (N/128)
  const int NT = K >> 6;

  const int schunk = (l & 7) ^ ((l >> 3) & 7);
  const bf16* gA = A + (size_t)(bm * 256 + wid * 8 + (l >> 3)) * K + schunk * 8;
  const bf16* gB = Bt + (size_t)(bn * 128 + wid * 8 + (l >> 3)) * K + schunk * 8;

  auto stage_unit = [&](int mat, int t, int u, int buf) {
    const bf16* g = (mat ? gB : gA) + (size_t)(u * 64) * K + t * 64;
    gload_lds16(g, &Lsm[buf][(mat ? 32768 : 0) + u * 8192 + wid * 1024]);
  };

  f32x4 acc[8][2] = {};

#pragma unroll
  for (int u = 0; u < 4; ++u) stage_unit(0, 0, u, 0);
#pragma unroll
  for (int u = 0; u < 2; ++u) stage_unit(1, 0, u, 0);

  for (int t = 0; t < NT; ++t) {
    const int cur = t & 1;
    const char* As = &Lsm[cur][0];
    const char* Bs = &Lsm[cur][32768];
    bf16x8 af[8][2], bfr[2][2];

    WAITV0();
    BARRIER8();

    // ---- read all frags + stage t+1
#pragma unroll
    for (int mf = 0; mf < 8; ++mf)
#pragma unroll
      for (int kk = 0; kk < 2; ++kk) {
        int row = wm * 128 + mf * 16 + lane16;
        int ch = (kk * 4 + lgrp) ^ (lane16 & 7);
        af[mf][kk] = *(const bf16x8*)(As + row * 128 + ch * 16);
      }
#pragma unroll
    for (int nf = 0; nf < 2; ++nf)
#pragma unroll
      for (int kk = 0; kk < 2; ++kk) {
        int row = wn * 32 + nf * 16 + lane16;
        int ch = (kk * 4 + lgrp) ^ (lane16 & 7);
        bfr[nf][kk] = *(const bf16x8*)(Bs + row * 128 + ch * 16);
      }
    if (t + 1 < NT) {
#pragma unroll
      for (int u = 0; u < 4; ++u) stage_unit(0, t + 1, u, cur ^ 1);
#pragma unroll
      for (int u = 0; u < 2; ++u) stage_unit(1, t + 1, u, cur ^ 1);
    }

    // ---- all 32 MFMA
    MFMA_Q(0, 0, 2);
    MFMA_Q(4, 0, 2);
  }

  // ---- epilogue: bias + f32 row-major store
#pragma unroll
  for (int nf = 0; nf < 2; ++nf) {
    int colg = bn * 128 + wn * 32 + nf * 16 + lane16;
    float bv = bias[colg];
#pragma unroll
    for (int mf = 0; mf < 8; ++mf)
#pragma unroll
      for (int r = 0; r < 4; ++r) {
        int row = bm * 256 + wm * 128 + mf * 16 + lgrp * 4 + r;
        c_out[(size_t)row * N + colg] = acc[mf][nf][r] + bv;
      }
  }
}

// ---------------------------------------------------------------- attention
// R17 structure + R18 edit: s_setprio(1/0) around QK^T and PV MFMA clusters
// (T5, guide-measured +4-7% on attn when waves have phase skew).
__global__ __launch_bounds__(512, 2) void attn_k(
    const bf16* __restrict__ Q, const bf16* __restrict__ Kt,
    const bf16* __restrict__ V, bf16* __restrict__ Y) {
  __shared__ __align__(16) bf16 Ksm[128 * 128];   // [key][hd], chunk^=g4(key), 32KB
  __shared__ __align__(16) bf16 Vsm[128 * 128];   // [hd][key], chunk^=g4(hd), 32KB
  __shared__ __align__(16) bf16 Psm[8][16 * 128]; // per-wave P, chunk^=g4(row), 32KB
  const int tid = threadIdx.x, w = tid >> 6, l = tid & 63;
  const int lane16 = l & 15, lgrp = l >> 4;
  const int bh = blockIdx.y;
  const int b = bh >> 4, h = bh & 15;
  const size_t base = (size_t)bh * TT * HDD;

  uint4 vreg[4];
  const int vg = tid >> 4, vh8 = tid & 15;

  auto load_V = [&](int k0) {
#pragma unroll
    for (int kq = 0; kq < 4; ++kq)
      vreg[kq] = *(const uint4*)(V + base + (size_t)(k0 + vg * 4 + kq) * HDD + vh8 * 8);
  };
  auto issue_K = [&](int k0) {
#pragma unroll
    for (int i = 0; i < 4; ++i) {
      int key = w * 16 + i * 4 + (l >> 4);
      int c = (l & 15) ^ ((key ^ (key >> 3)) & 15);
      gload_lds16(Kt + base + (size_t)(k0 + key) * HDD + c * 8,
                  &Ksm[(w * 16 + i * 4) * 128 + (l & 15) * 8]);
    }
  };
  auto write_V = [&]() {
    const unsigned* dw = (const unsigned*)vreg;
    int hd0 = vh8 * 8;
#pragma unroll
    for (int j = 0; j < 8; ++j) {
      int ww = j >> 1;
      unsigned sel = (j & 1) ? 0x07060302u : 0x05040100u;
      uint2 val;
      val.x = __builtin_amdgcn_perm(dw[4 + ww], dw[0 + ww], sel);
      val.y = __builtin_amdgcn_perm(dw[12 + ww], dw[8 + ww], sel);
      int hd = hd0 + j;
      int ch = (vg >> 1) ^ ((hd ^ (hd >> 3)) & 15);
      *(uint2*)((char*)Vsm + hd * 256 + (ch << 4) + ((vg & 1) << 3)) = val;
    }
  };

  for (int pass = 0; pass < 2; ++pass) {
    const int qt = (pass == 0) ? (int)blockIdx.x : 15 - (int)blockIdx.x;
    const int q0 = qt * 128;
    const int nt = qt + 1;

    load_V(0);              // prologue V prefetch (overlaps Q-frag loads)

    bf16x8 qa[4];
    {
      int row = q0 + w * 16 + lane16;
#pragma unroll
      for (int kk = 0; kk < 4; ++kk)
        qa[kk] = *(const bf16x8*)(Q + base + (size_t)row * HDD + kk * 32 + lgrp * 8);
    }

    f32x4 o[8] = {};
    float m_r[4], l_r[4];
#pragma unroll
    for (int r = 0; r < 4; ++r) { m_r[r] = NEG_INF; l_r[r] = 0.f; }

    for (int kt = 0; kt < nt; ++kt) {
      const int k0 = kt * 128;
      issue_K(k0);          // K direct-to-LDS (linear dest, single buffer)
      write_V();            // vreg prefetched last tile -> zero wait
      __syncthreads();      // drains K gloads + V ds_writes: staged for all
      if (kt + 1 < nt) load_V(k0 + 128);   // lands under compute

      // ---- S = Q K^T  (logits already in log2 domain via QSCALE)
      f32x4 s[8] = {};
      __builtin_amdgcn_s_setprio(1);
#pragma unroll
      for (int kk = 0; kk < 4; ++kk) {
#pragma unroll
        for (int nf = 0; nf < 8; ++nf) {
          int key = nf * 16 + lane16;
          int ch = (kk * 4 + lgrp) ^ ((key ^ (key >> 3)) & 15);
          bf16x8 kf = *(const bf16x8*)((char*)Ksm + key * 256 + (ch << 4));
          s[nf] = __builtin_amdgcn_mfma_f32_16x16x32_bf16(
              qa[kk], kf, s[nf], 0, 0, 0);
        }
      }
      __builtin_amdgcn_s_setprio(0);

      // ---- causal mask (diagonal tile only; wave-uniform branch)
      if (k0 + 127 > q0 + w * 16) {
        const int rowbase = q0 + w * 16 + lgrp * 4;
#pragma unroll
        for (int nf = 0; nf < 8; ++nf) {
          int col = k0 + nf * 16 + lane16;
#pragma unroll
          for (int r = 0; r < 4; ++r)
            if (col > rowbase + r) s[nf][r] = -3.0e38f;
        }
      }

      // ---- online softmax (log2 domain, unconditional rescale)
#pragma unroll
      for (int r = 0; r < 4; ++r) {
        float tm = fmaxf(fmaxf(fmaxf(s[0][r], s[1][r]), fmaxf(s[2][r], s[3][r])),
                         fmaxf(fmaxf(s[4][r], s[5][r]), fmaxf(s[6][r], s[7][r])));
        tm = fmaxf(tm, __shfl_xor(tm, 1));
        tm = fmaxf(tm, __shfl_xor(tm, 2));
        tm = fmaxf(tm, __shfl_xor(tm, 4));
        tm = fmaxf(tm, __shfl_xor(tm, 8));
        float mo = m_r[r];
        float mn = fmaxf(mo, tm);
        float alpha = exp2f(mo - mn);
        m_r[r] = mn;
        float rs = 0.f;
#pragma unroll
        for (int nf = 0; nf < 8; ++nf) {
          float p = exp2f(s[nf][r] - mn);
          s[nf][r] = p;
          rs += p;
        }
        rs += __shfl_xor(rs, 1);
        rs += __shfl_xor(rs, 2);
        rs += __shfl_xor(rs, 4);
        rs += __shfl_xor(rs, 8);
        l_r[r] = l_r[r] * alpha + rs;
#pragma unroll
        for (int nf = 0; nf < 8; ++nf) o[nf][r] *= alpha;
      }

      // ---- P -> LDS (per-wave region, same-wave readback; no barrier)
#pragma unroll
      for (int nf = 0; nf < 8; ++nf)
#pragma unroll
        for (int r = 0; r < 4; ++r) {
          int rl = lgrp * 4 + r;
          int ch = (2 * nf + (lane16 >> 3)) ^ ((rl ^ (rl >> 3)) & 15);
          int byte = rl * 256 + (ch << 4) + ((lane16 & 7) << 1);
          *(bf16*)((char*)&Psm[w][0] + byte) = (bf16)s[nf][r];
        }
      bf16x8 pa[4];
#pragma unroll
      for (int kk = 0; kk < 4; ++kk) {
        int ch = (kk * 4 + lgrp) ^ ((lane16 ^ (lane16 >> 3)) & 15);
        pa[kk] = *(const bf16x8*)((char*)&Psm[w][0] + lane16 * 256 + (ch << 4));
      }

      // ---- O += P V
      __builtin_amdgcn_s_setprio(1);
#pragma unroll
      for (int nf = 0; nf < 8; ++nf) {
#pragma unroll
        for (int kk = 0; kk < 4; ++kk) {
          int hd = nf * 16 + lane16;
          int ch = (kk * 4 + lgrp) ^ ((hd ^ (hd >> 3)) & 15);
          bf16x8 vf = *(const bf16x8*)((char*)Vsm + hd * 256 + (ch << 4));
          o[nf] = __builtin_amdgcn_mfma_f32_16x16x32_bf16(
              pa[kk], vf, o[nf], 0, 0, 0);
        }
      }
      __builtin_amdgcn_s_setprio(0);

      __syncthreads();      // all reads of Ksm/Vsm done; V prefetch landed
    }

    // ---- finalize: O / l -> Y (b,t,D) bf16
#pragma unroll
    for (int r = 0; r < 4; ++r) {
      float inv = 1.0f / l_r[r];
      int row = q0 + w * 16 + lgrp * 4 + r;
#pragma unroll
      for (int nf = 0; nf < 8; ++nf) {
        int hd = nf * 16 + lane16;
        Y[(size_t)(b * TT + row) * DM + h * HDD + hd] = (bf16)(o[nf][r] * inv);
      }
    }
  }
}

// ---------------------------------------------------------------- launch
extern "C" void kernel_launch(void* const* d_in, const int* in_sizes, int n_in,
                              void* d_out, int out_size, void* d_ws, size_t ws_size,
                              hipStream_t stream) {
  const float* x = (const float*)d_in[0];
  const float* Wqkv = (const float*)d_in[2];
  const float* bqkv = (const float*)d_in[3];
  const float* Wproj = (const float*)d_in[4];
  const float* bproj = (const float*)d_in[5];
  float* out = (float*)d_out;

  char* ws = (char*)d_ws;
  bf16* xb = (bf16*)ws;                 ws += (size_t)MM * DM * 2;
  bf16* Wqkvt = (bf16*)ws;              ws += (size_t)NQKV * DM * 2;
  bf16* Wprojt = (bf16*)ws;             ws += (size_t)DM * DM * 2;
  bf16* kb = (bf16*)ws;                 ws += (size_t)MM * DM * 2;
  bf16* vb = (bf16*)ws;                 ws += (size_t)MM * DM * 2;
  float* cosT = (float*)ws;             ws += (size_t)TT * 64 * 4;
  float* sinT = (float*)ws;             ws += (size_t)TT * 64 * 4;
  bf16* qb = (bf16*)d_out;              // q lives in d_out (overwritten by proj)
  bf16* yb = xb;                        // xb dead after QKV GEMM

  rope_table_k<<<dim3(512), dim3(256), 0, stream>>>(cosT, sinT);
  convert_x_k<<<dim3(4096), dim3(256), 0, stream>>>(x, xb);
  transpose_w_k<<<dim3(96, 32), dim3(256), 0, stream>>>(Wqkv, Wqkvt, DM, NQKV);
  transpose_w_k<<<dim3(32, 32), dim3(256), 0, stream>>>(Wproj, Wprojt, DM, DM);

  gemm8_qkv_k<<<dim3(16, 32), dim3(512), 0, stream>>>(
      xb, Wqkvt, bqkv, qb, kb, vb, MM, NQKV, DM);

  rope_apply_k<<<dim3(8192), dim3(256), 0, stream>>>(qb, kb, cosT, sinT);

  attn_k<<<dim3(8, 32), dim3(512), 0, stream>>>(qb, kb, vb, yb);

  gemm4_proj_k<<<dim3(16, 16), dim3(512), 0, stream>>>(
      yb, Wprojt, bproj, out, MM, DM, DM);
}

// Round 19
// 255.652 us; speedup vs baseline: 1.1700x; 1.0303x over previous
//
#include <hip/hip_runtime.h>
#include <hip/hip_bf16.h>
#include <stdint.h>
#include <stddef.h>

typedef __bf16 bf16;
typedef __attribute__((ext_vector_type(8))) __bf16 bf16x8;
typedef __attribute__((ext_vector_type(4))) __bf16 bf16x4;
typedef __attribute__((ext_vector_type(4))) float f32x4;

#define DM 2048      // model dim
#define NH 16        // heads
#define HDD 128      // head dim
#define BB 2         // batch
#define TT 2048      // seq len
#define MM (BB*TT)   // 4096 rows
#define NQKV (3*DM)  // 6144

#define L2E 1.4426950408889634f
#define ATT_SCALE 0.08838834764831845f       // 1/sqrt(128)
#define QSCALE (ATT_SCALE * L2E)             // folded into Q: logits in log2 domain
#define NEG_INF (-__builtin_inff())

static_assert(sizeof(bf16x8) == 16, "bf16x8 must be 16B");

#define SB0() __builtin_amdgcn_sched_barrier(0)
#define WAITV0() { asm volatile("s_waitcnt vmcnt(0)" ::: "memory"); SB0(); }
#define BARRIER8() { SB0(); __builtin_amdgcn_s_barrier(); SB0(); }

// ---------------------------------------------------------------- helpers
static __device__ __forceinline__ void gload_lds16(const void* g, void* l) {
  __builtin_amdgcn_global_load_lds(
      (__attribute__((address_space(1))) void*)g,
      (__attribute__((address_space(3))) void*)l, 16, 0, 0);
}

// ---------------------------------------------------------------- fused pre-pass
// One launch, 4 independent jobs selected by blockIdx range:
//   [0,512)        rope cos/sin table (2048 x 64)
//   [512,4608)     x f32 -> bf16 convert (8M elements)
//   [4608,7680)    Wqkv (K x N) f32 -> Wt (N x K) bf16, 64x64 tiles (96 x 32)
//   [7680,8704)    Wproj transpose (32 x 32 tiles)
__global__ __launch_bounds__(256) void prepass_k(
    const float* __restrict__ x, bf16* __restrict__ xb,
    const float* __restrict__ Wqkv, bf16* __restrict__ Wqkvt,
    const float* __restrict__ Wproj, bf16* __restrict__ Wprojt,
    float* __restrict__ cT, float* __restrict__ sT) {
  __shared__ float tile[64][65];
  const int blk = blockIdx.x;
  const int t = threadIdx.x;

  if (blk < 512) {                       // ---- rope table
    int id = blk * 256 + t;
    int tt = id >> 6, i = id & 63;
    float freq = powf(10000.0f, -(float)i * (1.0f / 64.0f));
    float theta = (float)tt * freq;
    float s, c;
    __sincosf(theta, &s, &c);
    cT[id] = c;
    sT[id] = s;
  } else if (blk < 4608) {               // ---- convert x
    size_t id = (size_t)(blk - 512) * 256 + t;
    size_t o = id * 8;
    float4 a = *(const float4*)(x + o);
    float4 b = *(const float4*)(x + o + 4);
    bf16x8 r;
    r[0] = (bf16)a.x; r[1] = (bf16)a.y; r[2] = (bf16)a.z; r[3] = (bf16)a.w;
    r[4] = (bf16)b.x; r[5] = (bf16)b.y; r[6] = (bf16)b.z; r[7] = (bf16)b.w;
    *(bf16x8*)(xb + o) = r;
  } else {                               // ---- weight transposes
    const float* W;
    bf16* Wt;
    int bx, by, N;
    if (blk < 7680) {
      int bb = blk - 4608;               // 96 x 32
      bx = bb % 96; by = bb / 96;
      W = Wqkv; Wt = Wqkvt; N = NQKV;
    } else {
      int bb = blk - 7680;               // 32 x 32
      bx = bb % 32; by = bb / 32;
      W = Wproj; Wt = Wprojt; N = DM;
    }
    const int K = DM;
    int n0 = bx * 64, k0 = by * 64;
#pragma unroll
    for (int i = 0; i < 16; ++i) {
      int idx = t + i * 256;
      int r = idx >> 6, c = idx & 63;
      tile[r][c] = W[(size_t)(k0 + r) * N + n0 + c];
    }
    __syncthreads();
#pragma unroll
    for (int i = 0; i < 16; ++i) {
      int idx = t + i * 256;
      int r = idx >> 6, c = idx & 63;
      Wt[(size_t)(n0 + r) * K + k0 + c] = (bf16)tile[c][r];
    }
  }
}

// in-place RoPE on BOTH q and k in one launch (block-uniform buffer select);
// q gets QSCALE folded (log2-domain logits).
__global__ __launch_bounds__(256) void rope_apply_k(bf16* __restrict__ qbuf,
                                                    bf16* __restrict__ kbuf,
                                                    const float* __restrict__ cT,
                                                    const float* __restrict__ sT) {
  int id = blockIdx.x * 256 + threadIdx.x;   // < 64*2048*16
  int i4 = id & 15;
  int t = (id >> 4) & 2047;
  int bh64 = id >> 15;                       // 0..63; <32 -> q, >=32 -> k
  const bool isq = bh64 < 32;
  bf16* buf = isq ? qbuf : kbuf;
  const float scl = isq ? (float)QSCALE : 1.0f;
  int bh = isq ? bh64 : (bh64 - 32);
  int idx0 = i4 * 4;
  size_t base = ((size_t)bh * TT + t) * HDD;
  bf16x4 x1 = *(const bf16x4*)(buf + base + idx0);
  bf16x4 x2 = *(const bf16x4*)(buf + base + 64 + idx0);
  float4 ct = *(const float4*)(cT + t * 64 + idx0);
  float4 st = *(const float4*)(sT + t * 64 + idx0);
  bf16x4 o1, o2;
  float c0, s0, a, b2;
#pragma unroll
  for (int j = 0; j < 4; ++j) {
    c0 = (j == 0) ? ct.x : (j == 1) ? ct.y : (j == 2) ? ct.z : ct.w;
    s0 = (j == 0) ? st.x : (j == 1) ? st.y : (j == 2) ? st.z : st.w;
    a = (float)x1[j];
    b2 = (float)x2[j];
    o1[j] = (bf16)((a * c0 - b2 * s0) * scl);
    o2[j] = (bf16)((a * s0 + b2 * c0) * scl);
  }
  *(bf16x4*)(buf + base + idx0) = o1;
  *(bf16x4*)(buf + base + 64 + idx0) = o2;
}

// ---------------------------------------------------------------- GEMM (QKV, 1-barrier 256x192)
#define MFMA_Q(MF0, NF0, NCNT)                                             \
  do {                                                                     \
    __builtin_amdgcn_s_setprio(1);                                         \
    _Pragma("unroll") for (int mf = 0; mf < 4; ++mf)                       \
    _Pragma("unroll") for (int nf = 0; nf < (NCNT); ++nf)                  \
    _Pragma("unroll") for (int kk = 0; kk < 2; ++kk)                       \
      acc[(MF0) + mf][(NF0) + nf] = __builtin_amdgcn_mfma_f32_16x16x32_bf16( \
          af[(MF0) + mf][kk], bfr[(NF0) + nf][kk], acc[(MF0) + mf][(NF0) + nf], 0, 0, 0); \
    __builtin_amdgcn_s_setprio(0);                                         \
  } while (0)

__global__ __launch_bounds__(512, 2) void gemm8_qkv_k(
    const bf16* __restrict__ A, const bf16* __restrict__ Bt,
    const float* __restrict__ bias,
    bf16* __restrict__ q_out, bf16* __restrict__ k_out, bf16* __restrict__ v_out,
    int M, int N, int K) {
  __shared__ __align__(16) char Lsm[2][57344];   // [buf][A:32KB | B:24KB]
  const int tid = threadIdx.x;
  const int wid = tid >> 6, l = tid & 63;
  const int lane16 = l & 15, lgrp = l >> 4;
  const int wm = wid >> 2, wn = wid & 3;

  int flat = blockIdx.y * gridDim.x + blockIdx.x;
  {
    const int cpx = (gridDim.x * gridDim.y) >> 3;
    flat = (flat & 7) * cpx + (flat >> 3);
  }
  const int bm = flat % gridDim.x;       // 0..15  (M/256)
  const int bn = flat / gridDim.x;       // 0..31  (N/192)
  const int NT = K >> 6;

  const int schunk = (l & 7) ^ ((l >> 3) & 7);
  const bf16* gA = A + (size_t)(bm * 256 + wid * 8 + (l >> 3)) * K + schunk * 8;
  const bf16* gB = Bt + (size_t)(bn * 192 + wid * 8 + (l >> 3)) * K + schunk * 8;

  auto stage_unit = [&](int mat, int t, int u, int buf) {
    const bf16* g = (mat ? gB : gA) + (size_t)(u * 64) * K + t * 64;
    gload_lds16(g, &Lsm[buf][(mat ? 32768 : 0) + u * 8192 + wid * 1024]);
  };

  f32x4 acc[8][3] = {};

#pragma unroll
  for (int u = 0; u < 4; ++u) stage_unit(0, 0, u, 0);
#pragma unroll
  for (int u = 0; u < 3; ++u) stage_unit(1, 0, u, 0);

  for (int t = 0; t < NT; ++t) {
    const int cur = t & 1;
    const char* As = &Lsm[cur][0];
    const char* Bs = &Lsm[cur][32768];
    bf16x8 af[8][2], bfr[3][2];

    WAITV0();                 // this tile's 7 stage loads landed (my wave's)
    BARRIER8();               // visible to all waves; prev tile fully done

    // ---- read all frags (ds_read) + stage t+1 (gload_lds -> buf^1)
#pragma unroll
    for (int mf = 0; mf < 8; ++mf)
#pragma unroll
      for (int kk = 0; kk < 2; ++kk) {
        int row = wm * 128 + mf * 16 + lane16;
        int ch = (kk * 4 + lgrp) ^ (lane16 & 7);
        af[mf][kk] = *(const bf16x8*)(As + row * 128 + ch * 16);
      }
#pragma unroll
    for (int nf = 0; nf < 3; ++nf)
#pragma unroll
      for (int kk = 0; kk < 2; ++kk) {
        int row = wn * 48 + nf * 16 + lane16;
        int ch = (kk * 4 + lgrp) ^ (lane16 & 7);
        bfr[nf][kk] = *(const bf16x8*)(Bs + row * 128 + ch * 16);
      }
    if (t + 1 < NT) {
#pragma unroll
      for (int u = 0; u < 4; ++u) stage_unit(0, t + 1, u, cur ^ 1);
#pragma unroll
      for (int u = 0; u < 3; ++u) stage_unit(1, t + 1, u, cur ^ 1);
    }

    // ---- all 48 MFMA; compiler interleaves with the ds_reads above
    MFMA_Q(0, 0, 3);
    MFMA_Q(4, 0, 3);
  }

  // ---- epilogue
#pragma unroll
  for (int nf = 0; nf < 3; ++nf) {
    int colg = bn * 192 + wn * 48 + nf * 16 + lane16;
    int which = colg >> 11;
    bf16* outb = (which == 0) ? q_out : (which == 1 ? k_out : v_out);
    int head = (colg >> 7) & 15, hd = colg & 127;
    float bv = bias[colg];
#pragma unroll
    for (int mf = 0; mf < 8; ++mf)
#pragma unroll
      for (int r = 0; r < 4; ++r) {
        int row = bm * 256 + wm * 128 + mf * 16 + lgrp * 4 + r;
        int bb = row >> 11, tt2 = row & 2047;
        outb[((size_t)(bb * NH + head) * TT + tt2) * HDD + hd] =
            (bf16)(acc[mf][nf][r] + bv);
      }
  }
}

// ---------------------------------------------------------------- GEMM (proj, 1-barrier 256x128)
__global__ __launch_bounds__(512, 2) void gemm4_proj_k(
    const bf16* __restrict__ A, const bf16* __restrict__ Bt,
    const float* __restrict__ bias, float* __restrict__ c_out,
    int M, int N, int K) {
  __shared__ __align__(16) char Lsm[2][49152];   // [buf][A:32KB | B:16KB]
  const int tid = threadIdx.x;
  const int wid = tid >> 6, l = tid & 63;
  const int lane16 = l & 15, lgrp = l >> 4;
  const int wm = wid >> 2, wn = wid & 3;

  int flat = blockIdx.y * gridDim.x + blockIdx.x;
  {
    const int cpx = (gridDim.x * gridDim.y) >> 3;
    flat = (flat & 7) * cpx + (flat >> 3);
  }
  const int bm = flat % gridDim.x;       // 0..15 (M/256)
  const int bn = flat / gridDim.x;       // 0..15 (N/128)
  const int NT = K >> 6;

  const int schunk = (l & 7) ^ ((l >> 3) & 7);
  const bf16* gA = A + (size_t)(bm * 256 + wid * 8 + (l >> 3)) * K + schunk * 8;
  const bf16* gB = Bt + (size_t)(bn * 128 + wid * 8 + (l >> 3)) * K + schunk * 8;

  auto stage_unit = [&](int mat, int t, int u, int buf) {
    const bf16* g = (mat ? gB : gA) + (size_t)(u * 64) * K + t * 64;
    gload_lds16(g, &Lsm[buf][(mat ? 32768 : 0) + u * 8192 + wid * 1024]);
  };

  f32x4 acc[8][2] = {};

#pragma unroll
  for (int u = 0; u < 4; ++u) stage_unit(0, 0, u, 0);
#pragma unroll
  for (int u = 0; u < 2; ++u) stage_unit(1, 0, u, 0);

  for (int t = 0; t < NT; ++t) {
    const int cur = t & 1;
    const char* As = &Lsm[cur][0];
    const char* Bs = &Lsm[cur][32768];
    bf16x8 af[8][2], bfr[2][2];

    WAITV0();
    BARRIER8();

    // ---- read all frags + stage t+1
#pragma unroll
    for (int mf = 0; mf < 8; ++mf)
#pragma unroll
      for (int kk = 0; kk < 2; ++kk) {
        int row = wm * 128 + mf * 16 + lane16;
        int ch = (kk * 4 + lgrp) ^ (lane16 & 7);
        af[mf][kk] = *(const bf16x8*)(As + row * 128 + ch * 16);
      }
#pragma unroll
    for (int nf = 0; nf < 2; ++nf)
#pragma unroll
      for (int kk = 0; kk < 2; ++kk) {
        int row = wn * 32 + nf * 16 + lane16;
        int ch = (kk * 4 + lgrp) ^ (lane16 & 7);
        bfr[nf][kk] = *(const bf16x8*)(Bs + row * 128 + ch * 16);
      }
    if (t + 1 < NT) {
#pragma unroll
      for (int u = 0; u < 4; ++u) stage_unit(0, t + 1, u, cur ^ 1);
#pragma unroll
      for (int u = 0; u < 2; ++u) stage_unit(1, t + 1, u, cur ^ 1);
    }

    // ---- all 32 MFMA
    MFMA_Q(0, 0, 2);
    MFMA_Q(4, 0, 2);
  }

  // ---- epilogue: bias + f32 row-major store
#pragma unroll
  for (int nf = 0; nf < 2; ++nf) {
    int colg = bn * 128 + wn * 32 + nf * 16 + lane16;
    float bv = bias[colg];
#pragma unroll
    for (int mf = 0; mf < 8; ++mf)
#pragma unroll
      for (int r = 0; r < 4; ++r) {
        int row = bm * 256 + wm * 128 + mf * 16 + lgrp * 4 + r;
        c_out[(size_t)row * N + colg] = acc[mf][nf][r] + bv;
      }
  }
}

// ---------------------------------------------------------------- attention
// R18-proven: 4-bit swizzle K/V/P; K gload_lds single-buffer; V reg-prefetch
// into compute; log2-domain softmax; setprio around MFMA clusters.
__global__ __launch_bounds__(512, 2) void attn_k(
    const bf16* __restrict__ Q, const bf16* __restrict__ Kt,
    const bf16* __restrict__ V, bf16* __restrict__ Y) {
  __shared__ __align__(16) bf16 Ksm[128 * 128];   // [key][hd], chunk^=g4(key), 32KB
  __shared__ __align__(16) bf16 Vsm[128 * 128];   // [hd][key], chunk^=g4(hd), 32KB
  __shared__ __align__(16) bf16 Psm[8][16 * 128]; // per-wave P, chunk^=g4(row), 32KB
  const int tid = threadIdx.x, w = tid >> 6, l = tid & 63;
  const int lane16 = l & 15, lgrp = l >> 4;
  const int bh = blockIdx.y;
  const int b = bh >> 4, h = bh & 15;
  const size_t base = (size_t)bh * TT * HDD;

  uint4 vreg[4];
  const int vg = tid >> 4, vh8 = tid & 15;

  auto load_V = [&](int k0) {
#pragma unroll
    for (int kq = 0; kq < 4; ++kq)
      vreg[kq] = *(const uint4*)(V + base + (size_t)(k0 + vg * 4 + kq) * HDD + vh8 * 8);
  };
  auto issue_K = [&](int k0) {
#pragma unroll
    for (int i = 0; i < 4; ++i) {
      int key = w * 16 + i * 4 + (l >> 4);
      int c = (l & 15) ^ ((key ^ (key >> 3)) & 15);
      gload_lds16(Kt + base + (size_t)(k0 + key) * HDD + c * 8,
                  &Ksm[(w * 16 + i * 4) * 128 + (l & 15) * 8]);
    }
  };
  auto write_V = [&]() {
    const unsigned* dw = (const unsigned*)vreg;
    int hd0 = vh8 * 8;
#pragma unroll
    for (int j = 0; j < 8; ++j) {
      int ww = j >> 1;
      unsigned sel = (j & 1) ? 0x07060302u : 0x05040100u;
      uint2 val;
      val.x = __builtin_amdgcn_perm(dw[4 + ww], dw[0 + ww], sel);
      val.y = __builtin_amdgcn_perm(dw[12 + ww], dw[8 + ww], sel);
      int hd = hd0 + j;
      int ch = (vg >> 1) ^ ((hd ^ (hd >> 3)) & 15);
      *(uint2*)((char*)Vsm + hd * 256 + (ch << 4) + ((vg & 1) << 3)) = val;
    }
  };

  for (int pass = 0; pass < 2; ++pass) {
    const int qt = (pass == 0) ? (int)blockIdx.x : 15 - (int)blockIdx.x;
    const int q0 = qt * 128;
    const int nt = qt + 1;

    load_V(0);              // prologue V prefetch (overlaps Q-frag loads)

    bf16x8 qa[4];
    {
      int row = q0 + w * 16 + lane16;
#pragma unroll
      for (int kk = 0; kk < 4; ++kk)
        qa[kk] = *(const bf16x8*)(Q + base + (size_t)row * HDD + kk * 32 + lgrp * 8);
    }

    f32x4 o[8] = {};
    float m_r[4], l_r[4];
#pragma unroll
    for (int r = 0; r < 4; ++r) { m_r[r] = NEG_INF; l_r[r] = 0.f; }

    for (int kt = 0; kt < nt; ++kt) {
      const int k0 = kt * 128;
      issue_K(k0);          // K direct-to-LDS (linear dest, single buffer)
      write_V();            // vreg prefetched last tile -> zero wait
      __syncthreads();      // drains K gloads + V ds_writes: staged for all
      if (kt + 1 < nt) load_V(k0 + 128);   // lands under compute

      // ---- S = Q K^T  (logits already in log2 domain via QSCALE)
      f32x4 s[8] = {};
      __builtin_amdgcn_s_setprio(1);
#pragma unroll
      for (int kk = 0; kk < 4; ++kk) {
#pragma unroll
        for (int nf = 0; nf < 8; ++nf) {
          int key = nf * 16 + lane16;
          int ch = (kk * 4 + lgrp) ^ ((key ^ (key >> 3)) & 15);
          bf16x8 kf = *(const bf16x8*)((char*)Ksm + key * 256 + (ch << 4));
          s[nf] = __builtin_amdgcn_mfma_f32_16x16x32_bf16(
              qa[kk], kf, s[nf], 0, 0, 0);
        }
      }
      __builtin_amdgcn_s_setprio(0);

      // ---- causal mask (diagonal tile only; wave-uniform branch)
      if (k0 + 127 > q0 + w * 16) {
        const int rowbase = q0 + w * 16 + lgrp * 4;
#pragma unroll
        for (int nf = 0; nf < 8; ++nf) {
          int col = k0 + nf * 16 + lane16;
#pragma unroll
          for (int r = 0; r < 4; ++r)
            if (col > rowbase + r) s[nf][r] = -3.0e38f;
        }
      }

      // ---- online softmax (log2 domain, unconditional rescale)
#pragma unroll
      for (int r = 0; r < 4; ++r) {
        float tm = fmaxf(fmaxf(fmaxf(s[0][r], s[1][r]), fmaxf(s[2][r], s[3][r])),
                         fmaxf(fmaxf(s[4][r], s[5][r]), fmaxf(s[6][r], s[7][r])));
        tm = fmaxf(tm, __shfl_xor(tm, 1));
        tm = fmaxf(tm, __shfl_xor(tm, 2));
        tm = fmaxf(tm, __shfl_xor(tm, 4));
        tm = fmaxf(tm, __shfl_xor(tm, 8));
        float mo = m_r[r];
        float mn = fmaxf(mo, tm);
        float alpha = exp2f(mo - mn);
        m_r[r] = mn;
        float rs = 0.f;
#pragma unroll
        for (int nf = 0; nf < 8; ++nf) {
          float p = exp2f(s[nf][r] - mn);
          s[nf][r] = p;
          rs += p;
        }
        rs += __shfl_xor(rs, 1);
        rs += __shfl_xor(rs, 2);
        rs += __shfl_xor(rs, 4);
        rs += __shfl_xor(rs, 8);
        l_r[r] = l_r[r] * alpha + rs;
#pragma unroll
        for (int nf = 0; nf < 8; ++nf) o[nf][r] *= alpha;
      }

      // ---- P -> LDS (per-wave region, same-wave readback; no barrier)
#pragma unroll
      for (int nf = 0; nf < 8; ++nf)
#pragma unroll
        for (int r = 0; r < 4; ++r) {
          int rl = lgrp * 4 + r;
          int ch = (2 * nf + (lane16 >> 3)) ^ ((rl ^ (rl >> 3)) & 15);
          int byte = rl * 256 + (ch << 4) + ((lane16 & 7) << 1);
          *(bf16*)((char*)&Psm[w][0] + byte) = (bf16)s[nf][r];
        }
      bf16x8 pa[4];
#pragma unroll
      for (int kk = 0; kk < 4; ++kk) {
        int ch = (kk * 4 + lgrp) ^ ((lane16 ^ (lane16 >> 3)) & 15);
        pa[kk] = *(const bf16x8*)((char*)&Psm[w][0] + lane16 * 256 + (ch << 4));
      }

      // ---- O += P V
      __builtin_amdgcn_s_setprio(1);
#pragma unroll
      for (int nf = 0; nf < 8; ++nf) {
#pragma unroll
        for (int kk = 0; kk < 4; ++kk) {
          int hd = nf * 16 + lane16;
          int ch = (kk * 4 + lgrp) ^ ((hd ^ (hd >> 3)) & 15);
          bf16x8 vf = *(const bf16x8*)((char*)Vsm + hd * 256 + (ch << 4));
          o[nf] = __builtin_amdgcn_mfma_f32_16x16x32_bf16(
              pa[kk], vf, o[nf], 0, 0, 0);
        }
      }
      __builtin_amdgcn_s_setprio(0);

      __syncthreads();      // all reads of Ksm/Vsm done; V prefetch landed
    }

    // ---- finalize: O / l -> Y (b,t,D) bf16
#pragma unroll
    for (int r = 0; r < 4; ++r) {
      float inv = 1.0f / l_r[r];
      int row = q0 + w * 16 + lgrp * 4 + r;
#pragma unroll
      for (int nf = 0; nf < 8; ++nf) {
        int hd = nf * 16 + lane16;
        Y[(size_t)(b * TT + row) * DM + h * HDD + hd] = (bf16)(o[nf][r] * inv);
      }
    }
  }
}

// ---------------------------------------------------------------- launch
extern "C" void kernel_launch(void* const* d_in, const int* in_sizes, int n_in,
                              void* d_out, int out_size, void* d_ws, size_t ws_size,
                              hipStream_t stream) {
  const float* x = (const float*)d_in[0];
  const float* Wqkv = (const float*)d_in[2];
  const float* bqkv = (const float*)d_in[3];
  const float* Wproj = (const float*)d_in[4];
  const float* bproj = (const float*)d_in[5];
  float* out = (float*)d_out;

  char* ws = (char*)d_ws;
  bf16* xb = (bf16*)ws;                 ws += (size_t)MM * DM * 2;
  bf16* Wqkvt = (bf16*)ws;              ws += (size_t)NQKV * DM * 2;
  bf16* Wprojt = (bf16*)ws;             ws += (size_t)DM * DM * 2;
  bf16* kb = (bf16*)ws;                 ws += (size_t)MM * DM * 2;
  bf16* vb = (bf16*)ws;                 ws += (size_t)MM * DM * 2;
  float* cosT = (float*)ws;             ws += (size_t)TT * 64 * 4;
  float* sinT = (float*)ws;             ws += (size_t)TT * 64 * 4;
  bf16* qb = (bf16*)d_out;              // q lives in d_out (overwritten by proj)
  bf16* yb = xb;                        // xb dead after QKV GEMM

  prepass_k<<<dim3(8704), dim3(256), 0, stream>>>(
      x, xb, Wqkv, Wqkvt, Wproj, Wprojt, cosT, sinT);

  gemm8_qkv_k<<<dim3(16, 32), dim3(512), 0, stream>>>(
      xb, Wqkvt, bqkv, qb, kb, vb, MM, NQKV, DM);

  rope_apply_k<<<dim3(8192), dim3(256), 0, stream>>>(qb, kb, cosT, sinT);

  attn_k<<<dim3(8, 32), dim3(512), 0, stream>>>(qb, kb, vb, yb);

  gemm4_proj_k<<<dim3(16, 16), dim3(512), 0, stream>>>(
      yb, Wprojt, bproj, out, MM, DM, DM);
}

// Round 20
// 252.971 us; speedup vs baseline: 1.1824x; 1.0106x over previous
//
#include <hip/hip_runtime.h>
#include <hip/hip_bf16.h>
#include <stdint.h>
#include <stddef.h>

typedef __bf16 bf16;
typedef __attribute__((ext_vector_type(8))) __bf16 bf16x8;
typedef __attribute__((ext_vector_type(4))) __bf16 bf16x4;
typedef __attribute__((ext_vector_type(4))) float f32x4;

#define DM 2048      // model dim
#define NH 16        // heads
#define HDD 128      // head dim
#define BB 2         // batch
#define TT 2048      // seq len
#define MM (BB*TT)   // 4096 rows
#define NQKV (3*DM)  // 6144

#define L2E 1.4426950408889634f
#define ATT_SCALE 0.08838834764831845f       // 1/sqrt(128)
#define QSCALE (ATT_SCALE * L2E)             // folded into Q: logits in log2 domain
#define NEG_INF (-__builtin_inff())

static_assert(sizeof(bf16x8) == 16, "bf16x8 must be 16B");

#define SB0() __builtin_amdgcn_sched_barrier(0)
#define WAITV0() { asm volatile("s_waitcnt vmcnt(0)" ::: "memory"); SB0(); }
#define BARRIER8() { SB0(); __builtin_amdgcn_s_barrier(); SB0(); }

// ---------------------------------------------------------------- helpers
static __device__ __forceinline__ void gload_lds16(const void* g, void* l) {
  __builtin_amdgcn_global_load_lds(
      (__attribute__((address_space(1))) void*)g,
      (__attribute__((address_space(3))) void*)l, 16, 0, 0);
}

// ---------------------------------------------------------------- fused pre-pass
__global__ __launch_bounds__(256) void prepass_k(
    const float* __restrict__ x, bf16* __restrict__ xb,
    const float* __restrict__ Wqkv, bf16* __restrict__ Wqkvt,
    const float* __restrict__ Wproj, bf16* __restrict__ Wprojt,
    float* __restrict__ cT, float* __restrict__ sT) {
  __shared__ float tile[64][65];
  const int blk = blockIdx.x;
  const int t = threadIdx.x;

  if (blk < 512) {                       // ---- rope table
    int id = blk * 256 + t;
    int tt = id >> 6, i = id & 63;
    float freq = powf(10000.0f, -(float)i * (1.0f / 64.0f));
    float theta = (float)tt * freq;
    float s, c;
    __sincosf(theta, &s, &c);
    cT[id] = c;
    sT[id] = s;
  } else if (blk < 4608) {               // ---- convert x
    size_t id = (size_t)(blk - 512) * 256 + t;
    size_t o = id * 8;
    float4 a = *(const float4*)(x + o);
    float4 b = *(const float4*)(x + o + 4);
    bf16x8 r;
    r[0] = (bf16)a.x; r[1] = (bf16)a.y; r[2] = (bf16)a.z; r[3] = (bf16)a.w;
    r[4] = (bf16)b.x; r[5] = (bf16)b.y; r[6] = (bf16)b.z; r[7] = (bf16)b.w;
    *(bf16x8*)(xb + o) = r;
  } else {                               // ---- weight transposes
    const float* W;
    bf16* Wt;
    int bx, by, N;
    if (blk < 7680) {
      int bb = blk - 4608;               // 96 x 32
      bx = bb % 96; by = bb / 96;
      W = Wqkv; Wt = Wqkvt; N = NQKV;
    } else {
      int bb = blk - 7680;               // 32 x 32
      bx = bb % 32; by = bb / 32;
      W = Wproj; Wt = Wprojt; N = DM;
    }
    const int K = DM;
    int n0 = bx * 64, k0 = by * 64;
#pragma unroll
    for (int i = 0; i < 16; ++i) {
      int idx = t + i * 256;
      int r = idx >> 6, c = idx & 63;
      tile[r][c] = W[(size_t)(k0 + r) * N + n0 + c];
    }
    __syncthreads();
#pragma unroll
    for (int i = 0; i < 16; ++i) {
      int idx = t + i * 256;
      int r = idx >> 6, c = idx & 63;
      Wt[(size_t)(n0 + r) * K + k0 + c] = (bf16)tile[c][r];
    }
  }
}

// in-place RoPE on BOTH q and k in one launch; q gets QSCALE folded.
__global__ __launch_bounds__(256) void rope_apply_k(bf16* __restrict__ qbuf,
                                                    bf16* __restrict__ kbuf,
                                                    const float* __restrict__ cT,
                                                    const float* __restrict__ sT) {
  int id = blockIdx.x * 256 + threadIdx.x;   // < 64*2048*16
  int i4 = id & 15;
  int t = (id >> 4) & 2047;
  int bh64 = id >> 15;                       // 0..63; <32 -> q, >=32 -> k
  const bool isq = bh64 < 32;
  bf16* buf = isq ? qbuf : kbuf;
  const float scl = isq ? (float)QSCALE : 1.0f;
  int bh = isq ? bh64 : (bh64 - 32);
  int idx0 = i4 * 4;
  size_t base = ((size_t)bh * TT + t) * HDD;
  bf16x4 x1 = *(const bf16x4*)(buf + base + idx0);
  bf16x4 x2 = *(const bf16x4*)(buf + base + 64 + idx0);
  float4 ct = *(const float4*)(cT + t * 64 + idx0);
  float4 st = *(const float4*)(sT + t * 64 + idx0);
  bf16x4 o1, o2;
  float c0, s0, a, b2;
#pragma unroll
  for (int j = 0; j < 4; ++j) {
    c0 = (j == 0) ? ct.x : (j == 1) ? ct.y : (j == 2) ? ct.z : ct.w;
    s0 = (j == 0) ? st.x : (j == 1) ? st.y : (j == 2) ? st.z : st.w;
    a = (float)x1[j];
    b2 = (float)x2[j];
    o1[j] = (bf16)((a * c0 - b2 * s0) * scl);
    o2[j] = (bf16)((a * s0 + b2 * c0) * scl);
  }
  *(bf16x4*)(buf + base + idx0) = o1;
  *(bf16x4*)(buf + base + 64 + idx0) = o2;
}

// ---------------------------------------------------------------- GEMM (QKV, 1-barrier 256x192)
// R20: wave grid 4M x 2N (wm=wid>>1, wn=wid&1); per-wave output 64x96.
// Per-CU LDS read volume/tile drops 176KB -> 160KB (A re-read 2x, B 4x).
// Same staging, swizzle, 1-barrier schedule as R16-proven.
__global__ __launch_bounds__(512, 2) void gemm8_qkv_k(
    const bf16* __restrict__ A, const bf16* __restrict__ Bt,
    const float* __restrict__ bias,
    bf16* __restrict__ q_out, bf16* __restrict__ k_out, bf16* __restrict__ v_out,
    int M, int N, int K) {
  __shared__ __align__(16) char Lsm[2][57344];   // [buf][A:32KB | B:24KB]
  const int tid = threadIdx.x;
  const int wid = tid >> 6, l = tid & 63;
  const int lane16 = l & 15, lgrp = l >> 4;
  const int wm = wid >> 1, wn = wid & 1;

  int flat = blockIdx.y * gridDim.x + blockIdx.x;
  {
    const int cpx = (gridDim.x * gridDim.y) >> 3;
    flat = (flat & 7) * cpx + (flat >> 3);
  }
  const int bm = flat % gridDim.x;       // 0..15  (M/256)
  const int bn = flat / gridDim.x;       // 0..31  (N/192)
  const int NT = K >> 6;

  const int schunk = (l & 7) ^ ((l >> 3) & 7);
  const bf16* gA = A + (size_t)(bm * 256 + wid * 8 + (l >> 3)) * K + schunk * 8;
  const bf16* gB = Bt + (size_t)(bn * 192 + wid * 8 + (l >> 3)) * K + schunk * 8;

  auto stage_unit = [&](int mat, int t, int u, int buf) {
    const bf16* g = (mat ? gB : gA) + (size_t)(u * 64) * K + t * 64;
    gload_lds16(g, &Lsm[buf][(mat ? 32768 : 0) + u * 8192 + wid * 1024]);
  };

  f32x4 acc[4][6] = {};

#pragma unroll
  for (int u = 0; u < 4; ++u) stage_unit(0, 0, u, 0);
#pragma unroll
  for (int u = 0; u < 3; ++u) stage_unit(1, 0, u, 0);

  for (int t = 0; t < NT; ++t) {
    const int cur = t & 1;
    const char* As = &Lsm[cur][0];
    const char* Bs = &Lsm[cur][32768];
    bf16x8 af[4][2], bfr[6][2];

    WAITV0();                 // this tile's 7 stage loads landed (my wave's)
    BARRIER8();               // visible to all waves; prev tile fully done

    // ---- read all frags (ds_read) + stage t+1 (gload_lds -> buf^1)
#pragma unroll
    for (int mf = 0; mf < 4; ++mf)
#pragma unroll
      for (int kk = 0; kk < 2; ++kk) {
        int row = wm * 64 + mf * 16 + lane16;
        int ch = (kk * 4 + lgrp) ^ (lane16 & 7);
        af[mf][kk] = *(const bf16x8*)(As + row * 128 + ch * 16);
      }
#pragma unroll
    for (int nf = 0; nf < 6; ++nf)
#pragma unroll
      for (int kk = 0; kk < 2; ++kk) {
        int row = wn * 96 + nf * 16 + lane16;
        int ch = (kk * 4 + lgrp) ^ (lane16 & 7);
        bfr[nf][kk] = *(const bf16x8*)(Bs + row * 128 + ch * 16);
      }
    if (t + 1 < NT) {
#pragma unroll
      for (int u = 0; u < 4; ++u) stage_unit(0, t + 1, u, cur ^ 1);
#pragma unroll
      for (int u = 0; u < 3; ++u) stage_unit(1, t + 1, u, cur ^ 1);
    }

    // ---- all 48 MFMA; compiler interleaves with the ds_reads above
    __builtin_amdgcn_s_setprio(1);
#pragma unroll
    for (int mf = 0; mf < 4; ++mf)
#pragma unroll
      for (int nf = 0; nf < 6; ++nf)
#pragma unroll
        for (int kk = 0; kk < 2; ++kk)
          acc[mf][nf] = __builtin_amdgcn_mfma_f32_16x16x32_bf16(
              af[mf][kk], bfr[nf][kk], acc[mf][nf], 0, 0, 0);
    __builtin_amdgcn_s_setprio(0);
  }

  // ---- epilogue
#pragma unroll
  for (int nf = 0; nf < 6; ++nf) {
    int colg = bn * 192 + wn * 96 + nf * 16 + lane16;
    int which = colg >> 11;
    bf16* outb = (which == 0) ? q_out : (which == 1 ? k_out : v_out);
    int head = (colg >> 7) & 15, hd = colg & 127;
    float bv = bias[colg];
#pragma unroll
    for (int mf = 0; mf < 4; ++mf)
#pragma unroll
      for (int r = 0; r < 4; ++r) {
        int row = bm * 256 + wm * 64 + mf * 16 + lgrp * 4 + r;
        int bb = row >> 11, tt2 = row & 2047;
        outb[((size_t)(bb * NH + head) * TT + tt2) * HDD + hd] =
            (bf16)(acc[mf][nf][r] + bv);
      }
  }
}

// ---------------------------------------------------------------- GEMM (proj, 1-barrier 256x128)
// R20: wave grid 4M x 2N; per-wave output 64x64. LDS reads 160KB->128KB/tile.
__global__ __launch_bounds__(512, 2) void gemm4_proj_k(
    const bf16* __restrict__ A, const bf16* __restrict__ Bt,
    const float* __restrict__ bias, float* __restrict__ c_out,
    int M, int N, int K) {
  __shared__ __align__(16) char Lsm[2][49152];   // [buf][A:32KB | B:16KB]
  const int tid = threadIdx.x;
  const int wid = tid >> 6, l = tid & 63;
  const int lane16 = l & 15, lgrp = l >> 4;
  const int wm = wid >> 1, wn = wid & 1;

  int flat = blockIdx.y * gridDim.x + blockIdx.x;
  {
    const int cpx = (gridDim.x * gridDim.y) >> 3;
    flat = (flat & 7) * cpx + (flat >> 3);
  }
  const int bm = flat % gridDim.x;       // 0..15 (M/256)
  const int bn = flat / gridDim.x;       // 0..15 (N/128)
  const int NT = K >> 6;

  const int schunk = (l & 7) ^ ((l >> 3) & 7);
  const bf16* gA = A + (size_t)(bm * 256 + wid * 8 + (l >> 3)) * K + schunk * 8;
  const bf16* gB = Bt + (size_t)(bn * 128 + wid * 8 + (l >> 3)) * K + schunk * 8;

  auto stage_unit = [&](int mat, int t, int u, int buf) {
    const bf16* g = (mat ? gB : gA) + (size_t)(u * 64) * K + t * 64;
    gload_lds16(g, &Lsm[buf][(mat ? 32768 : 0) + u * 8192 + wid * 1024]);
  };

  f32x4 acc[4][4] = {};

#pragma unroll
  for (int u = 0; u < 4; ++u) stage_unit(0, 0, u, 0);
#pragma unroll
  for (int u = 0; u < 2; ++u) stage_unit(1, 0, u, 0);

  for (int t = 0; t < NT; ++t) {
    const int cur = t & 1;
    const char* As = &Lsm[cur][0];
    const char* Bs = &Lsm[cur][32768];
    bf16x8 af[4][2], bfr[4][2];

    WAITV0();
    BARRIER8();

    // ---- read all frags + stage t+1
#pragma unroll
    for (int mf = 0; mf < 4; ++mf)
#pragma unroll
      for (int kk = 0; kk < 2; ++kk) {
        int row = wm * 64 + mf * 16 + lane16;
        int ch = (kk * 4 + lgrp) ^ (lane16 & 7);
        af[mf][kk] = *(const bf16x8*)(As + row * 128 + ch * 16);
      }
#pragma unroll
    for (int nf = 0; nf < 4; ++nf)
#pragma unroll
      for (int kk = 0; kk < 2; ++kk) {
        int row = wn * 64 + nf * 16 + lane16;
        int ch = (kk * 4 + lgrp) ^ (lane16 & 7);
        bfr[nf][kk] = *(const bf16x8*)(Bs + row * 128 + ch * 16);
      }
    if (t + 1 < NT) {
#pragma unroll
      for (int u = 0; u < 4; ++u) stage_unit(0, t + 1, u, cur ^ 1);
#pragma unroll
      for (int u = 0; u < 2; ++u) stage_unit(1, t + 1, u, cur ^ 1);
    }

    // ---- all 32 MFMA
    __builtin_amdgcn_s_setprio(1);
#pragma unroll
    for (int mf = 0; mf < 4; ++mf)
#pragma unroll
      for (int nf = 0; nf < 4; ++nf)
#pragma unroll
        for (int kk = 0; kk < 2; ++kk)
          acc[mf][nf] = __builtin_amdgcn_mfma_f32_16x16x32_bf16(
              af[mf][kk], bfr[nf][kk], acc[mf][nf], 0, 0, 0);
    __builtin_amdgcn_s_setprio(0);
  }

  // ---- epilogue: bias + f32 row-major store
#pragma unroll
  for (int nf = 0; nf < 4; ++nf) {
    int colg = bn * 128 + wn * 64 + nf * 16 + lane16;
    float bv = bias[colg];
#pragma unroll
    for (int mf = 0; mf < 4; ++mf)
#pragma unroll
      for (int r = 0; r < 4; ++r) {
        int row = bm * 256 + wm * 64 + mf * 16 + lgrp * 4 + r;
        c_out[(size_t)row * N + colg] = acc[mf][nf][r] + bv;
      }
  }
}

// ---------------------------------------------------------------- attention
// R18-proven: 4-bit swizzle K/V/P; K gload_lds single-buffer; V reg-prefetch
// into compute; log2-domain softmax; setprio around MFMA clusters.
__global__ __launch_bounds__(512, 2) void attn_k(
    const bf16* __restrict__ Q, const bf16* __restrict__ Kt,
    const bf16* __restrict__ V, bf16* __restrict__ Y) {
  __shared__ __align__(16) bf16 Ksm[128 * 128];   // [key][hd], chunk^=g4(key), 32KB
  __shared__ __align__(16) bf16 Vsm[128 * 128];   // [hd][key], chunk^=g4(hd), 32KB
  __shared__ __align__(16) bf16 Psm[8][16 * 128]; // per-wave P, chunk^=g4(row), 32KB
  const int tid = threadIdx.x, w = tid >> 6, l = tid & 63;
  const int lane16 = l & 15, lgrp = l >> 4;
  const int bh = blockIdx.y;
  const int b = bh >> 4, h = bh & 15;
  const size_t base = (size_t)bh * TT * HDD;

  uint4 vreg[4];
  const int vg = tid >> 4, vh8 = tid & 15;

  auto load_V = [&](int k0) {
#pragma unroll
    for (int kq = 0; kq < 4; ++kq)
      vreg[kq] = *(const uint4*)(V + base + (size_t)(k0 + vg * 4 + kq) * HDD + vh8 * 8);
  };
  auto issue_K = [&](int k0) {
#pragma unroll
    for (int i = 0; i < 4; ++i) {
      int key = w * 16 + i * 4 + (l >> 4);
      int c = (l & 15) ^ ((key ^ (key >> 3)) & 15);
      gload_lds16(Kt + base + (size_t)(k0 + key) * HDD + c * 8,
                  &Ksm[(w * 16 + i * 4) * 128 + (l & 15) * 8]);
    }
  };
  auto write_V = [&]() {
    const unsigned* dw = (const unsigned*)vreg;
    int hd0 = vh8 * 8;
#pragma unroll
    for (int j = 0; j < 8; ++j) {
      int ww = j >> 1;
      unsigned sel = (j & 1) ? 0x07060302u : 0x05040100u;
      uint2 val;
      val.x = __builtin_amdgcn_perm(dw[4 + ww], dw[0 + ww], sel);
      val.y = __builtin_amdgcn_perm(dw[12 + ww], dw[8 + ww], sel);
      int hd = hd0 + j;
      int ch = (vg >> 1) ^ ((hd ^ (hd >> 3)) & 15);
      *(uint2*)((char*)Vsm + hd * 256 + (ch << 4) + ((vg & 1) << 3)) = val;
    }
  };

  for (int pass = 0; pass < 2; ++pass) {
    const int qt = (pass == 0) ? (int)blockIdx.x : 15 - (int)blockIdx.x;
    const int q0 = qt * 128;
    const int nt = qt + 1;

    load_V(0);              // prologue V prefetch (overlaps Q-frag loads)

    bf16x8 qa[4];
    {
      int row = q0 + w * 16 + lane16;
#pragma unroll
      for (int kk = 0; kk < 4; ++kk)
        qa[kk] = *(const bf16x8*)(Q + base + (size_t)row * HDD + kk * 32 + lgrp * 8);
    }

    f32x4 o[8] = {};
    float m_r[4], l_r[4];
#pragma unroll
    for (int r = 0; r < 4; ++r) { m_r[r] = NEG_INF; l_r[r] = 0.f; }

    for (int kt = 0; kt < nt; ++kt) {
      const int k0 = kt * 128;
      issue_K(k0);          // K direct-to-LDS (linear dest, single buffer)
      write_V();            // vreg prefetched last tile -> zero wait
      __syncthreads();      // drains K gloads + V ds_writes: staged for all
      if (kt + 1 < nt) load_V(k0 + 128);   // lands under compute

      // ---- S = Q K^T  (logits already in log2 domain via QSCALE)
      f32x4 s[8] = {};
      __builtin_amdgcn_s_setprio(1);
#pragma unroll
      for (int kk = 0; kk < 4; ++kk) {
#pragma unroll
        for (int nf = 0; nf < 8; ++nf) {
          int key = nf * 16 + lane16;
          int ch = (kk * 4 + lgrp) ^ ((key ^ (key >> 3)) & 15);
          bf16x8 kf = *(const bf16x8*)((char*)Ksm + key * 256 + (ch << 4));
          s[nf] = __builtin_amdgcn_mfma_f32_16x16x32_bf16(
              qa[kk], kf, s[nf], 0, 0, 0);
        }
      }
      __builtin_amdgcn_s_setprio(0);

      // ---- causal mask (diagonal tile only; wave-uniform branch)
      if (k0 + 127 > q0 + w * 16) {
        const int rowbase = q0 + w * 16 + lgrp * 4;
#pragma unroll
        for (int nf = 0; nf < 8; ++nf) {
          int col = k0 + nf * 16 + lane16;
#pragma unroll
          for (int r = 0; r < 4; ++r)
            if (col > rowbase + r) s[nf][r] = -3.0e38f;
        }
      }

      // ---- online softmax (log2 domain, unconditional rescale)
#pragma unroll
      for (int r = 0; r < 4; ++r) {
        float tm = fmaxf(fmaxf(fmaxf(s[0][r], s[1][r]), fmaxf(s[2][r], s[3][r])),
                         fmaxf(fmaxf(s[4][r], s[5][r]), fmaxf(s[6][r], s[7][r])));
        tm = fmaxf(tm, __shfl_xor(tm, 1));
        tm = fmaxf(tm, __shfl_xor(tm, 2));
        tm = fmaxf(tm, __shfl_xor(tm, 4));
        tm = fmaxf(tm, __shfl_xor(tm, 8));
        float mo = m_r[r];
        float mn = fmaxf(mo, tm);
        float alpha = exp2f(mo - mn);
        m_r[r] = mn;
        float rs = 0.f;
#pragma unroll
        for (int nf = 0; nf < 8; ++nf) {
          float p = exp2f(s[nf][r] - mn);
          s[nf][r] = p;
          rs += p;
        }
        rs += __shfl_xor(rs, 1);
        rs += __shfl_xor(rs, 2);
        rs += __shfl_xor(rs, 4);
        rs += __shfl_xor(rs, 8);
        l_r[r] = l_r[r] * alpha + rs;
#pragma unroll
        for (int nf = 0; nf < 8; ++nf) o[nf][r] *= alpha;
      }

      // ---- P -> LDS (per-wave region, same-wave readback; no barrier)
#pragma unroll
      for (int nf = 0; nf < 8; ++nf)
#pragma unroll
        for (int r = 0; r < 4; ++r) {
          int rl = lgrp * 4 + r;
          int ch = (2 * nf + (lane16 >> 3)) ^ ((rl ^ (rl >> 3)) & 15);
          int byte = rl * 256 + (ch << 4) + ((lane16 & 7) << 1);
          *(bf16*)((char*)&Psm[w][0] + byte) = (bf16)s[nf][r];
        }
      bf16x8 pa[4];
#pragma unroll
      for (int kk = 0; kk < 4; ++kk) {
        int ch = (kk * 4 + lgrp) ^ ((lane16 ^ (lane16 >> 3)) & 15);
        pa[kk] = *(const bf16x8*)((char*)&Psm[w][0] + lane16 * 256 + (ch << 4));
      }

      // ---- O += P V
      __builtin_amdgcn_s_setprio(1);
#pragma unroll
      for (int nf = 0; nf < 8; ++nf) {
#pragma unroll
        for (int kk = 0; kk < 4; ++kk) {
          int hd = nf * 16 + lane16;
          int ch = (kk * 4 + lgrp) ^ ((hd ^ (hd >> 3)) & 15);
          bf16x8 vf = *(const bf16x8*)((char*)Vsm + hd * 256 + (ch << 4));
          o[nf] = __builtin_amdgcn_mfma_f32_16x16x32_bf16(
              pa[kk], vf, o[nf], 0, 0, 0);
        }
      }
      __builtin_amdgcn_s_setprio(0);

      __syncthreads();      // all reads of Ksm/Vsm done; V prefetch landed
    }

    // ---- finalize: O / l -> Y (b,t,D) bf16
#pragma unroll
    for (int r = 0; r < 4; ++r) {
      float inv = 1.0f / l_r[r];
      int row = q0 + w * 16 + lgrp * 4 + r;
#pragma unroll
      for (int nf = 0; nf < 8; ++nf) {
        int hd = nf * 16 + lane16;
        Y[(size_t)(b * TT + row) * DM + h * HDD + hd] = (bf16)(o[nf][r] * inv);
      }
    }
  }
}

// ---------------------------------------------------------------- launch
extern "C" void kernel_launch(void* const* d_in, const int* in_sizes, int n_in,
                              void* d_out, int out_size, void* d_ws, size_t ws_size,
                              hipStream_t stream) {
  const float* x = (const float*)d_in[0];
  const float* Wqkv = (const float*)d_in[2];
  const float* bqkv = (const float*)d_in[3];
  const float* Wproj = (const float*)d_in[4];
  const float* bproj = (const float*)d_in[5];
  float* out = (float*)d_out;

  char* ws = (char*)d_ws;
  bf16* xb = (bf16*)ws;                 ws += (size_t)MM * DM * 2;
  bf16* Wqkvt = (bf16*)ws;              ws += (size_t)NQKV * DM * 2;
  bf16* Wprojt = (bf16*)ws;             ws += (size_t)DM * DM * 2;
  bf16* kb = (bf16*)ws;                 ws += (size_t)MM * DM * 2;
  bf16* vb = (bf16*)ws;                 ws += (size_t)MM * DM * 2;
  float* cosT = (float*)ws;             ws += (size_t)TT * 64 * 4;
  float* sinT = (float*)ws;             ws += (size_t)TT * 64 * 4;
  bf16* qb = (bf16*)d_out;              // q lives in d_out (overwritten by proj)
  bf16* yb = xb;                        // xb dead after QKV GEMM

  prepass_k<<<dim3(8704), dim3(256), 0, stream>>>(
      x, xb, Wqkv, Wqkvt, Wproj, Wprojt, cosT, sinT);

  gemm8_qkv_k<<<dim3(16, 32), dim3(512), 0, stream>>>(
      xb, Wqkvt, bqkv, qb, kb, vb, MM, NQKV, DM);

  rope_apply_k<<<dim3(8192), dim3(256), 0, stream>>>(qb, kb, cosT, sinT);

  attn_k<<<dim3(8, 32), dim3(512), 0, stream>>>(qb, kb, vb, yb);

  gemm4_proj_k<<<dim3(16, 16), dim3(512), 0, stream>>>(
      yb, Wprojt, bproj, out, MM, DM, DM);
}

// Round 21
// 245.324 us; speedup vs baseline: 1.2192x; 1.0312x over previous
//
#include <hip/hip_runtime.h>
#include <hip/hip_bf16.h>
#include <stdint.h>
#include <stddef.h>

typedef __bf16 bf16;
typedef __attribute__((ext_vector_type(8))) __bf16 bf16x8;
typedef __attribute__((ext_vector_type(4))) __bf16 bf16x4;
typedef __attribute__((ext_vector_type(4))) float f32x4;

#define DM 2048      // model dim
#define NH 16        // heads
#define HDD 128      // head dim
#define BB 2         // batch
#define TT 2048      // seq len
#define MM (BB*TT)   // 4096 rows
#define NQKV (3*DM)  // 6144

#define L2E 1.4426950408889634f
#define ATT_SCALE 0.08838834764831845f       // 1/sqrt(128)
#define QSCALE (ATT_SCALE * L2E)             // folded into Q: logits in log2 domain
#define NEG_INF (-__builtin_inff())

static_assert(sizeof(bf16x8) == 16, "bf16x8 must be 16B");

#define SB0() __builtin_amdgcn_sched_barrier(0)
#define WAITV0() { asm volatile("s_waitcnt vmcnt(0)" ::: "memory"); SB0(); }
#define BARRIER8() { SB0(); __builtin_amdgcn_s_barrier(); SB0(); }

// ---------------------------------------------------------------- helpers
static __device__ __forceinline__ void gload_lds16(const void* g, void* l) {
  __builtin_amdgcn_global_load_lds(
      (__attribute__((address_space(1))) void*)g,
      (__attribute__((address_space(3))) void*)l, 16, 0, 0);
}

// ---------------------------------------------------------------- fused pre-pass
__global__ __launch_bounds__(256) void prepass_k(
    const float* __restrict__ x, bf16* __restrict__ xb,
    const float* __restrict__ Wqkv, bf16* __restrict__ Wqkvt,
    const float* __restrict__ Wproj, bf16* __restrict__ Wprojt,
    float* __restrict__ cT, float* __restrict__ sT) {
  __shared__ float tile[64][65];
  const int blk = blockIdx.x;
  const int t = threadIdx.x;

  if (blk < 512) {                       // ---- rope table
    int id = blk * 256 + t;
    int tt = id >> 6, i = id & 63;
    float freq = powf(10000.0f, -(float)i * (1.0f / 64.0f));
    float theta = (float)tt * freq;
    float s, c;
    __sincosf(theta, &s, &c);
    cT[id] = c;
    sT[id] = s;
  } else if (blk < 4608) {               // ---- convert x
    size_t id = (size_t)(blk - 512) * 256 + t;
    size_t o = id * 8;
    float4 a = *(const float4*)(x + o);
    float4 b = *(const float4*)(x + o + 4);
    bf16x8 r;
    r[0] = (bf16)a.x; r[1] = (bf16)a.y; r[2] = (bf16)a.z; r[3] = (bf16)a.w;
    r[4] = (bf16)b.x; r[5] = (bf16)b.y; r[6] = (bf16)b.z; r[7] = (bf16)b.w;
    *(bf16x8*)(xb + o) = r;
  } else {                               // ---- weight transposes
    const float* W;
    bf16* Wt;
    int bx, by, N;
    if (blk < 7680) {
      int bb = blk - 4608;               // 96 x 32
      bx = bb % 96; by = bb / 96;
      W = Wqkv; Wt = Wqkvt; N = NQKV;
    } else {
      int bb = blk - 7680;               // 32 x 32
      bx = bb % 32; by = bb / 32;
      W = Wproj; Wt = Wprojt; N = DM;
    }
    const int K = DM;
    int n0 = bx * 64, k0 = by * 64;
#pragma unroll
    for (int i = 0; i < 16; ++i) {
      int idx = t + i * 256;
      int r = idx >> 6, c = idx & 63;
      tile[r][c] = W[(size_t)(k0 + r) * N + n0 + c];
    }
    __syncthreads();
#pragma unroll
    for (int i = 0; i < 16; ++i) {
      int idx = t + i * 256;
      int r = idx >> 6, c = idx & 63;
      Wt[(size_t)(n0 + r) * K + k0 + c] = (bf16)tile[c][r];
    }
  }
}

// in-place RoPE on BOTH q and k in one launch; q gets QSCALE folded.
__global__ __launch_bounds__(256) void rope_apply_k(bf16* __restrict__ qbuf,
                                                    bf16* __restrict__ kbuf,
                                                    const float* __restrict__ cT,
                                                    const float* __restrict__ sT) {
  int id = blockIdx.x * 256 + threadIdx.x;   // < 64*2048*16
  int i4 = id & 15;
  int t = (id >> 4) & 2047;
  int bh64 = id >> 15;                       // 0..63; <32 -> q, >=32 -> k
  const bool isq = bh64 < 32;
  bf16* buf = isq ? qbuf : kbuf;
  const float scl = isq ? (float)QSCALE : 1.0f;
  int bh = isq ? bh64 : (bh64 - 32);
  int idx0 = i4 * 4;
  size_t base = ((size_t)bh * TT + t) * HDD;
  bf16x4 x1 = *(const bf16x4*)(buf + base + idx0);
  bf16x4 x2 = *(const bf16x4*)(buf + base + 64 + idx0);
  float4 ct = *(const float4*)(cT + t * 64 + idx0);
  float4 st = *(const float4*)(sT + t * 64 + idx0);
  bf16x4 o1, o2;
  float c0, s0, a, b2;
#pragma unroll
  for (int j = 0; j < 4; ++j) {
    c0 = (j == 0) ? ct.x : (j == 1) ? ct.y : (j == 2) ? ct.z : ct.w;
    s0 = (j == 0) ? st.x : (j == 1) ? st.y : (j == 2) ? st.z : st.w;
    a = (float)x1[j];
    b2 = (float)x2[j];
    o1[j] = (bf16)((a * c0 - b2 * s0) * scl);
    o2[j] = (bf16)((a * s0 + b2 * c0) * scl);
  }
  *(bf16x4*)(buf + base + idx0) = o1;
  *(bf16x4*)(buf + base + 64 + idx0) = o2;
}

// ---------------------------------------------------------------- GEMM (QKV, 1-barrier 256x192)
// R20-proven: wave grid 4M x 2N; per-wave output 64x96; 1 barrier/tile.
__global__ __launch_bounds__(512, 2) void gemm8_qkv_k(
    const bf16* __restrict__ A, const bf16* __restrict__ Bt,
    const float* __restrict__ bias,
    bf16* __restrict__ q_out, bf16* __restrict__ k_out, bf16* __restrict__ v_out,
    int M, int N, int K) {
  __shared__ __align__(16) char Lsm[2][57344];   // [buf][A:32KB | B:24KB]
  const int tid = threadIdx.x;
  const int wid = tid >> 6, l = tid & 63;
  const int lane16 = l & 15, lgrp = l >> 4;
  const int wm = wid >> 1, wn = wid & 1;

  int flat = blockIdx.y * gridDim.x + blockIdx.x;
  {
    const int cpx = (gridDim.x * gridDim.y) >> 3;
    flat = (flat & 7) * cpx + (flat >> 3);
  }
  const int bm = flat % gridDim.x;       // 0..15  (M/256)
  const int bn = flat / gridDim.x;       // 0..31  (N/192)
  const int NT = K >> 6;

  const int schunk = (l & 7) ^ ((l >> 3) & 7);
  const bf16* gA = A + (size_t)(bm * 256 + wid * 8 + (l >> 3)) * K + schunk * 8;
  const bf16* gB = Bt + (size_t)(bn * 192 + wid * 8 + (l >> 3)) * K + schunk * 8;

  auto stage_unit = [&](int mat, int t, int u, int buf) {
    const bf16* g = (mat ? gB : gA) + (size_t)(u * 64) * K + t * 64;
    gload_lds16(g, &Lsm[buf][(mat ? 32768 : 0) + u * 8192 + wid * 1024]);
  };

  f32x4 acc[4][6] = {};

#pragma unroll
  for (int u = 0; u < 4; ++u) stage_unit(0, 0, u, 0);
#pragma unroll
  for (int u = 0; u < 3; ++u) stage_unit(1, 0, u, 0);

  for (int t = 0; t < NT; ++t) {
    const int cur = t & 1;
    const char* As = &Lsm[cur][0];
    const char* Bs = &Lsm[cur][32768];
    bf16x8 af[4][2], bfr[6][2];

    WAITV0();                 // this tile's 7 stage loads landed (my wave's)
    BARRIER8();               // visible to all waves; prev tile fully done

    // ---- read all frags (ds_read) + stage t+1 (gload_lds -> buf^1)
#pragma unroll
    for (int mf = 0; mf < 4; ++mf)
#pragma unroll
      for (int kk = 0; kk < 2; ++kk) {
        int row = wm * 64 + mf * 16 + lane16;
        int ch = (kk * 4 + lgrp) ^ (lane16 & 7);
        af[mf][kk] = *(const bf16x8*)(As + row * 128 + ch * 16);
      }
#pragma unroll
    for (int nf = 0; nf < 6; ++nf)
#pragma unroll
      for (int kk = 0; kk < 2; ++kk) {
        int row = wn * 96 + nf * 16 + lane16;
        int ch = (kk * 4 + lgrp) ^ (lane16 & 7);
        bfr[nf][kk] = *(const bf16x8*)(Bs + row * 128 + ch * 16);
      }
    if (t + 1 < NT) {
#pragma unroll
      for (int u = 0; u < 4; ++u) stage_unit(0, t + 1, u, cur ^ 1);
#pragma unroll
      for (int u = 0; u < 3; ++u) stage_unit(1, t + 1, u, cur ^ 1);
    }

    // ---- all 48 MFMA; compiler interleaves with the ds_reads above
    __builtin_amdgcn_s_setprio(1);
#pragma unroll
    for (int mf = 0; mf < 4; ++mf)
#pragma unroll
      for (int nf = 0; nf < 6; ++nf)
#pragma unroll
        for (int kk = 0; kk < 2; ++kk)
          acc[mf][nf] = __builtin_amdgcn_mfma_f32_16x16x32_bf16(
              af[mf][kk], bfr[nf][kk], acc[mf][nf], 0, 0, 0);
    __builtin_amdgcn_s_setprio(0);
  }

  // ---- epilogue
#pragma unroll
  for (int nf = 0; nf < 6; ++nf) {
    int colg = bn * 192 + wn * 96 + nf * 16 + lane16;
    int which = colg >> 11;
    bf16* outb = (which == 0) ? q_out : (which == 1 ? k_out : v_out);
    int head = (colg >> 7) & 15, hd = colg & 127;
    float bv = bias[colg];
#pragma unroll
    for (int mf = 0; mf < 4; ++mf)
#pragma unroll
      for (int r = 0; r < 4; ++r) {
        int row = bm * 256 + wm * 64 + mf * 16 + lgrp * 4 + r;
        int bb = row >> 11, tt2 = row & 2047;
        outb[((size_t)(bb * NH + head) * TT + tt2) * HDD + hd] =
            (bf16)(acc[mf][nf][r] + bv);
      }
  }
}

// ---------------------------------------------------------------- GEMM (proj, 1-barrier 256x128)
__global__ __launch_bounds__(512, 2) void gemm4_proj_k(
    const bf16* __restrict__ A, const bf16* __restrict__ Bt,
    const float* __restrict__ bias, float* __restrict__ c_out,
    int M, int N, int K) {
  __shared__ __align__(16) char Lsm[2][49152];   // [buf][A:32KB | B:16KB]
  const int tid = threadIdx.x;
  const int wid = tid >> 6, l = tid & 63;
  const int lane16 = l & 15, lgrp = l >> 4;
  const int wm = wid >> 1, wn = wid & 1;

  int flat = blockIdx.y * gridDim.x + blockIdx.x;
  {
    const int cpx = (gridDim.x * gridDim.y) >> 3;
    flat = (flat & 7) * cpx + (flat >> 3);
  }
  const int bm = flat % gridDim.x;       // 0..15 (M/256)
  const int bn = flat / gridDim.x;       // 0..15 (N/128)
  const int NT = K >> 6;

  const int schunk = (l & 7) ^ ((l >> 3) & 7);
  const bf16* gA = A + (size_t)(bm * 256 + wid * 8 + (l >> 3)) * K + schunk * 8;
  const bf16* gB = Bt + (size_t)(bn * 128 + wid * 8 + (l >> 3)) * K + schunk * 8;

  auto stage_unit = [&](int mat, int t, int u, int buf) {
    const bf16* g = (mat ? gB : gA) + (size_t)(u * 64) * K + t * 64;
    gload_lds16(g, &Lsm[buf][(mat ? 32768 : 0) + u * 8192 + wid * 1024]);
  };

  f32x4 acc[4][4] = {};

#pragma unroll
  for (int u = 0; u < 4; ++u) stage_unit(0, 0, u, 0);
#pragma unroll
  for (int u = 0; u < 2; ++u) stage_unit(1, 0, u, 0);

  for (int t = 0; t < NT; ++t) {
    const int cur = t & 1;
    const char* As = &Lsm[cur][0];
    const char* Bs = &Lsm[cur][32768];
    bf16x8 af[4][2], bfr[4][2];

    WAITV0();
    BARRIER8();

    // ---- read all frags + stage t+1
#pragma unroll
    for (int mf = 0; mf < 4; ++mf)
#pragma unroll
      for (int kk = 0; kk < 2; ++kk) {
        int row = wm * 64 + mf * 16 + lane16;
        int ch = (kk * 4 + lgrp) ^ (lane16 & 7);
        af[mf][kk] = *(const bf16x8*)(As + row * 128 + ch * 16);
      }
#pragma unroll
    for (int nf = 0; nf < 4; ++nf)
#pragma unroll
      for (int kk = 0; kk < 2; ++kk) {
        int row = wn * 64 + nf * 16 + lane16;
        int ch = (kk * 4 + lgrp) ^ (lane16 & 7);
        bfr[nf][kk] = *(const bf16x8*)(Bs + row * 128 + ch * 16);
      }
    if (t + 1 < NT) {
#pragma unroll
      for (int u = 0; u < 4; ++u) stage_unit(0, t + 1, u, cur ^ 1);
#pragma unroll
      for (int u = 0; u < 2; ++u) stage_unit(1, t + 1, u, cur ^ 1);
    }

    // ---- all 32 MFMA
    __builtin_amdgcn_s_setprio(1);
#pragma unroll
    for (int mf = 0; mf < 4; ++mf)
#pragma unroll
      for (int nf = 0; nf < 4; ++nf)
#pragma unroll
        for (int kk = 0; kk < 2; ++kk)
          acc[mf][nf] = __builtin_amdgcn_mfma_f32_16x16x32_bf16(
              af[mf][kk], bfr[nf][kk], acc[mf][nf], 0, 0, 0);
    __builtin_amdgcn_s_setprio(0);
  }

  // ---- epilogue: bias + f32 row-major store
#pragma unroll
  for (int nf = 0; nf < 4; ++nf) {
    int colg = bn * 128 + wn * 64 + nf * 16 + lane16;
    float bv = bias[colg];
#pragma unroll
    for (int mf = 0; mf < 4; ++mf)
#pragma unroll
      for (int r = 0; r < 4; ++r) {
        int row = bm * 256 + wm * 64 + mf * 16 + lgrp * 4 + r;
        c_out[(size_t)row * N + colg] = acc[mf][nf][r] + bv;
      }
  }
}

// ---------------------------------------------------------------- attention
// R18-proven structure + R21 edit: XCD-aware block swizzle (T1). The 8
// q-tile blocks of one head share the same K/V panels (read 17x each);
// work = (orig&7)*32 + orig>>3 maps them onto ONE XCD so K/V stays hot in
// that XCD's 4MB L2 (1MB working set). Bijective (256 = 8*32); work
// assignment is order-free so any bijection is correct.
__global__ __launch_bounds__(512, 2) void attn_k(
    const bf16* __restrict__ Q, const bf16* __restrict__ Kt,
    const bf16* __restrict__ V, bf16* __restrict__ Y) {
  __shared__ __align__(16) bf16 Ksm[128 * 128];   // [key][hd], chunk^=g4(key), 32KB
  __shared__ __align__(16) bf16 Vsm[128 * 128];   // [hd][key], chunk^=g4(hd), 32KB
  __shared__ __align__(16) bf16 Psm[8][16 * 128]; // per-wave P, chunk^=g4(row), 32KB
  const int tid = threadIdx.x, w = tid >> 6, l = tid & 63;
  const int lane16 = l & 15, lgrp = l >> 4;

  int work = blockIdx.y * gridDim.x + blockIdx.x;   // 0..255
  work = (work & 7) * 32 + (work >> 3);             // co-XCD heads
  const int bxw = work & 7;                         // q-tile pair index
  const int bh = work >> 3;                         // (b,h)
  const int b = bh >> 4, h = bh & 15;
  const size_t base = (size_t)bh * TT * HDD;

  uint4 vreg[4];
  const int vg = tid >> 4, vh8 = tid & 15;

  auto load_V = [&](int k0) {
#pragma unroll
    for (int kq = 0; kq < 4; ++kq)
      vreg[kq] = *(const uint4*)(V + base + (size_t)(k0 + vg * 4 + kq) * HDD + vh8 * 8);
  };
  auto issue_K = [&](int k0) {
#pragma unroll
    for (int i = 0; i < 4; ++i) {
      int key = w * 16 + i * 4 + (l >> 4);
      int c = (l & 15) ^ ((key ^ (key >> 3)) & 15);
      gload_lds16(Kt + base + (size_t)(k0 + key) * HDD + c * 8,
                  &Ksm[(w * 16 + i * 4) * 128 + (l & 15) * 8]);
    }
  };
  auto write_V = [&]() {
    const unsigned* dw = (const unsigned*)vreg;
    int hd0 = vh8 * 8;
#pragma unroll
    for (int j = 0; j < 8; ++j) {
      int ww = j >> 1;
      unsigned sel = (j & 1) ? 0x07060302u : 0x05040100u;
      uint2 val;
      val.x = __builtin_amdgcn_perm(dw[4 + ww], dw[0 + ww], sel);
      val.y = __builtin_amdgcn_perm(dw[12 + ww], dw[8 + ww], sel);
      int hd = hd0 + j;
      int ch = (vg >> 1) ^ ((hd ^ (hd >> 3)) & 15);
      *(uint2*)((char*)Vsm + hd * 256 + (ch << 4) + ((vg & 1) << 3)) = val;
    }
  };

  for (int pass = 0; pass < 2; ++pass) {
    const int qt = (pass == 0) ? bxw : 15 - bxw;
    const int q0 = qt * 128;
    const int nt = qt + 1;

    load_V(0);              // prologue V prefetch (overlaps Q-frag loads)

    bf16x8 qa[4];
    {
      int row = q0 + w * 16 + lane16;
#pragma unroll
      for (int kk = 0; kk < 4; ++kk)
        qa[kk] = *(const bf16x8*)(Q + base + (size_t)row * HDD + kk * 32 + lgrp * 8);
    }

    f32x4 o[8] = {};
    float m_r[4], l_r[4];
#pragma unroll
    for (int r = 0; r < 4; ++r) { m_r[r] = NEG_INF; l_r[r] = 0.f; }

    for (int kt = 0; kt < nt; ++kt) {
      const int k0 = kt * 128;
      issue_K(k0);          // K direct-to-LDS (linear dest, single buffer)
      write_V();            // vreg prefetched last tile -> zero wait
      __syncthreads();      // drains K gloads + V ds_writes: staged for all
      if (kt + 1 < nt) load_V(k0 + 128);   // lands under compute

      // ---- S = Q K^T  (logits already in log2 domain via QSCALE)
      f32x4 s[8] = {};
      __builtin_amdgcn_s_setprio(1);
#pragma unroll
      for (int kk = 0; kk < 4; ++kk) {
#pragma unroll
        for (int nf = 0; nf < 8; ++nf) {
          int key = nf * 16 + lane16;
          int ch = (kk * 4 + lgrp) ^ ((key ^ (key >> 3)) & 15);
          bf16x8 kf = *(const bf16x8*)((char*)Ksm + key * 256 + (ch << 4));
          s[nf] = __builtin_amdgcn_mfma_f32_16x16x32_bf16(
              qa[kk], kf, s[nf], 0, 0, 0);
        }
      }
      __builtin_amdgcn_s_setprio(0);

      // ---- causal mask (diagonal tile only; wave-uniform branch)
      if (k0 + 127 > q0 + w * 16) {
        const int rowbase = q0 + w * 16 + lgrp * 4;
#pragma unroll
        for (int nf = 0; nf < 8; ++nf) {
          int col = k0 + nf * 16 + lane16;
#pragma unroll
          for (int r = 0; r < 4; ++r)
            if (col > rowbase + r) s[nf][r] = -3.0e38f;
        }
      }

      // ---- online softmax (log2 domain, unconditional rescale)
#pragma unroll
      for (int r = 0; r < 4; ++r) {
        float tm = fmaxf(fmaxf(fmaxf(s[0][r], s[1][r]), fmaxf(s[2][r], s[3][r])),
                         fmaxf(fmaxf(s[4][r], s[5][r]), fmaxf(s[6][r], s[7][r])));
        tm = fmaxf(tm, __shfl_xor(tm, 1));
        tm = fmaxf(tm, __shfl_xor(tm, 2));
        tm = fmaxf(tm, __shfl_xor(tm, 4));
        tm = fmaxf(tm, __shfl_xor(tm, 8));
        float mo = m_r[r];
        float mn = fmaxf(mo, tm);
        float alpha = exp2f(mo - mn);
        m_r[r] = mn;
        float rs = 0.f;
#pragma unroll
        for (int nf = 0; nf < 8; ++nf) {
          float p = exp2f(s[nf][r] - mn);
          s[nf][r] = p;
          rs += p;
        }
        rs += __shfl_xor(rs, 1);
        rs += __shfl_xor(rs, 2);
        rs += __shfl_xor(rs, 4);
        rs += __shfl_xor(rs, 8);
        l_r[r] = l_r[r] * alpha + rs;
#pragma unroll
        for (int nf = 0; nf < 8; ++nf) o[nf][r] *= alpha;
      }

      // ---- P -> LDS (per-wave region, same-wave readback; no barrier)
#pragma unroll
      for (int nf = 0; nf < 8; ++nf)
#pragma unroll
        for (int r = 0; r < 4; ++r) {
          int rl = lgrp * 4 + r;
          int ch = (2 * nf + (lane16 >> 3)) ^ ((rl ^ (rl >> 3)) & 15);
          int byte = rl * 256 + (ch << 4) + ((lane16 & 7) << 1);
          *(bf16*)((char*)&Psm[w][0] + byte) = (bf16)s[nf][r];
        }
      bf16x8 pa[4];
#pragma unroll
      for (int kk = 0; kk < 4; ++kk) {
        int ch = (kk * 4 + lgrp) ^ ((lane16 ^ (lane16 >> 3)) & 15);
        pa[kk] = *(const bf16x8*)((char*)&Psm[w][0] + lane16 * 256 + (ch << 4));
      }

      // ---- O += P V
      __builtin_amdgcn_s_setprio(1);
#pragma unroll
      for (int nf = 0; nf < 8; ++nf) {
#pragma unroll
        for (int kk = 0; kk < 4; ++kk) {
          int hd = nf * 16 + lane16;
          int ch = (kk * 4 + lgrp) ^ ((hd ^ (hd >> 3)) & 15);
          bf16x8 vf = *(const bf16x8*)((char*)Vsm + hd * 256 + (ch << 4));
          o[nf] = __builtin_amdgcn_mfma_f32_16x16x32_bf16(
              pa[kk], vf, o[nf], 0, 0, 0);
        }
      }
      __builtin_amdgcn_s_setprio(0);

      __syncthreads();      // all reads of Ksm/Vsm done; V prefetch landed
    }

    // ---- finalize: O / l -> Y (b,t,D) bf16
#pragma unroll
    for (int r = 0; r < 4; ++r) {
      float inv = 1.0f / l_r[r];
      int row = q0 + w * 16 + lgrp * 4 + r;
#pragma unroll
      for (int nf = 0; nf < 8; ++nf) {
        int hd = nf * 16 + lane16;
        Y[(size_t)(b * TT + row) * DM + h * HDD + hd] = (bf16)(o[nf][r] * inv);
      }
    }
  }
}

// ---------------------------------------------------------------- launch
extern "C" void kernel_launch(void* const* d_in, const int* in_sizes, int n_in,
                              void* d_out, int out_size, void* d_ws, size_t ws_size,
                              hipStream_t stream) {
  const float* x = (const float*)d_in[0];
  const float* Wqkv = (const float*)d_in[2];
  const float* bqkv = (const float*)d_in[3];
  const float* Wproj = (const float*)d_in[4];
  const float* bproj = (const float*)d_in[5];
  float* out = (float*)d_out;

  char* ws = (char*)d_ws;
  bf16* xb = (bf16*)ws;                 ws += (size_t)MM * DM * 2;
  bf16* Wqkvt = (bf16*)ws;              ws += (size_t)NQKV * DM * 2;
  bf16* Wprojt = (bf16*)ws;             ws += (size_t)DM * DM * 2;
  bf16* kb = (bf16*)ws;                 ws += (size_t)MM * DM * 2;
  bf16* vb = (bf16*)ws;                 ws += (size_t)MM * DM * 2;
  float* cosT = (float*)ws;             ws += (size_t)TT * 64 * 4;
  float* sinT = (float*)ws;             ws += (size_t)TT * 64 * 4;
  bf16* qb = (bf16*)d_out;              // q lives in d_out (overwritten by proj)
  bf16* yb = xb;                        // xb dead after QKV GEMM

  prepass_k<<<dim3(8704), dim3(256), 0, stream>>>(
      x, xb, Wqkv, Wqkvt, Wproj, Wprojt, cosT, sinT);

  gemm8_qkv_k<<<dim3(16, 32), dim3(512), 0, stream>>>(
      xb, Wqkvt, bqkv, qb, kb, vb, MM, NQKV, DM);

  rope_apply_k<<<dim3(8192), dim3(256), 0, stream>>>(qb, kb, cosT, sinT);

  attn_k<<<dim3(8, 32), dim3(512), 0, stream>>>(qb, kb, vb, yb);

  gemm4_proj_k<<<dim3(16, 16), dim3(512), 0, stream>>>(
      yb, Wprojt, bproj, out, MM, DM, DM);
}

// Round 23
// 245.129 us; speedup vs baseline: 1.2202x; 1.0008x over previous
//
#include <hip/hip_runtime.h>
#include <hip/hip_bf16.h>
#include <stdint.h>
#include <stddef.h>

typedef __bf16 bf16;
typedef __attribute__((ext_vector_type(8))) __bf16 bf16x8;
typedef __attribute__((ext_vector_type(4))) __bf16 bf16x4;
typedef __attribute__((ext_vector_type(4))) float f32x4;

#define DM 2048      // model dim
#define NH 16        // heads
#define HDD 128      // head dim
#define BB 2         // batch
#define TT 2048      // seq len
#define MM (BB*TT)   // 4096 rows
#define NQKV (3*DM)  // 6144

#define L2E 1.4426950408889634f
#define ATT_SCALE 0.08838834764831845f       // 1/sqrt(128)
#define QSCALE (ATT_SCALE * L2E)             // folded into Q: logits in log2 domain
#define NEG_INF (-__builtin_inff())

static_assert(sizeof(bf16x8) == 16, "bf16x8 must be 16B");

#define SB0() __builtin_amdgcn_sched_barrier(0)
#define WAITV0() { asm volatile("s_waitcnt vmcnt(0)" ::: "memory"); SB0(); }
#define BARRIER8() { SB0(); __builtin_amdgcn_s_barrier(); SB0(); }

// ---------------------------------------------------------------- helpers
static __device__ __forceinline__ void gload_lds16(const void* g, void* l) {
  __builtin_amdgcn_global_load_lds(
      (__attribute__((address_space(1))) void*)g,
      (__attribute__((address_space(3))) void*)l, 16, 0, 0);
}

// ---------------------------------------------------------------- fused pre-pass
__global__ __launch_bounds__(256) void prepass_k(
    const float* __restrict__ x, bf16* __restrict__ xb,
    const float* __restrict__ Wqkv, bf16* __restrict__ Wqkvt,
    const float* __restrict__ Wproj, bf16* __restrict__ Wprojt,
    float* __restrict__ cT, float* __restrict__ sT) {
  __shared__ float tile[64][65];
  const int blk = blockIdx.x;
  const int t = threadIdx.x;

  if (blk < 512) {                       // ---- rope table
    int id = blk * 256 + t;
    int tt = id >> 6, i = id & 63;
    float freq = powf(10000.0f, -(float)i * (1.0f / 64.0f));
    float theta = (float)tt * freq;
    float s, c;
    __sincosf(theta, &s, &c);
    cT[id] = c;
    sT[id] = s;
  } else if (blk < 4608) {               // ---- convert x
    size_t id = (size_t)(blk - 512) * 256 + t;
    size_t o = id * 8;
    float4 a = *(const float4*)(x + o);
    float4 b = *(const float4*)(x + o + 4);
    bf16x8 r;
    r[0] = (bf16)a.x; r[1] = (bf16)a.y; r[2] = (bf16)a.z; r[3] = (bf16)a.w;
    r[4] = (bf16)b.x; r[5] = (bf16)b.y; r[6] = (bf16)b.z; r[7] = (bf16)b.w;
    *(bf16x8*)(xb + o) = r;
  } else {                               // ---- weight transposes
    const float* W;
    bf16* Wt;
    int bx, by, N;
    if (blk < 7680) {
      int bb = blk - 4608;               // 96 x 32
      bx = bb % 96; by = bb / 96;
      W = Wqkv; Wt = Wqkvt; N = NQKV;
    } else {
      int bb = blk - 7680;               // 32 x 32
      bx = bb % 32; by = bb / 32;
      W = Wproj; Wt = Wprojt; N = DM;
    }
    const int K = DM;
    int n0 = bx * 64, k0 = by * 64;
#pragma unroll
    for (int i = 0; i < 16; ++i) {
      int idx = t + i * 256;
      int r = idx >> 6, c = idx & 63;
      tile[r][c] = W[(size_t)(k0 + r) * N + n0 + c];
    }
    __syncthreads();
#pragma unroll
    for (int i = 0; i < 16; ++i) {
      int idx = t + i * 256;
      int r = idx >> 6, c = idx & 63;
      Wt[(size_t)(n0 + r) * K + k0 + c] = (bf16)tile[c][r];
    }
  }
}

// in-place RoPE on BOTH q and k in one launch; q gets QSCALE folded.
__global__ __launch_bounds__(256) void rope_apply_k(bf16* __restrict__ qbuf,
                                                    bf16* __restrict__ kbuf,
                                                    const float* __restrict__ cT,
                                                    const float* __restrict__ sT) {
  int id = blockIdx.x * 256 + threadIdx.x;   // < 64*2048*16
  int i4 = id & 15;
  int t = (id >> 4) & 2047;
  int bh64 = id >> 15;                       // 0..63; <32 -> q, >=32 -> k
  const bool isq = bh64 < 32;
  bf16* buf = isq ? qbuf : kbuf;
  const float scl = isq ? (float)QSCALE : 1.0f;
  int bh = isq ? bh64 : (bh64 - 32);
  int idx0 = i4 * 4;
  size_t base = ((size_t)bh * TT + t) * HDD;
  bf16x4 x1 = *(const bf16x4*)(buf + base + idx0);
  bf16x4 x2 = *(const bf16x4*)(buf + base + 64 + idx0);
  float4 ct = *(const float4*)(cT + t * 64 + idx0);
  float4 st = *(const float4*)(sT + t * 64 + idx0);
  bf16x4 o1, o2;
  float c0, s0, a, b2;
#pragma unroll
  for (int j = 0; j < 4; ++j) {
    c0 = (j == 0) ? ct.x : (j == 1) ? ct.y : (j == 2) ? ct.z : ct.w;
    s0 = (j == 0) ? st.x : (j == 1) ? st.y : (j == 2) ? st.z : st.w;
    a = (float)x1[j];
    b2 = (float)x2[j];
    o1[j] = (bf16)((a * c0 - b2 * s0) * scl);
    o2[j] = (bf16)((a * s0 + b2 * c0) * scl);
  }
  *(bf16x4*)(buf + base + idx0) = o1;
  *(bf16x4*)(buf + base + 64 + idx0) = o2;
}

// ---------------------------------------------------------------- GEMM (QKV, 1-barrier 256x192)
// R20-proven main loop; R23: LDS-staged epilogue with CORRECT chunk count
// (24 chunks/row of 8 bf16; 256*24 = 6144 = 12 * 512 vectors).
__global__ __launch_bounds__(512, 2) void gemm8_qkv_k(
    const bf16* __restrict__ A, const bf16* __restrict__ Bt,
    const float* __restrict__ bias,
    bf16* __restrict__ q_out, bf16* __restrict__ k_out, bf16* __restrict__ v_out,
    int M, int N, int K) {
  __shared__ __align__(16) char Lsm[2][57344];   // [buf][A:32KB | B:24KB]
  const int tid = threadIdx.x;
  const int wid = tid >> 6, l = tid & 63;
  const int lane16 = l & 15, lgrp = l >> 4;
  const int wm = wid >> 1, wn = wid & 1;

  int flat = blockIdx.y * gridDim.x + blockIdx.x;
  {
    const int cpx = (gridDim.x * gridDim.y) >> 3;
    flat = (flat & 7) * cpx + (flat >> 3);
  }
  const int bm = flat % gridDim.x;       // 0..15  (M/256)
  const int bn = flat / gridDim.x;       // 0..31  (N/192)
  const int NT = K >> 6;

  const int schunk = (l & 7) ^ ((l >> 3) & 7);
  const bf16* gA = A + (size_t)(bm * 256 + wid * 8 + (l >> 3)) * K + schunk * 8;
  const bf16* gB = Bt + (size_t)(bn * 192 + wid * 8 + (l >> 3)) * K + schunk * 8;

  auto stage_unit = [&](int mat, int t, int u, int buf) {
    const bf16* g = (mat ? gB : gA) + (size_t)(u * 64) * K + t * 64;
    gload_lds16(g, &Lsm[buf][(mat ? 32768 : 0) + u * 8192 + wid * 1024]);
  };

  f32x4 acc[4][6] = {};

#pragma unroll
  for (int u = 0; u < 4; ++u) stage_unit(0, 0, u, 0);
#pragma unroll
  for (int u = 0; u < 3; ++u) stage_unit(1, 0, u, 0);

  for (int t = 0; t < NT; ++t) {
    const int cur = t & 1;
    const char* As = &Lsm[cur][0];
    const char* Bs = &Lsm[cur][32768];
    bf16x8 af[4][2], bfr[6][2];

    WAITV0();                 // this tile's 7 stage loads landed (my wave's)
    BARRIER8();               // visible to all waves; prev tile fully done

    // ---- read all frags (ds_read) + stage t+1 (gload_lds -> buf^1)
#pragma unroll
    for (int mf = 0; mf < 4; ++mf)
#pragma unroll
      for (int kk = 0; kk < 2; ++kk) {
        int row = wm * 64 + mf * 16 + lane16;
        int ch = (kk * 4 + lgrp) ^ (lane16 & 7);
        af[mf][kk] = *(const bf16x8*)(As + row * 128 + ch * 16);
      }
#pragma unroll
    for (int nf = 0; nf < 6; ++nf)
#pragma unroll
      for (int kk = 0; kk < 2; ++kk) {
        int row = wn * 96 + nf * 16 + lane16;
        int ch = (kk * 4 + lgrp) ^ (lane16 & 7);
        bfr[nf][kk] = *(const bf16x8*)(Bs + row * 128 + ch * 16);
      }
    if (t + 1 < NT) {
#pragma unroll
      for (int u = 0; u < 4; ++u) stage_unit(0, t + 1, u, cur ^ 1);
#pragma unroll
      for (int u = 0; u < 3; ++u) stage_unit(1, t + 1, u, cur ^ 1);
    }

    // ---- all 48 MFMA; compiler interleaves with the ds_reads above
    __builtin_amdgcn_s_setprio(1);
#pragma unroll
    for (int mf = 0; mf < 4; ++mf)
#pragma unroll
      for (int nf = 0; nf < 6; ++nf)
#pragma unroll
        for (int kk = 0; kk < 2; ++kk)
          acc[mf][nf] = __builtin_amdgcn_mfma_f32_16x16x32_bf16(
              af[mf][kk], bfr[nf][kk], acc[mf][nf], 0, 0, 0);
    __builtin_amdgcn_s_setprio(0);
  }

  // ---- epilogue: stage C tile in LDS (bf16, stride 200 = 400B), then
  // fully-coalesced 16B stores to the (b,head,t,hd) layout.
  WAITV0();
  BARRIER8();               // all waves done reading Lsm
  {
    bf16* Cs = (bf16*)&Lsm[0][0];        // 256 x 200 bf16 = 100KB (< 112KB)
#pragma unroll
    for (int nf = 0; nf < 6; ++nf) {
      int col = wn * 96 + nf * 16 + lane16;
      float bv = bias[bn * 192 + col];
#pragma unroll
      for (int mf = 0; mf < 4; ++mf)
#pragma unroll
        for (int r = 0; r < 4; ++r) {
          int row = wm * 64 + mf * 16 + lgrp * 4 + r;
          Cs[row * 200 + col] = (bf16)(acc[mf][nf][r] + bv);
        }
    }
    BARRIER8();                          // C tile staged
#pragma unroll
    for (int i = 0; i < 12; ++i) {
      int f = i * 512 + tid;             // 0..6143 = 256 rows x 24 chunks
      int row = f / 24, ch = f - row * 24;
      bf16x8 v = *(const bf16x8*)(Cs + row * 200 + ch * 8);
      int colg = bn * 192 + ch * 8;
      int which = colg >> 11;
      bf16* outb = (which == 0) ? q_out : (which == 1 ? k_out : v_out);
      int head = (colg >> 7) & 15, hd = colg & 127;
      int row_g = bm * 256 + row;
      int bb = row_g >> 11, tt2 = row_g & 2047;
      *(bf16x8*)(&outb[((size_t)(bb * NH + head) * TT + tt2) * HDD + hd]) = v;
    }
  }
}

// ---------------------------------------------------------------- GEMM (proj, 1-barrier 256x128)
__global__ __launch_bounds__(512, 2) void gemm4_proj_k(
    const bf16* __restrict__ A, const bf16* __restrict__ Bt,
    const float* __restrict__ bias, float* __restrict__ c_out,
    int M, int N, int K) {
  __shared__ __align__(16) char Lsm[2][49152];   // [buf][A:32KB | B:16KB]
  const int tid = threadIdx.x;
  const int wid = tid >> 6, l = tid & 63;
  const int lane16 = l & 15, lgrp = l >> 4;
  const int wm = wid >> 1, wn = wid & 1;

  int flat = blockIdx.y * gridDim.x + blockIdx.x;
  {
    const int cpx = (gridDim.x * gridDim.y) >> 3;
    flat = (flat & 7) * cpx + (flat >> 3);
  }
  const int bm = flat % gridDim.x;       // 0..15 (M/256)
  const int bn = flat / gridDim.x;       // 0..15 (N/128)
  const int NT = K >> 6;

  const int schunk = (l & 7) ^ ((l >> 3) & 7);
  const bf16* gA = A + (size_t)(bm * 256 + wid * 8 + (l >> 3)) * K + schunk * 8;
  const bf16* gB = Bt + (size_t)(bn * 128 + wid * 8 + (l >> 3)) * K + schunk * 8;

  auto stage_unit = [&](int mat, int t, int u, int buf) {
    const bf16* g = (mat ? gB : gA) + (size_t)(u * 64) * K + t * 64;
    gload_lds16(g, &Lsm[buf][(mat ? 32768 : 0) + u * 8192 + wid * 1024]);
  };

  f32x4 acc[4][4] = {};

#pragma unroll
  for (int u = 0; u < 4; ++u) stage_unit(0, 0, u, 0);
#pragma unroll
  for (int u = 0; u < 2; ++u) stage_unit(1, 0, u, 0);

  for (int t = 0; t < NT; ++t) {
    const int cur = t & 1;
    const char* As = &Lsm[cur][0];
    const char* Bs = &Lsm[cur][32768];
    bf16x8 af[4][2], bfr[4][2];

    WAITV0();
    BARRIER8();

    // ---- read all frags + stage t+1
#pragma unroll
    for (int mf = 0; mf < 4; ++mf)
#pragma unroll
      for (int kk = 0; kk < 2; ++kk) {
        int row = wm * 64 + mf * 16 + lane16;
        int ch = (kk * 4 + lgrp) ^ (lane16 & 7);
        af[mf][kk] = *(const bf16x8*)(As + row * 128 + ch * 16);
      }
#pragma unroll
    for (int nf = 0; nf < 4; ++nf)
#pragma unroll
      for (int kk = 0; kk < 2; ++kk) {
        int row = wn * 64 + nf * 16 + lane16;
        int ch = (kk * 4 + lgrp) ^ (lane16 & 7);
        bfr[nf][kk] = *(const bf16x8*)(Bs + row * 128 + ch * 16);
      }
    if (t + 1 < NT) {
#pragma unroll
      for (int u = 0; u < 4; ++u) stage_unit(0, t + 1, u, cur ^ 1);
#pragma unroll
      for (int u = 0; u < 2; ++u) stage_unit(1, t + 1, u, cur ^ 1);
    }

    // ---- all 32 MFMA
    __builtin_amdgcn_s_setprio(1);
#pragma unroll
    for (int mf = 0; mf < 4; ++mf)
#pragma unroll
      for (int nf = 0; nf < 4; ++nf)
#pragma unroll
        for (int kk = 0; kk < 2; ++kk)
          acc[mf][nf] = __builtin_amdgcn_mfma_f32_16x16x32_bf16(
              af[mf][kk], bfr[nf][kk], acc[mf][nf], 0, 0, 0);
    __builtin_amdgcn_s_setprio(0);
  }

  // ---- epilogue: bias + f32 row-major store (already coalesced)
#pragma unroll
  for (int nf = 0; nf < 4; ++nf) {
    int colg = bn * 128 + wn * 64 + nf * 16 + lane16;
    float bv = bias[colg];
#pragma unroll
    for (int mf = 0; mf < 4; ++mf)
#pragma unroll
      for (int r = 0; r < 4; ++r) {
        int row = bm * 256 + wm * 64 + mf * 16 + lgrp * 4 + r;
        c_out[(size_t)row * N + colg] = acc[mf][nf][r] + bv;
      }
  }
}

// ---------------------------------------------------------------- attention
// R21-proven: 4-bit swizzle K/V/P; K gload_lds single-buffer; V reg-prefetch;
// log2-domain softmax; setprio; co-XCD head swizzle.
__global__ __launch_bounds__(512, 2) void attn_k(
    const bf16* __restrict__ Q, const bf16* __restrict__ Kt,
    const bf16* __restrict__ V, bf16* __restrict__ Y) {
  __shared__ __align__(16) bf16 Ksm[128 * 128];   // [key][hd], chunk^=g4(key), 32KB
  __shared__ __align__(16) bf16 Vsm[128 * 128];   // [hd][key], chunk^=g4(hd), 32KB
  __shared__ __align__(16) bf16 Psm[8][16 * 128]; // per-wave P, chunk^=g4(row), 32KB
  const int tid = threadIdx.x, w = tid >> 6, l = tid & 63;
  const int lane16 = l & 15, lgrp = l >> 4;

  int work = blockIdx.y * gridDim.x + blockIdx.x;   // 0..255
  work = (work & 7) * 32 + (work >> 3);             // co-XCD heads
  const int bxw = work & 7;                         // q-tile pair index
  const int bh = work >> 3;                         // (b,h)
  const int b = bh >> 4, h = bh & 15;
  const size_t base = (size_t)bh * TT * HDD;

  uint4 vreg[4];
  const int vg = tid >> 4, vh8 = tid & 15;

  auto load_V = [&](int k0) {
#pragma unroll
    for (int kq = 0; kq < 4; ++kq)
      vreg[kq] = *(const uint4*)(V + base + (size_t)(k0 + vg * 4 + kq) * HDD + vh8 * 8);
  };
  auto issue_K = [&](int k0) {
#pragma unroll
    for (int i = 0; i < 4; ++i) {
      int key = w * 16 + i * 4 + (l >> 4);
      int c = (l & 15) ^ ((key ^ (key >> 3)) & 15);
      gload_lds16(Kt + base + (size_t)(k0 + key) * HDD + c * 8,
                  &Ksm[(w * 16 + i * 4) * 128 + (l & 15) * 8]);
    }
  };
  auto write_V = [&]() {
    const unsigned* dw = (const unsigned*)vreg;
    int hd0 = vh8 * 8;
#pragma unroll
    for (int j = 0; j < 8; ++j) {
      int ww = j >> 1;
      unsigned sel = (j & 1) ? 0x07060302u : 0x05040100u;
      uint2 val;
      val.x = __builtin_amdgcn_perm(dw[4 + ww], dw[0 + ww], sel);
      val.y = __builtin_amdgcn_perm(dw[12 + ww], dw[8 + ww], sel);
      int hd = hd0 + j;
      int ch = (vg >> 1) ^ ((hd ^ (hd >> 3)) & 15);
      *(uint2*)((char*)Vsm + hd * 256 + (ch << 4) + ((vg & 1) << 3)) = val;
    }
  };

  for (int pass = 0; pass < 2; ++pass) {
    const int qt = (pass == 0) ? bxw : 15 - bxw;
    const int q0 = qt * 128;
    const int nt = qt + 1;

    load_V(0);              // prologue V prefetch (overlaps Q-frag loads)

    bf16x8 qa[4];
    {
      int row = q0 + w * 16 + lane16;
#pragma unroll
      for (int kk = 0; kk < 4; ++kk)
        qa[kk] = *(const bf16x8*)(Q + base + (size_t)row * HDD + kk * 32 + lgrp * 8);
    }

    f32x4 o[8] = {};
    float m_r[4], l_r[4];
#pragma unroll
    for (int r = 0; r < 4; ++r) { m_r[r] = NEG_INF; l_r[r] = 0.f; }

    for (int kt = 0; kt < nt; ++kt) {
      const int k0 = kt * 128;
      issue_K(k0);          // K direct-to-LDS (linear dest, single buffer)
      write_V();            // vreg prefetched last tile -> zero wait
      __syncthreads();      // drains K gloads + V ds_writes: staged for all
      if (kt + 1 < nt) load_V(k0 + 128);   // lands under compute

      // ---- S = Q K^T  (logits already in log2 domain via QSCALE)
      f32x4 s[8] = {};
      __builtin_amdgcn_s_setprio(1);
#pragma unroll
      for (int kk = 0; kk < 4; ++kk) {
#pragma unroll
        for (int nf = 0; nf < 8; ++nf) {
          int key = nf * 16 + lane16;
          int ch = (kk * 4 + lgrp) ^ ((key ^ (key >> 3)) & 15);
          bf16x8 kf = *(const bf16x8*)((char*)Ksm + key * 256 + (ch << 4));
          s[nf] = __builtin_amdgcn_mfma_f32_16x16x32_bf16(
              qa[kk], kf, s[nf], 0, 0, 0);
        }
      }
      __builtin_amdgcn_s_setprio(0);

      // ---- causal mask (diagonal tile only; wave-uniform branch)
      if (k0 + 127 > q0 + w * 16) {
        const int rowbase = q0 + w * 16 + lgrp * 4;
#pragma unroll
        for (int nf = 0; nf < 8; ++nf) {
          int col = k0 + nf * 16 + lane16;
#pragma unroll
          for (int r = 0; r < 4; ++r)
            if (col > rowbase + r) s[nf][r] = -3.0e38f;
        }
      }

      // ---- online softmax (log2 domain, unconditional rescale)
#pragma unroll
      for (int r = 0; r < 4; ++r) {
        float tm = fmaxf(fmaxf(fmaxf(s[0][r], s[1][r]), fmaxf(s[2][r], s[3][r])),
                         fmaxf(fmaxf(s[4][r], s[5][r]), fmaxf(s[6][r], s[7][r])));
        tm = fmaxf(tm, __shfl_xor(tm, 1));
        tm = fmaxf(tm, __shfl_xor(tm, 2));
        tm = fmaxf(tm, __shfl_xor(tm, 4));
        tm = fmaxf(tm, __shfl_xor(tm, 8));
        float mo = m_r[r];
        float mn = fmaxf(mo, tm);
        float alpha = exp2f(mo - mn);
        m_r[r] = mn;
        float rs = 0.f;
#pragma unroll
        for (int nf = 0; nf < 8; ++nf) {
          float p = exp2f(s[nf][r] - mn);
          s[nf][r] = p;
          rs += p;
        }
        rs += __shfl_xor(rs, 1);
        rs += __shfl_xor(rs, 2);
        rs += __shfl_xor(rs, 4);
        rs += __shfl_xor(rs, 8);
        l_r[r] = l_r[r] * alpha + rs;
#pragma unroll
        for (int nf = 0; nf < 8; ++nf) o[nf][r] *= alpha;
      }

      // ---- P -> LDS (per-wave region, same-wave readback; no barrier)
#pragma unroll
      for (int nf = 0; nf < 8; ++nf)
#pragma unroll
        for (int r = 0; r < 4; ++r) {
          int rl = lgrp * 4 + r;
          int ch = (2 * nf + (lane16 >> 3)) ^ ((rl ^ (rl >> 3)) & 15);
          int byte = rl * 256 + (ch << 4) + ((lane16 & 7) << 1);
          *(bf16*)((char*)&Psm[w][0] + byte) = (bf16)s[nf][r];
        }
      bf16x8 pa[4];
#pragma unroll
      for (int kk = 0; kk < 4; ++kk) {
        int ch = (kk * 4 + lgrp) ^ ((lane16 ^ (lane16 >> 3)) & 15);
        pa[kk] = *(const bf16x8*)((char*)&Psm[w][0] + lane16 * 256 + (ch << 4));
      }

      // ---- O += P V
      __builtin_amdgcn_s_setprio(1);
#pragma unroll
      for (int nf = 0; nf < 8; ++nf) {
#pragma unroll
        for (int kk = 0; kk < 4; ++kk) {
          int hd = nf * 16 + lane16;
          int ch = (kk * 4 + lgrp) ^ ((hd ^ (hd >> 3)) & 15);
          bf16x8 vf = *(const bf16x8*)((char*)Vsm + hd * 256 + (ch << 4));
          o[nf] = __builtin_amdgcn_mfma_f32_16x16x32_bf16(
              pa[kk], vf, o[nf], 0, 0, 0);
        }
      }
      __builtin_amdgcn_s_setprio(0);

      __syncthreads();      // all reads of Ksm/Vsm done; V prefetch landed
    }

    // ---- finalize: O / l -> Y (b,t,D) bf16
#pragma unroll
    for (int r = 0; r < 4; ++r) {
      float inv = 1.0f / l_r[r];
      int row = q0 + w * 16 + lgrp * 4 + r;
#pragma unroll
      for (int nf = 0; nf < 8; ++nf) {
        int hd = nf * 16 + lane16;
        Y[(size_t)(b * TT + row) * DM + h * HDD + hd] = (bf16)(o[nf][r] * inv);
      }
    }
  }
}

// ---------------------------------------------------------------- launch
extern "C" void kernel_launch(void* const* d_in, const int* in_sizes, int n_in,
                              void* d_out, int out_size, void* d_ws, size_t ws_size,
                              hipStream_t stream) {
  const float* x = (const float*)d_in[0];
  const float* Wqkv = (const float*)d_in[2];
  const float* bqkv = (const float*)d_in[3];
  const float* Wproj = (const float*)d_in[4];
  const float* bproj = (const float*)d_in[5];
  float* out = (float*)d_out;

  char* ws = (char*)d_ws;
  bf16* xb = (bf16*)ws;                 ws += (size_t)MM * DM * 2;
  bf16* Wqkvt = (bf16*)ws;              ws += (size_t)NQKV * DM * 2;
  bf16* Wprojt = (bf16*)ws;             ws += (size_t)DM * DM * 2;
  bf16* kb = (bf16*)ws;                 ws += (size_t)MM * DM * 2;
  bf16* vb = (bf16*)ws;                 ws += (size_t)MM * DM * 2;
  float* cosT = (float*)ws;             ws += (size_t)TT * 64 * 4;
  float* sinT = (float*)ws;             ws += (size_t)TT * 64 * 4;
  bf16* qb = (bf16*)d_out;              // q lives in d_out (overwritten by proj)
  bf16* yb = xb;                        // xb dead after QKV GEMM

  prepass_k<<<dim3(8704), dim3(256), 0, stream>>>(
      x, xb, Wqkv, Wqkvt, Wproj, Wprojt, cosT, sinT);

  gemm8_qkv_k<<<dim3(16, 32), dim3(512), 0, stream>>>(
      xb, Wqkvt, bqkv, qb, kb, vb, MM, NQKV, DM);

  rope_apply_k<<<dim3(8192), dim3(256), 0, stream>>>(qb, kb, cosT, sinT);

  attn_k<<<dim3(8, 32), dim3(512), 0, stream>>>(qb, kb, vb, yb);

  gemm4_proj_k<<<dim3(16, 16), dim3(512), 0, stream>>>(
      yb, Wprojt, bproj, out, MM, DM, DM);
}